// Round 1
// baseline (5678.138 us; speedup 1.0000x reference)
//
#include <hip/hip_runtime.h>
#include <math.h>

#define T_TOK 8192
#define DMODEL 512
#define NHEAD 8
#define DKH 64
#define TEDIM 192
#define CATD 768
#define DFF 1365
#define NLAYER 3
#define WINSZ 128
#define NBLK 16
#define LSEQ 2048
#define BATCH 4

__device__ __forceinline__ float silu_f(float x) { return x / (1.0f + expf(-x)); }
__device__ __forceinline__ float softplus_f(float x) {
    return (x > 20.0f) ? x : log1pf(expf(x));
}

// ---------------- K1: encode features -> silu(cat)  (T x 768) ----------------
__global__ __launch_bounds__(256)
void encode_kernel(const int* __restrict__ x, const float* __restrict__ emb,
                   const float* __restrict__ reg_w, const float* __restrict__ reg_b,
                   const float* __restrict__ br_w, const float* __restrict__ br_b,
                   const float* __restrict__ sh_w, const float* __restrict__ sh_b,
                   float* __restrict__ cat) {
    int tok = blockIdx.x;
    int tid = threadIdx.x;
    __shared__ float xr[288];
    const int* xp = x + (size_t)tok * 289;
    for (int i = tid; i < 288; i += 256) xr[i] = (float)xp[1 + i];
    __syncthreads();
    int tokid = xp[0];
    for (int o = tid; o < CATD; o += 256) {
        float v;
        if (o < 192) {
            v = emb[(size_t)tokid * TEDIM + o];
        } else if (o < 384) {
            int j = o - 192;
            float s = reg_b[j];
            const float* wr = reg_w + (size_t)j * 64;
            #pragma unroll 8
            for (int k = 0; k < 64; ++k) s += xr[k] * wr[k];
            v = s;
        } else if (o < 576) {
            int j = o - 384;
            float s = br_b[j];
            const float* wr = br_w + (size_t)j * 32;
            #pragma unroll 8
            for (int k = 0; k < 32; ++k) s += xr[256 + k] * wr[k];
            v = s;
        } else {
            int j = o - 576;
            float s = sh_b[j];
            const float* wr = sh_w + (size_t)j * 192;
            #pragma unroll 8
            for (int k = 0; k < 192; ++k) s += xr[64 + k] * wr[k];
            v = s;
        }
        cat[(size_t)tok * CATD + o] = silu_f(v);
    }
}

// ---------------- generic tiled GEMM: C[M,N] = A[M,K] @ W[N,K]^T (+bias)(+res) --
#define BM 64
#define BN 64
#define BK 16

__global__ __launch_bounds__(256)
void gemm_nt(const float* __restrict__ A, const float* __restrict__ W,
             const float* __restrict__ bias, const float* __restrict__ res,
             float* __restrict__ C, int M, int N, int K, int flags) {
    __shared__ __align__(16) float As[BK][BM + 4];
    __shared__ __align__(16) float Ws[BK][BN + 4];
    int tid = threadIdx.x;
    int bm = blockIdx.y * BM;
    int bn = blockIdx.x * BN;
    int tx = tid & 15, ty = tid >> 4;
    float acc[4][4] = {};
    for (int kt = 0; kt < K; kt += BK) {
        #pragma unroll
        for (int q = 0; q < 4; ++q) {
            int idx = tid * 4 + q;           // 0..1023
            int row = idx >> 4, kk = idx & 15;
            int k = kt + kk;
            As[kk][row] = (k < K) ? A[(size_t)(bm + row) * K + k] : 0.0f;
            int n = bn + row;
            Ws[kk][row] = (k < K && n < N) ? W[(size_t)n * K + k] : 0.0f;
        }
        __syncthreads();
        #pragma unroll
        for (int kk = 0; kk < BK; ++kk) {
            float4 av = *(const float4*)&As[kk][ty * 4];
            float4 bv = *(const float4*)&Ws[kk][tx * 4];
            float a[4] = {av.x, av.y, av.z, av.w};
            float b[4] = {bv.x, bv.y, bv.z, bv.w};
            #pragma unroll
            for (int i = 0; i < 4; ++i)
                #pragma unroll
                for (int j = 0; j < 4; ++j) acc[i][j] += a[i] * b[j];
        }
        __syncthreads();
    }
    #pragma unroll
    for (int i = 0; i < 4; ++i) {
        int m = bm + ty * 4 + i;
        #pragma unroll
        for (int j = 0; j < 4; ++j) {
            int n = bn + tx * 4 + j;
            if (n < N) {
                float v = acc[i][j];
                if (flags & 1) v += bias[n];
                if (flags & 2) v += res[(size_t)m * N + n];
                C[(size_t)m * N + n] = v;
            }
        }
    }
}

// ---------------- fused GLU GEMM: C = silu(A@W1^T + b1) * (A@W3^T + b3) -------
__global__ __launch_bounds__(256)
void gemm_glu(const float* __restrict__ A, const float* __restrict__ W1,
              const float* __restrict__ b1, const float* __restrict__ W3,
              const float* __restrict__ b3, float* __restrict__ C,
              int M, int N, int K) {
    __shared__ __align__(16) float As[BK][BM + 4];
    __shared__ __align__(16) float W1s[BK][BN + 4];
    __shared__ __align__(16) float W3s[BK][BN + 4];
    int tid = threadIdx.x;
    int bm = blockIdx.y * BM;
    int bn = blockIdx.x * BN;
    int tx = tid & 15, ty = tid >> 4;
    float acc1[4][4] = {};
    float acc3[4][4] = {};
    for (int kt = 0; kt < K; kt += BK) {
        #pragma unroll
        for (int q = 0; q < 4; ++q) {
            int idx = tid * 4 + q;
            int row = idx >> 4, kk = idx & 15;
            int k = kt + kk;
            As[kk][row] = (k < K) ? A[(size_t)(bm + row) * K + k] : 0.0f;
            int n = bn + row;
            bool ok = (k < K && n < N);
            W1s[kk][row] = ok ? W1[(size_t)n * K + k] : 0.0f;
            W3s[kk][row] = ok ? W3[(size_t)n * K + k] : 0.0f;
        }
        __syncthreads();
        #pragma unroll
        for (int kk = 0; kk < BK; ++kk) {
            float4 av = *(const float4*)&As[kk][ty * 4];
            float4 b1v = *(const float4*)&W1s[kk][tx * 4];
            float4 b3v = *(const float4*)&W3s[kk][tx * 4];
            float a[4] = {av.x, av.y, av.z, av.w};
            float u1[4] = {b1v.x, b1v.y, b1v.z, b1v.w};
            float u3[4] = {b3v.x, b3v.y, b3v.z, b3v.w};
            #pragma unroll
            for (int i = 0; i < 4; ++i)
                #pragma unroll
                for (int j = 0; j < 4; ++j) {
                    acc1[i][j] += a[i] * u1[j];
                    acc3[i][j] += a[i] * u3[j];
                }
        }
        __syncthreads();
    }
    #pragma unroll
    for (int i = 0; i < 4; ++i) {
        int m = bm + ty * 4 + i;
        #pragma unroll
        for (int j = 0; j < 4; ++j) {
            int n = bn + tx * 4 + j;
            if (n < N) {
                float v1 = acc1[i][j] + b1[n];
                float v3 = acc3[i][j] + b3[n];
                C[(size_t)m * N + n] = silu_f(v1) * v3;
            }
        }
    }
}

// ---------------- per-token reductions ----------------------------------------
__device__ __forceinline__ float block_reduce_sum256(float v, float* red) {
    #pragma unroll
    for (int off = 32; off > 0; off >>= 1) v += __shfl_down(v, off, 64);
    int lane = threadIdx.x & 63, wid = threadIdx.x >> 6;
    if (lane == 0) red[wid] = v;
    __syncthreads();
    float s = red[0] + red[1] + red[2] + red[3];
    __syncthreads();
    return s;
}

__global__ __launch_bounds__(256)
void rms_kernel(const float* __restrict__ h, const float* __restrict__ w,
                float* __restrict__ out) {
    __shared__ float red[4];
    int t = blockIdx.x, tid = threadIdx.x;
    float x0 = h[(size_t)t * 512 + tid];
    float x1 = h[(size_t)t * 512 + 256 + tid];
    float ss = block_reduce_sum256(x0 * x0 + x1 * x1, red);
    float inv = rsqrtf(ss * (1.0f / 512.0f) + 1.1920929e-07f);
    out[(size_t)t * 512 + tid] = x0 * inv * w[tid];
    out[(size_t)t * 512 + 256 + tid] = x1 * inv * w[256 + tid];
}

__global__ __launch_bounds__(256)
void ln_silu_kernel(const float* __restrict__ h, const float* __restrict__ w,
                    const float* __restrict__ b, float* __restrict__ out) {
    __shared__ float red[4];
    int t = blockIdx.x, tid = threadIdx.x;
    float x0 = h[(size_t)t * 512 + tid];
    float x1 = h[(size_t)t * 512 + 256 + tid];
    float m = block_reduce_sum256(x0 + x1, red) * (1.0f / 512.0f);
    float d0 = x0 - m, d1 = x1 - m;
    float var = block_reduce_sum256(d0 * d0 + d1 * d1, red) * (1.0f / 512.0f);
    float inv = rsqrtf(var + 1e-5f);
    out[(size_t)t * 512 + tid] = silu_f(d0 * inv * w[tid] + b[tid]);
    out[(size_t)t * 512 + 256 + tid] = silu_f(d1 * inv * w[256 + tid] + b[256 + tid]);
}

// ---------------- local attention ---------------------------------------------
// grid: (nb=16, head=8, batch=4); 128 threads, 1 query/thread; online softmax.
__global__ __launch_bounds__(128)
void attn_kernel(const float* __restrict__ qkv, float* __restrict__ attn) {
    int nb = blockIdx.x;
    int head = blockIdx.y;
    int b = blockIdx.z;
    int i = threadIdx.x;   // query index in block, 0..127
    __shared__ __align__(16) float Ks[64][64];
    __shared__ __align__(16) float Vs[64][64];

    int qtok = nb * WINSZ + i;
    size_t qbase = ((size_t)(b * LSEQ + qtok)) * 1536 + (size_t)head * 192;
    float q[64];
    float posq = (float)qtok;
    #pragma unroll
    for (int p = 0; p < 32; ++p) {
        float x1 = qkv[qbase + (2 * p) * 3 + 0];
        float x2 = qkv[qbase + (2 * p + 1) * 3 + 0];
        float invf = powf(10000.0f, -(float)p * (1.0f / 32.0f));
        float ang = posq * invf;
        float sn, cs;
        sincosf(ang, &sn, &cs);
        q[2 * p] = (x1 * cs - x2 * sn) * 0.125f;      // fold 1/sqrt(64)
        q[2 * p + 1] = (x1 * sn + x2 * cs) * 0.125f;
    }

    float mrun = -1e30f, lrun = 0.0f;
    float o[64];
    #pragma unroll
    for (int d = 0; d < 64; ++d) o[d] = 0.0f;

    int c0 = (nb == 0) ? 2 : 0;     // block 0: prev-block keys fully masked
    for (int c = c0; c < 4; ++c) {
        // stage 64 keys (RoPE'd) + values
        int r = threadIdx.x >> 1;
        int half = threadIdx.x & 1;
        int ktok = nb * WINSZ - WINSZ + c * 64 + r;
        size_t kbase = ((size_t)(b * LSEQ + ktok)) * 1536 + (size_t)head * 192;
        float posk = (float)ktok;
        #pragma unroll
        for (int p = 0; p < 16; ++p) {
            int pp = half * 16 + p;
            float x1 = qkv[kbase + (2 * pp) * 3 + 1];
            float x2 = qkv[kbase + (2 * pp + 1) * 3 + 1];
            float invf = powf(10000.0f, -(float)pp * (1.0f / 32.0f));
            float ang = posk * invf;
            float sn, cs;
            sincosf(ang, &sn, &cs);
            Ks[r][2 * pp] = x1 * cs - x2 * sn;
            Ks[r][2 * pp + 1] = x1 * sn + x2 * cs;
            Vs[r][2 * pp] = qkv[kbase + (2 * pp) * 3 + 2];
            Vs[r][2 * pp + 1] = qkv[kbase + (2 * pp + 1) * 3 + 2];
        }
        __syncthreads();
        for (int jj = 0; jj < 64; ++jj) {
            int j = c * 64 + jj;               // 0..255 in concat
            float s = 0.0f;
            #pragma unroll
            for (int d = 0; d < 64; d += 4) {
                float4 kv = *(const float4*)&Ks[jj][d];
                s += q[d] * kv.x + q[d + 1] * kv.y + q[d + 2] * kv.z + q[d + 3] * kv.w;
            }
            bool valid = (j >= i) && (j <= i + WINSZ);
            if (valid) {
                float mn = fmaxf(mrun, s);
                float alpha = expf(mrun - mn);
                float p = expf(s - mn);
                lrun = lrun * alpha + p;
                #pragma unroll
                for (int d = 0; d < 64; d += 4) {
                    float4 vv = *(const float4*)&Vs[jj][d];
                    o[d]     = o[d]     * alpha + p * vv.x;
                    o[d + 1] = o[d + 1] * alpha + p * vv.y;
                    o[d + 2] = o[d + 2] * alpha + p * vv.z;
                    o[d + 3] = o[d + 3] * alpha + p * vv.w;
                }
                mrun = mn;
            }
        }
        __syncthreads();
    }
    float invl = 1.0f / lrun;
    size_t obase = ((size_t)(b * LSEQ + qtok)) * 512 + (size_t)head * 64;
    #pragma unroll
    for (int d = 0; d < 64; ++d) attn[obase + d] = o[d] * invl;
}

// ---------------- head + postprocess ------------------------------------------
__global__ __launch_bounds__(256)
void head_kernel(const float* __restrict__ hh, const float* __restrict__ head_w,
                 const float* __restrict__ head_b, float* __restrict__ out) {
    int wid = threadIdx.x >> 6, lane = threadIdx.x & 63;
    int t = blockIdx.x * 4 + wid;
    __shared__ float yv[4][32];
    const float* xr = hh + (size_t)t * 512;
    float xv[8];
    #pragma unroll
    for (int u = 0; u < 8; ++u) xv[u] = xr[u * 64 + lane];
    for (int j = 0; j < 31; ++j) {
        const float* wr = head_w + (size_t)j * 512;
        float p = 0.0f;
        #pragma unroll
        for (int u = 0; u < 8; ++u) p += xv[u] * wr[u * 64 + lane];
        #pragma unroll
        for (int off = 32; off > 0; off >>= 1) p += __shfl_down(p, off, 64);
        if (lane == 0) yv[wid][j] = p + head_b[j];
    }
    if (lane == 0) {
        float* y = yv[wid];
        float* op = out + (size_t)t * 40;
        // fetch
        int am = 0; float best = y[0];
        for (int j = 1; j < 11; ++j) if (y[j] > best) { best = y[j]; am = j; }
        float fc_reg = softplus_f(y[11]);
        op[0] = (am < 10) ? (float)(am + 1) : fc_reg;
        for (int j = 0; j < 11; ++j) op[1 + j] = y[j];
        op[12] = fc_reg;
        // exec
        int am2 = 0; float best2 = y[12];
        for (int j = 1; j < 11; ++j) if (y[12 + j] > best2) { best2 = y[12 + j]; am2 = j; }
        float ec_reg = softplus_f(y[23]);
        op[13] = (am2 < 10) ? (float)(am2 + 1) : ec_reg;
        for (int j = 0; j < 11; ++j) op[14 + j] = y[12 + j];
        op[25] = ec_reg;
        float bm_log = y[24];
        op[26] = 1.0f / (1.0f + expf(-bm_log));
        float mi = fmaxf(y[25], fmaxf(y[26], y[27]));
        float e0 = expf(y[25] - mi), e1 = expf(y[26] - mi), e2 = expf(y[27] - mi);
        float si = e0 + e1 + e2;
        op[27] = e0 / si; op[28] = e1 / si; op[29] = e2 / si;
        float md = fmaxf(y[28], fmaxf(y[29], y[30]));
        float d0 = expf(y[28] - md), d1 = expf(y[29] - md), d2 = expf(y[30] - md);
        float sd = d0 + d1 + d2;
        op[30] = d0 / sd; op[31] = d1 / sd; op[32] = d2 / sd;
        op[33] = bm_log;
        op[34] = y[25]; op[35] = y[26]; op[36] = y[27];
        op[37] = y[28]; op[38] = y[29]; op[39] = y[30];
    }
}

// ---------------- launch -------------------------------------------------------
extern "C" void kernel_launch(void* const* d_in, const int* in_sizes, int n_in,
                              void* d_out, int out_size, void* d_ws, size_t ws_size,
                              hipStream_t stream) {
    const int*   x        = (const int*)d_in[0];
    const float* emb      = (const float*)d_in[1];
    const float* reg_w    = (const float*)d_in[2];
    const float* reg_b    = (const float*)d_in[3];
    const float* br_w     = (const float*)d_in[4];
    const float* br_b     = (const float*)d_in[5];
    const float* sh_w     = (const float*)d_in[6];
    const float* sh_b     = (const float*)d_in[7];
    const float* inst_w   = (const float*)d_in[8];
    const float* inst_b   = (const float*)d_in[9];
    const float* enc_ln_w = (const float*)d_in[10];
    const float* enc_ln_b = (const float*)d_in[11];
    const float* qkv_w    = (const float*)d_in[12];
    const float* out_w    = (const float*)d_in[13];
    const float* out_b    = (const float*)d_in[14];
    const float* w1_w     = (const float*)d_in[15];
    const float* w1_b     = (const float*)d_in[16];
    const float* w3_w     = (const float*)d_in[17];
    const float* w3_b     = (const float*)d_in[18];
    const float* w2_w     = (const float*)d_in[19];
    const float* w2_b     = (const float*)d_in[20];
    const float* n1_w     = (const float*)d_in[21];
    const float* n2_w     = (const float*)d_in[22];
    const float* hl_w     = (const float*)d_in[23];
    const float* hl_b     = (const float*)d_in[24];
    const float* head_w   = (const float*)d_in[25];
    const float* head_b   = (const float*)d_in[26];

    float* R1 = (float*)d_ws;                       // cat (T*768) / qkv (T*1536)
    float* R2 = R1 + (size_t)T_TOK * 1536;          // h
    float* R3 = R2 + (size_t)T_TOK * 512;           // rms/ln outputs
    float* R4 = R3 + (size_t)T_TOK * 512;           // attn out
    float* R5 = R4 + (size_t)T_TOK * 512;           // g (T*1365)

    // encoder
    encode_kernel<<<T_TOK, 256, 0, stream>>>(x, emb, reg_w, reg_b, br_w, br_b,
                                             sh_w, sh_b, R1);
    {
        dim3 g(DMODEL / BN, T_TOK / BM);
        gemm_nt<<<g, 256, 0, stream>>>(R1, inst_w, inst_b, nullptr, R2,
                                       T_TOK, DMODEL, CATD, 1);
    }
    ln_silu_kernel<<<T_TOK, 256, 0, stream>>>(R2, enc_ln_w, enc_ln_b, R2);

    for (int l = 0; l < NLAYER; ++l) {
        rms_kernel<<<T_TOK, 256, 0, stream>>>(R2, n1_w + l * DMODEL, R3);
        {
            dim3 g(1536 / BN, T_TOK / BM);
            gemm_nt<<<g, 256, 0, stream>>>(R3, qkv_w + (size_t)l * 1536 * DMODEL,
                                           nullptr, nullptr, R1,
                                           T_TOK, 1536, DMODEL, 0);
        }
        {
            dim3 g(NBLK, NHEAD, BATCH);
            attn_kernel<<<g, 128, 0, stream>>>(R1, R4);
        }
        {
            dim3 g(DMODEL / BN, T_TOK / BM);
            gemm_nt<<<g, 256, 0, stream>>>(R4, out_w + (size_t)l * DMODEL * DMODEL,
                                           out_b + l * DMODEL, R2, R2,
                                           T_TOK, DMODEL, DMODEL, 3);
        }
        rms_kernel<<<T_TOK, 256, 0, stream>>>(R2, n2_w + l * DMODEL, R3);
        {
            dim3 g((DFF + BN - 1) / BN, T_TOK / BM);
            gemm_glu<<<g, 256, 0, stream>>>(R3, w1_w + (size_t)l * DFF * DMODEL,
                                            w1_b + l * DFF,
                                            w3_w + (size_t)l * DFF * DMODEL,
                                            w3_b + l * DFF, R5,
                                            T_TOK, DFF, DMODEL);
        }
        {
            dim3 g(DMODEL / BN, T_TOK / BM);
            gemm_nt<<<g, 256, 0, stream>>>(R5, w2_w + (size_t)l * DMODEL * DFF,
                                           w2_b + l * DMODEL, R2, R2,
                                           T_TOK, DMODEL, DFF, 3);
        }
    }

    ln_silu_kernel<<<T_TOK, 256, 0, stream>>>(R2, hl_w, hl_b, R3);
    head_kernel<<<T_TOK / 4, 256, 0, stream>>>(R3, head_w, head_b, (float*)d_out);
}

// Round 2
// 2428.190 us; speedup vs baseline: 2.3384x; 2.3384x over previous
//
#include <hip/hip_runtime.h>
#include <hip/hip_bf16.h>
#include <math.h>

#define T_TOK 8192
#define DMODEL 512
#define NHEAD 8
#define TEDIM 192
#define DFF 1365
#define DFFP 1408      // N-padded for tiles of 128
#define KP2 1376       // DFF padded to mult of 32
#define NLAYER 3
#define WINSZ 128
#define NBLK 16
#define LSEQ 2048
#define BATCH 4

typedef unsigned short ushort_t;
typedef __bf16 bf16x8 __attribute__((ext_vector_type(8)));
typedef float f32x4 __attribute__((ext_vector_type(4)));

__device__ __forceinline__ float silu_f(float x) { return x / (1.0f + expf(-x)); }
__device__ __forceinline__ float softplus_f(float x) {
    return (x > 20.0f) ? x : log1pf(expf(x));
}

__device__ __forceinline__ ushort_t f2u(float x) {
    __hip_bfloat16 b = __float2bfloat16(x);
    return *reinterpret_cast<ushort_t*>(&b);
}
__device__ __forceinline__ float u2f(ushort_t u) {
    __hip_bfloat16 b = *reinterpret_cast<__hip_bfloat16*>(&u);
    return __bfloat162float(b);
}
__device__ __forceinline__ void split2(float x, ushort_t& hi, ushort_t& lo) {
    hi = f2u(x);
    lo = f2u(x - u2f(hi));
}

__device__ __forceinline__ void gl_lds16(const ushort_t* g, ushort_t* l) {
    __builtin_amdgcn_global_load_lds(
        (const __attribute__((address_space(1))) unsigned int*)g,
        (__attribute__((address_space(3))) unsigned int*)l, 16, 0, 0);
}

// ---------------- weight split: W[N][K] fp32 -> W2[Npad][2*Kp] bf16 hi|lo -----
__global__ __launch_bounds__(256)
void splitw_kernel(const float* __restrict__ W, ushort_t* __restrict__ W2,
                   int N, int K, int Kp) {
    int n = blockIdx.y;
    int k = blockIdx.x * 256 + threadIdx.x;
    if (k >= Kp) return;
    float v = (n < N && k < K) ? W[(size_t)n * K + k] : 0.0f;
    ushort_t hi, lo;
    split2(v, hi, lo);
    W2[(size_t)n * (2 * Kp) + k] = hi;
    W2[(size_t)n * (2 * Kp) + Kp + k] = lo;
}

// ---------------- encode -> silu(cat) split bf16 (T x 2*768) ------------------
__global__ __launch_bounds__(256)
void encode_kernel(const int* __restrict__ x, const float* __restrict__ emb,
                   const float* __restrict__ reg_w, const float* __restrict__ reg_b,
                   const float* __restrict__ br_w, const float* __restrict__ br_b,
                   const float* __restrict__ sh_w, const float* __restrict__ sh_b,
                   ushort_t* __restrict__ cat2) {
    int tok = blockIdx.x;
    int tid = threadIdx.x;
    __shared__ float xr[288];
    const int* xp = x + (size_t)tok * 289;
    for (int i = tid; i < 288; i += 256) xr[i] = (float)xp[1 + i];
    __syncthreads();
    int tokid = xp[0];
    for (int o = tid; o < 768; o += 256) {
        float v;
        if (o < 192) {
            v = emb[(size_t)tokid * TEDIM + o];
        } else if (o < 384) {
            int j = o - 192;
            float s = reg_b[j];
            const float* wr = reg_w + (size_t)j * 64;
            #pragma unroll 8
            for (int k = 0; k < 64; ++k) s += xr[k] * wr[k];
            v = s;
        } else if (o < 576) {
            int j = o - 384;
            float s = br_b[j];
            const float* wr = br_w + (size_t)j * 32;
            #pragma unroll 8
            for (int k = 0; k < 32; ++k) s += xr[256 + k] * wr[k];
            v = s;
        } else {
            int j = o - 576;
            float s = sh_b[j];
            const float* wr = sh_w + (size_t)j * 192;
            #pragma unroll 8
            for (int k = 0; k < 192; ++k) s += xr[64 + k] * wr[k];
            v = s;
        }
        ushort_t hi, lo;
        split2(silu_f(v), hi, lo);
        cat2[(size_t)tok * 1536 + o] = hi;
        cat2[(size_t)tok * 1536 + 768 + o] = lo;
    }
}

// ---------------- bf16x3 MFMA GEMM: C[M,N] = A2[M,2Kp] x B2[N,2Kp] ------------
// 128x128 tile, 256 thr (4 waves 2x2 of 64x64), BK=32, 16x16x32 MFMA.
// mode 0: fp32 out (+bias)(+res); 1: fp32 silu(acc+bias); 2: glu -> split bf16
__global__ __launch_bounds__(256)
void gemm3_kernel(const ushort_t* __restrict__ A2, int rsA,
                  const ushort_t* __restrict__ B2, int rsB,
                  const float* __restrict__ bias, int Nb,
                  const float* __restrict__ res,
                  const float* __restrict__ aux, int rsAux,
                  void* __restrict__ Cout, int rsC,
                  int Kp, int mode) {
    __shared__ __align__(16) ushort_t lds[4 * 4096];  // Ahi|Alo|Bhi|Blo
    const int tid = threadIdx.x;
    const int bm = blockIdx.y * 128, bn = blockIdx.x * 128;
    const int w = tid >> 6, l = tid & 63;
    const int wm = (w & 1) * 64, wn = (w >> 1) * 64;

    f32x4 acc[4][4];
    #pragma unroll
    for (int i = 0; i < 4; ++i)
        #pragma unroll
        for (int j = 0; j < 4; ++j) acc[i][j] = (f32x4){0.f, 0.f, 0.f, 0.f};

    const int r0 = tid >> 2, k8 = (tid & 3) * 8;
    const ushort_t* gA0 = A2 + (size_t)(bm + r0) * rsA + k8;
    const ushort_t* gA1 = A2 + (size_t)(bm + 64 + r0) * rsA + k8;
    const ushort_t* gB0 = B2 + (size_t)(bn + r0) * rsB + k8;
    const ushort_t* gB1 = B2 + (size_t)(bn + 64 + r0) * rsB + k8;
    ushort_t* l0 = lds + tid * 8;
    ushort_t* l1 = lds + 2048 + tid * 8;

    const int fr = l & 15, fk = (l >> 4) * 8;

    for (int kt = 0; kt < Kp; kt += 32) {
        gl_lds16(gA0 + kt, l0);
        gl_lds16(gA1 + kt, l1);
        gl_lds16(gA0 + kt + Kp, l0 + 4096);
        gl_lds16(gA1 + kt + Kp, l1 + 4096);
        gl_lds16(gB0 + kt, l0 + 8192);
        gl_lds16(gB1 + kt, l1 + 8192);
        gl_lds16(gB0 + kt + Kp, l0 + 12288);
        gl_lds16(gB1 + kt + Kp, l1 + 12288);
        __syncthreads();

        bf16x8 ahi[4], alo[4], bhi[4], blo[4];
        #pragma unroll
        for (int i = 0; i < 4; ++i) {
            int ra = (wm + i * 16 + fr) * 32 + fk;
            int rb = (wn + i * 16 + fr) * 32 + fk;
            ahi[i] = *(const bf16x8*)&lds[ra];
            alo[i] = *(const bf16x8*)&lds[4096 + ra];
            bhi[i] = *(const bf16x8*)&lds[8192 + rb];
            blo[i] = *(const bf16x8*)&lds[12288 + rb];
        }
        #pragma unroll
        for (int i = 0; i < 4; ++i)
            #pragma unroll
            for (int j = 0; j < 4; ++j) {
                acc[i][j] = __builtin_amdgcn_mfma_f32_16x16x32_bf16(ahi[i], bhi[j], acc[i][j], 0, 0, 0);
                acc[i][j] = __builtin_amdgcn_mfma_f32_16x16x32_bf16(ahi[i], blo[j], acc[i][j], 0, 0, 0);
                acc[i][j] = __builtin_amdgcn_mfma_f32_16x16x32_bf16(alo[i], bhi[j], acc[i][j], 0, 0, 0);
            }
        __syncthreads();
    }

    const int er = (l >> 4) * 4, ec = l & 15;
    if (mode == 0) {
        float* Cf = (float*)Cout;
        #pragma unroll
        for (int i = 0; i < 4; ++i)
            #pragma unroll
            for (int j = 0; j < 4; ++j)
                #pragma unroll
                for (int r = 0; r < 4; ++r) {
                    int gm = bm + wm + i * 16 + er + r;
                    int gn = bn + wn + j * 16 + ec;
                    float v = acc[i][j][r];
                    if (bias) v += bias[gn];
                    if (res) v += res[(size_t)gm * rsC + gn];
                    Cf[(size_t)gm * rsC + gn] = v;
                }
    } else if (mode == 1) {
        float* Cf = (float*)Cout;
        #pragma unroll
        for (int i = 0; i < 4; ++i)
            #pragma unroll
            for (int j = 0; j < 4; ++j)
                #pragma unroll
                for (int r = 0; r < 4; ++r) {
                    int gm = bm + wm + i * 16 + er + r;
                    int gn = bn + wn + j * 16 + ec;
                    float b = (gn < Nb) ? bias[gn] : 0.0f;
                    Cf[(size_t)gm * rsC + gn] = silu_f(acc[i][j][r] + b);
                }
    } else {
        ushort_t* C2 = (ushort_t*)Cout;
        int half = rsC >> 1;
        #pragma unroll
        for (int i = 0; i < 4; ++i)
            #pragma unroll
            for (int j = 0; j < 4; ++j)
                #pragma unroll
                for (int r = 0; r < 4; ++r) {
                    int gm = bm + wm + i * 16 + er + r;
                    int gn = bn + wn + j * 16 + ec;
                    if (gn < half) {
                        float g = 0.0f;
                        if (gn < Nb) {
                            float v = acc[i][j][r] + bias[gn];
                            g = aux[(size_t)gm * rsAux + gn] * v;
                        }
                        ushort_t hi, lo;
                        split2(g, hi, lo);
                        C2[(size_t)gm * rsC + gn] = hi;
                        C2[(size_t)gm * rsC + half + gn] = lo;
                    }
                }
    }
}

// ---------------- per-token reductions ----------------------------------------
__device__ __forceinline__ float block_reduce_sum256(float v, float* red) {
    #pragma unroll
    for (int off = 32; off > 0; off >>= 1) v += __shfl_down(v, off, 64);
    int lane = threadIdx.x & 63, wid = threadIdx.x >> 6;
    if (lane == 0) red[wid] = v;
    __syncthreads();
    float s = red[0] + red[1] + red[2] + red[3];
    __syncthreads();
    return s;
}

__global__ __launch_bounds__(256)
void rms_kernel(const float* __restrict__ h, const float* __restrict__ w,
                ushort_t* __restrict__ out2) {
    __shared__ float red[4];
    int t = blockIdx.x, tid = threadIdx.x;
    float x0 = h[(size_t)t * 512 + tid];
    float x1 = h[(size_t)t * 512 + 256 + tid];
    float ss = block_reduce_sum256(x0 * x0 + x1 * x1, red);
    float inv = rsqrtf(ss * (1.0f / 512.0f) + 1.1920929e-07f);
    ushort_t hi, lo;
    split2(x0 * inv * w[tid], hi, lo);
    out2[(size_t)t * 1024 + tid] = hi;
    out2[(size_t)t * 1024 + 512 + tid] = lo;
    split2(x1 * inv * w[256 + tid], hi, lo);
    out2[(size_t)t * 1024 + 256 + tid] = hi;
    out2[(size_t)t * 1024 + 768 + tid] = lo;
}

__global__ __launch_bounds__(256)
void ln_silu_kernel(const float* __restrict__ h, const float* __restrict__ w,
                    const float* __restrict__ b, float* __restrict__ out) {
    __shared__ float red[4];
    int t = blockIdx.x, tid = threadIdx.x;
    float x0 = h[(size_t)t * 512 + tid];
    float x1 = h[(size_t)t * 512 + 256 + tid];
    float m = block_reduce_sum256(x0 + x1, red) * (1.0f / 512.0f);
    float d0 = x0 - m, d1 = x1 - m;
    float var = block_reduce_sum256(d0 * d0 + d1 * d1, red) * (1.0f / 512.0f);
    float inv = rsqrtf(var + 1e-5f);
    out[(size_t)t * 512 + tid] = silu_f(d0 * inv * w[tid] + b[tid]);
    out[(size_t)t * 512 + 256 + tid] = silu_f(d1 * inv * w[256 + tid] + b[256 + tid]);
}

// ---------------- local attention (fp32 in, split-bf16 out) -------------------
__global__ __launch_bounds__(128)
void attn_kernel(const float* __restrict__ qkv, ushort_t* __restrict__ attn2) {
    int nb = blockIdx.x;
    int head = blockIdx.y;
    int b = blockIdx.z;
    int i = threadIdx.x;
    __shared__ __align__(16) float Ks[64][64];
    __shared__ __align__(16) float Vs[64][64];

    int qtok = nb * WINSZ + i;
    size_t qbase = ((size_t)(b * LSEQ + qtok)) * 1536 + (size_t)head * 192;
    float q[64];
    float posq = (float)qtok;
    #pragma unroll
    for (int p = 0; p < 32; ++p) {
        float x1 = qkv[qbase + (2 * p) * 3 + 0];
        float x2 = qkv[qbase + (2 * p + 1) * 3 + 0];
        float invf = powf(10000.0f, -(float)p * (1.0f / 32.0f));
        float ang = posq * invf;
        float sn, cs;
        sincosf(ang, &sn, &cs);
        q[2 * p] = (x1 * cs - x2 * sn) * 0.125f;
        q[2 * p + 1] = (x1 * sn + x2 * cs) * 0.125f;
    }

    float mrun = -1e30f, lrun = 0.0f;
    float o[64];
    #pragma unroll
    for (int d = 0; d < 64; ++d) o[d] = 0.0f;

    int c0 = (nb == 0) ? 2 : 0;
    for (int c = c0; c < 4; ++c) {
        int r = threadIdx.x >> 1;
        int half = threadIdx.x & 1;
        int ktok = nb * WINSZ - WINSZ + c * 64 + r;
        size_t kbase = ((size_t)(b * LSEQ + ktok)) * 1536 + (size_t)head * 192;
        float posk = (float)ktok;
        #pragma unroll
        for (int p = 0; p < 16; ++p) {
            int pp = half * 16 + p;
            float x1 = qkv[kbase + (2 * pp) * 3 + 1];
            float x2 = qkv[kbase + (2 * pp + 1) * 3 + 1];
            float invf = powf(10000.0f, -(float)pp * (1.0f / 32.0f));
            float ang = posk * invf;
            float sn, cs;
            sincosf(ang, &sn, &cs);
            Ks[r][2 * pp] = x1 * cs - x2 * sn;
            Ks[r][2 * pp + 1] = x1 * sn + x2 * cs;
            Vs[r][2 * pp] = qkv[kbase + (2 * pp) * 3 + 2];
            Vs[r][2 * pp + 1] = qkv[kbase + (2 * pp + 1) * 3 + 2];
        }
        __syncthreads();
        for (int jj = 0; jj < 64; ++jj) {
            int j = c * 64 + jj;
            float s = 0.0f;
            #pragma unroll
            for (int d = 0; d < 64; d += 4) {
                float4 kv = *(const float4*)&Ks[jj][d];
                s += q[d] * kv.x + q[d + 1] * kv.y + q[d + 2] * kv.z + q[d + 3] * kv.w;
            }
            bool valid = (j >= i) && (j <= i + WINSZ);
            if (valid) {
                float mn = fmaxf(mrun, s);
                float alpha = expf(mrun - mn);
                float p = expf(s - mn);
                lrun = lrun * alpha + p;
                #pragma unroll
                for (int d = 0; d < 64; d += 4) {
                    float4 vv = *(const float4*)&Vs[jj][d];
                    o[d]     = o[d]     * alpha + p * vv.x;
                    o[d + 1] = o[d + 1] * alpha + p * vv.y;
                    o[d + 2] = o[d + 2] * alpha + p * vv.z;
                    o[d + 3] = o[d + 3] * alpha + p * vv.w;
                }
                mrun = mn;
            }
        }
        __syncthreads();
    }
    float invl = 1.0f / lrun;
    size_t obase = ((size_t)(b * LSEQ + qtok)) * 1024 + (size_t)head * 64;
    #pragma unroll
    for (int d = 0; d < 64; ++d) {
        ushort_t hi, lo;
        split2(o[d] * invl, hi, lo);
        attn2[obase + d] = hi;
        attn2[obase + 512 + d] = lo;
    }
}

// ---------------- head + postprocess ------------------------------------------
__global__ __launch_bounds__(256)
void head_kernel(const float* __restrict__ hh, const float* __restrict__ head_w,
                 const float* __restrict__ head_b, float* __restrict__ out) {
    int wid = threadIdx.x >> 6, lane = threadIdx.x & 63;
    int t = blockIdx.x * 4 + wid;
    __shared__ float yv[4][32];
    const float* xr = hh + (size_t)t * 512;
    float xv[8];
    #pragma unroll
    for (int u = 0; u < 8; ++u) xv[u] = xr[u * 64 + lane];
    for (int j = 0; j < 31; ++j) {
        const float* wr = head_w + (size_t)j * 512;
        float p = 0.0f;
        #pragma unroll
        for (int u = 0; u < 8; ++u) p += xv[u] * wr[u * 64 + lane];
        #pragma unroll
        for (int off = 32; off > 0; off >>= 1) p += __shfl_down(p, off, 64);
        if (lane == 0) yv[wid][j] = p + head_b[j];
    }
    if (lane == 0) {
        float* y = yv[wid];
        float* op = out + (size_t)t * 40;
        int am = 0; float best = y[0];
        for (int j = 1; j < 11; ++j) if (y[j] > best) { best = y[j]; am = j; }
        float fc_reg = softplus_f(y[11]);
        op[0] = (am < 10) ? (float)(am + 1) : fc_reg;
        for (int j = 0; j < 11; ++j) op[1 + j] = y[j];
        op[12] = fc_reg;
        int am2 = 0; float best2 = y[12];
        for (int j = 1; j < 11; ++j) if (y[12 + j] > best2) { best2 = y[12 + j]; am2 = j; }
        float ec_reg = softplus_f(y[23]);
        op[13] = (am2 < 10) ? (float)(am2 + 1) : ec_reg;
        for (int j = 0; j < 11; ++j) op[14 + j] = y[12 + j];
        op[25] = ec_reg;
        float bm_log = y[24];
        op[26] = 1.0f / (1.0f + expf(-bm_log));
        float mi = fmaxf(y[25], fmaxf(y[26], y[27]));
        float e0 = expf(y[25] - mi), e1 = expf(y[26] - mi), e2 = expf(y[27] - mi);
        float si = e0 + e1 + e2;
        op[27] = e0 / si; op[28] = e1 / si; op[29] = e2 / si;
        float md = fmaxf(y[28], fmaxf(y[29], y[30]));
        float d0 = expf(y[28] - md), d1 = expf(y[29] - md), d2 = expf(y[30] - md);
        float sd = d0 + d1 + d2;
        op[30] = d0 / sd; op[31] = d1 / sd; op[32] = d2 / sd;
        op[33] = bm_log;
        op[34] = y[25]; op[35] = y[26]; op[36] = y[27];
        op[37] = y[28]; op[38] = y[29]; op[39] = y[30];
    }
}

// ---------------- launch -------------------------------------------------------
extern "C" void kernel_launch(void* const* d_in, const int* in_sizes, int n_in,
                              void* d_out, int out_size, void* d_ws, size_t ws_size,
                              hipStream_t stream) {
    const int*   x        = (const int*)d_in[0];
    const float* emb      = (const float*)d_in[1];
    const float* reg_w    = (const float*)d_in[2];
    const float* reg_b    = (const float*)d_in[3];
    const float* br_w     = (const float*)d_in[4];
    const float* br_b     = (const float*)d_in[5];
    const float* sh_w     = (const float*)d_in[6];
    const float* sh_b     = (const float*)d_in[7];
    const float* inst_w   = (const float*)d_in[8];
    const float* inst_b   = (const float*)d_in[9];
    const float* enc_ln_w = (const float*)d_in[10];
    const float* enc_ln_b = (const float*)d_in[11];
    const float* qkv_w    = (const float*)d_in[12];
    const float* out_w    = (const float*)d_in[13];
    const float* out_b    = (const float*)d_in[14];
    const float* w1_w     = (const float*)d_in[15];
    const float* w1_b     = (const float*)d_in[16];
    const float* w3_w     = (const float*)d_in[17];
    const float* w3_b     = (const float*)d_in[18];
    const float* w2_w     = (const float*)d_in[19];
    const float* w2_b     = (const float*)d_in[20];
    const float* n1_w     = (const float*)d_in[21];
    const float* n2_w     = (const float*)d_in[22];
    const float* hl_w     = (const float*)d_in[23];
    const float* hl_b     = (const float*)d_in[24];
    const float* head_w   = (const float*)d_in[25];
    const float* head_b   = (const float*)d_in[26];

    char* ws = (char*)d_ws;
    size_t off = 0;
    ushort_t* inst2 = (ushort_t*)(ws + off); off += (size_t)512 * 1536 * 2;
    ushort_t* qkv2  = (ushort_t*)(ws + off); off += (size_t)3 * 1536 * 1024 * 2;
    ushort_t* out2w = (ushort_t*)(ws + off); off += (size_t)3 * 512 * 1024 * 2;
    ushort_t* w1s   = (ushort_t*)(ws + off); off += (size_t)3 * DFFP * 1024 * 2;
    ushort_t* w3s   = (ushort_t*)(ws + off); off += (size_t)3 * DFFP * 1024 * 2;
    ushort_t* w2s   = (ushort_t*)(ws + off); off += (size_t)3 * 512 * (2 * KP2) * 2;
    float*    h     = (float*)(ws + off);    off += (size_t)T_TOK * 512 * 4;
    ushort_t* x2    = (ushort_t*)(ws + off); off += (size_t)T_TOK * 1024 * 2;   // also hh (fp32)
    ushort_t* attn2 = (ushort_t*)(ws + off); off += (size_t)T_TOK * 1024 * 2;
    float*    qkvb  = (float*)(ws + off);    off += (size_t)T_TOK * 1536 * 4;   // also U1
    ushort_t* cat2  = (ushort_t*)(ws + off); off += (size_t)T_TOK * (2 * KP2) * 2; // also g2
    float*    U1    = qkvb;
    ushort_t* g2    = cat2;
    float*    hh    = (float*)x2;

    // ---- weight splits (each launch; ws is re-poisoned) ----
    splitw_kernel<<<dim3(3, 512), 256, 0, stream>>>(inst_w, inst2, 512, 768, 768);
    splitw_kernel<<<dim3(2, 3 * 1536), 256, 0, stream>>>(qkv_w, qkv2, 3 * 1536, 512, 512);
    splitw_kernel<<<dim3(2, 3 * 512), 256, 0, stream>>>(out_w, out2w, 3 * 512, 512, 512);
    for (int l = 0; l < NLAYER; ++l) {
        splitw_kernel<<<dim3(2, DFFP), 256, 0, stream>>>(
            w1_w + (size_t)l * DFF * 512, w1s + (size_t)l * DFFP * 1024, DFF, 512, 512);
        splitw_kernel<<<dim3(2, DFFP), 256, 0, stream>>>(
            w3_w + (size_t)l * DFF * 512, w3s + (size_t)l * DFFP * 1024, DFF, 512, 512);
        splitw_kernel<<<dim3(6, 512), 256, 0, stream>>>(
            w2_w + (size_t)l * 512 * DFF, w2s + (size_t)l * 512 * (2 * KP2), 512, DFF, KP2);
    }

    // ---- encoder ----
    encode_kernel<<<T_TOK, 256, 0, stream>>>(x, emb, reg_w, reg_b, br_w, br_b,
                                             sh_w, sh_b, cat2);
    gemm3_kernel<<<dim3(4, 64), 256, 0, stream>>>(
        cat2, 1536, inst2, 1536, inst_b, 512, nullptr, nullptr, 0,
        h, 512, 768, 0);
    ln_silu_kernel<<<T_TOK, 256, 0, stream>>>(h, enc_ln_w, enc_ln_b, h);

    for (int l = 0; l < NLAYER; ++l) {
        rms_kernel<<<T_TOK, 256, 0, stream>>>(h, n1_w + l * 512, x2);
        gemm3_kernel<<<dim3(12, 64), 256, 0, stream>>>(
            x2, 1024, qkv2 + (size_t)l * 1536 * 1024, 1024, nullptr, 0,
            nullptr, nullptr, 0, qkvb, 1536, 512, 0);
        {
            dim3 g(NBLK, NHEAD, BATCH);
            attn_kernel<<<g, 128, 0, stream>>>(qkvb, attn2);
        }
        gemm3_kernel<<<dim3(4, 64), 256, 0, stream>>>(
            attn2, 1024, out2w + (size_t)l * 512 * 1024, 1024, out_b + l * 512, 512,
            h, nullptr, 0, h, 512, 512, 0);
        rms_kernel<<<T_TOK, 256, 0, stream>>>(h, n2_w + l * 512, x2);
        gemm3_kernel<<<dim3(11, 64), 256, 0, stream>>>(
            x2, 1024, w1s + (size_t)l * DFFP * 1024, 1024, w1_b + l * DFF, DFF,
            nullptr, nullptr, 0, U1, DFFP, 512, 1);
        gemm3_kernel<<<dim3(11, 64), 256, 0, stream>>>(
            x2, 1024, w3s + (size_t)l * DFFP * 1024, 1024, w3_b + l * DFF, DFF,
            nullptr, U1, DFFP, g2, 2 * KP2, 512, 2);
        gemm3_kernel<<<dim3(4, 64), 256, 0, stream>>>(
            g2, 2 * KP2, w2s + (size_t)l * 512 * (2 * KP2), 2 * KP2, w2_b + l * 512, 512,
            h, nullptr, 0, h, 512, KP2, 0);
    }

    ln_silu_kernel<<<T_TOK, 256, 0, stream>>>(h, hl_w, hl_b, hh);
    head_kernel<<<T_TOK / 4, 256, 0, stream>>>(hh, head_w, head_b, (float*)d_out);
}

// Round 3
// 1820.831 us; speedup vs baseline: 3.1184x; 1.3336x over previous
//
#include <hip/hip_runtime.h>
#include <hip/hip_bf16.h>
#include <math.h>

#define T_TOK 8192
#define DMODEL 512
#define NHEAD 8
#define TEDIM 192
#define DFF 1365
#define DFFP 1408
#define KP2 1376
#define NLAYER 3
#define WINSZ 128
#define NBLK 16
#define LSEQ 2048
#define BATCH 4

typedef unsigned short ushort_t;
typedef __bf16 bf16x8 __attribute__((ext_vector_type(8)));
typedef float f32x4 __attribute__((ext_vector_type(4)));

__device__ __forceinline__ float silu_f(float x) { return x / (1.0f + expf(-x)); }
__device__ __forceinline__ float softplus_f(float x) {
    return (x > 20.0f) ? x : log1pf(expf(x));
}

__device__ __forceinline__ ushort_t f2u(float x) {
    __hip_bfloat16 b = __float2bfloat16(x);
    return *reinterpret_cast<ushort_t*>(&b);
}
__device__ __forceinline__ float u2f(ushort_t u) {
    __hip_bfloat16 b = *reinterpret_cast<__hip_bfloat16*>(&u);
    return __bfloat162float(b);
}
__device__ __forceinline__ void split2(float x, ushort_t& hi, ushort_t& lo) {
    hi = f2u(x);
    lo = f2u(x - u2f(hi));
}

__device__ __forceinline__ void gl_lds16(const ushort_t* g, ushort_t* l) {
    __builtin_amdgcn_global_load_lds(
        (const __attribute__((address_space(1))) unsigned int*)g,
        (__attribute__((address_space(3))) unsigned int*)l, 16, 0, 0);
}

// ---------------- RoPE table: cos/sin[2048][32] -------------------------------
__global__ __launch_bounds__(256)
void rope_kernel(float* __restrict__ ct, float* __restrict__ st) {
    int idx = blockIdx.x * 256 + threadIdx.x;   // 65536
    int tok = idx >> 5, p = idx & 31;
    float invf = powf(10000.0f, -(float)p * (1.0f / 32.0f));
    float sn, cs;
    sincosf((float)tok * invf, &sn, &cs);
    ct[idx] = cs;
    st[idx] = sn;
}

// ---------------- weight split: W[N][K] fp32 -> W2[Npad][2*Kp] bf16 hi|lo -----
__global__ __launch_bounds__(256)
void splitw_kernel(const float* __restrict__ W, ushort_t* __restrict__ W2,
                   int N, int K, int Kp) {
    int n = blockIdx.y;
    int k = blockIdx.x * 256 + threadIdx.x;
    if (k >= Kp) return;
    float v = (n < N && k < K) ? W[(size_t)n * K + k] : 0.0f;
    ushort_t hi, lo;
    split2(v, hi, lo);
    W2[(size_t)n * (2 * Kp) + k] = hi;
    W2[(size_t)n * (2 * Kp) + Kp + k] = lo;
}

// qkv weights: permute rows h*192+dk*3+which -> which*512+h*64+dk
__global__ __launch_bounds__(256)
void splitw_qkv_kernel(const float* __restrict__ W, ushort_t* __restrict__ W2) {
    int l = blockIdx.z;
    int rr = blockIdx.y;                       // 0..1535
    int k = blockIdx.x * 256 + threadIdx.x;    // 0..511
    int h = rr / 192, rem = rr % 192;
    int dk = rem / 3, which = rem % 3;
    int rp = which * 512 + h * 64 + dk;
    float v = W[((size_t)l * 1536 + rr) * 512 + k];
    ushort_t hi, lo;
    split2(v, hi, lo);
    W2[((size_t)l * 1536 + rp) * 1024 + k] = hi;
    W2[((size_t)l * 1536 + rp) * 1024 + 512 + k] = lo;
}

// ---------------- encode -> silu(cat) split bf16 (T x 1536) -------------------
__global__ __launch_bounds__(256)
void encode_kernel(const int* __restrict__ x, const float* __restrict__ emb,
                   const float* __restrict__ reg_w, const float* __restrict__ reg_b,
                   const float* __restrict__ br_w, const float* __restrict__ br_b,
                   const float* __restrict__ sh_w, const float* __restrict__ sh_b,
                   ushort_t* __restrict__ cat2) {
    int tok = blockIdx.x;
    int tid = threadIdx.x;
    __shared__ float xr[288];
    const int* xp = x + (size_t)tok * 289;
    for (int i = tid; i < 288; i += 256) xr[i] = (float)xp[1 + i];
    __syncthreads();
    int tokid = xp[0];
    for (int o = tid; o < 768; o += 256) {
        float v;
        if (o < 192) {
            v = emb[(size_t)tokid * TEDIM + o];
        } else if (o < 384) {
            int j = o - 192;
            float s = reg_b[j];
            const float* wr = reg_w + (size_t)j * 64;
            #pragma unroll 8
            for (int k = 0; k < 64; ++k) s += xr[k] * wr[k];
            v = s;
        } else if (o < 576) {
            int j = o - 384;
            float s = br_b[j];
            const float* wr = br_w + (size_t)j * 32;
            #pragma unroll 8
            for (int k = 0; k < 32; ++k) s += xr[256 + k] * wr[k];
            v = s;
        } else {
            int j = o - 576;
            float s = sh_b[j];
            const float* wr = sh_w + (size_t)j * 192;
            #pragma unroll 8
            for (int k = 0; k < 192; ++k) s += xr[64 + k] * wr[k];
            v = s;
        }
        ushort_t hi, lo;
        split2(silu_f(v), hi, lo);
        cat2[(size_t)tok * 1536 + o] = hi;
        cat2[(size_t)tok * 1536 + 768 + o] = lo;
    }
}

// ---------------- bf16x3 MFMA GEMM (mode 0: fp32 out + bias/res) --------------
__global__ __launch_bounds__(256)
void gemm3_kernel(const ushort_t* __restrict__ A2, int rsA,
                  const ushort_t* __restrict__ B2, int rsB,
                  const float* __restrict__ bias,
                  const float* __restrict__ res,
                  float* __restrict__ Cf, int rsC, int Kp) {
    __shared__ __align__(16) ushort_t lds[4 * 4096];
    const int tid = threadIdx.x;
    const int bm = blockIdx.y * 128, bn = blockIdx.x * 128;
    const int w = tid >> 6, l = tid & 63;
    const int wm = (w & 1) * 64, wn = (w >> 1) * 64;

    f32x4 acc[4][4];
    #pragma unroll
    for (int i = 0; i < 4; ++i)
        #pragma unroll
        for (int j = 0; j < 4; ++j) acc[i][j] = (f32x4){0.f, 0.f, 0.f, 0.f};

    const int r0 = tid >> 2, k8 = (tid & 3) * 8;
    const ushort_t* gA0 = A2 + (size_t)(bm + r0) * rsA + k8;
    const ushort_t* gA1 = A2 + (size_t)(bm + 64 + r0) * rsA + k8;
    const ushort_t* gB0 = B2 + (size_t)(bn + r0) * rsB + k8;
    const ushort_t* gB1 = B2 + (size_t)(bn + 64 + r0) * rsB + k8;
    ushort_t* l0 = lds + tid * 8;
    ushort_t* l1 = lds + 2048 + tid * 8;

    const int fr = l & 15, fk = (l >> 4) * 8;

    for (int kt = 0; kt < Kp; kt += 32) {
        gl_lds16(gA0 + kt, l0);
        gl_lds16(gA1 + kt, l1);
        gl_lds16(gA0 + kt + Kp, l0 + 4096);
        gl_lds16(gA1 + kt + Kp, l1 + 4096);
        gl_lds16(gB0 + kt, l0 + 8192);
        gl_lds16(gB1 + kt, l1 + 8192);
        gl_lds16(gB0 + kt + Kp, l0 + 12288);
        gl_lds16(gB1 + kt + Kp, l1 + 12288);
        __syncthreads();

        bf16x8 ahi[4], alo[4], bhi[4], blo[4];
        #pragma unroll
        for (int i = 0; i < 4; ++i) {
            int ra = (wm + i * 16 + fr) * 32 + fk;
            int rb = (wn + i * 16 + fr) * 32 + fk;
            ahi[i] = *(const bf16x8*)&lds[ra];
            alo[i] = *(const bf16x8*)&lds[4096 + ra];
            bhi[i] = *(const bf16x8*)&lds[8192 + rb];
            blo[i] = *(const bf16x8*)&lds[12288 + rb];
        }
        #pragma unroll
        for (int i = 0; i < 4; ++i)
            #pragma unroll
            for (int j = 0; j < 4; ++j) {
                acc[i][j] = __builtin_amdgcn_mfma_f32_16x16x32_bf16(ahi[i], bhi[j], acc[i][j], 0, 0, 0);
                acc[i][j] = __builtin_amdgcn_mfma_f32_16x16x32_bf16(ahi[i], blo[j], acc[i][j], 0, 0, 0);
                acc[i][j] = __builtin_amdgcn_mfma_f32_16x16x32_bf16(alo[i], bhi[j], acc[i][j], 0, 0, 0);
            }
        __syncthreads();
    }

    const int er = (l >> 4) * 4, ec = l & 15;
    #pragma unroll
    for (int i = 0; i < 4; ++i)
        #pragma unroll
        for (int j = 0; j < 4; ++j)
            #pragma unroll
            for (int r = 0; r < 4; ++r) {
                int gm = bm + wm + i * 16 + er + r;
                int gn = bn + wn + j * 16 + ec;
                float v = acc[i][j][r];
                if (bias) v += bias[gn];
                if (res) v += res[(size_t)gm * rsC + gn];
                Cf[(size_t)gm * rsC + gn] = v;
            }
}

// ---------------- fused GLU GEMM: g = silu(x@W1^T+b1)*(x@W3^T+b3) -> split ----
__global__ __launch_bounds__(256)
void gemm_glu3(const ushort_t* __restrict__ A2,
               const ushort_t* __restrict__ W1, const ushort_t* __restrict__ W3,
               const float* __restrict__ b1, const float* __restrict__ b3,
               ushort_t* __restrict__ C2) {
    __shared__ __align__(16) ushort_t lds[6 * 4096];  // Ahi Alo W1hi W1lo W3hi W3lo
    const int tid = threadIdx.x;
    const int bm = blockIdx.y * 128, bn = blockIdx.x * 128;
    const int w = tid >> 6, l = tid & 63;
    const int wm = (w & 1) * 64, wn = (w >> 1) * 64;
    const int Kp = 512;

    f32x4 acc1[4][4], acc3[4][4];
    #pragma unroll
    for (int i = 0; i < 4; ++i)
        #pragma unroll
        for (int j = 0; j < 4; ++j) {
            acc1[i][j] = (f32x4){0.f, 0.f, 0.f, 0.f};
            acc3[i][j] = (f32x4){0.f, 0.f, 0.f, 0.f};
        }

    const int r0 = tid >> 2, k8 = (tid & 3) * 8;
    const ushort_t* gA0 = A2 + (size_t)(bm + r0) * 1024 + k8;
    const ushort_t* gA1 = A2 + (size_t)(bm + 64 + r0) * 1024 + k8;
    const ushort_t* g10 = W1 + (size_t)(bn + r0) * 1024 + k8;
    const ushort_t* g11 = W1 + (size_t)(bn + 64 + r0) * 1024 + k8;
    const ushort_t* g30 = W3 + (size_t)(bn + r0) * 1024 + k8;
    const ushort_t* g31 = W3 + (size_t)(bn + 64 + r0) * 1024 + k8;
    ushort_t* l0 = lds + tid * 8;
    ushort_t* l1 = lds + 2048 + tid * 8;

    const int fr = l & 15, fk = (l >> 4) * 8;

    for (int kt = 0; kt < Kp; kt += 32) {
        gl_lds16(gA0 + kt, l0);
        gl_lds16(gA1 + kt, l1);
        gl_lds16(gA0 + kt + Kp, l0 + 4096);
        gl_lds16(gA1 + kt + Kp, l1 + 4096);
        gl_lds16(g10 + kt, l0 + 8192);
        gl_lds16(g11 + kt, l1 + 8192);
        gl_lds16(g10 + kt + Kp, l0 + 12288);
        gl_lds16(g11 + kt + Kp, l1 + 12288);
        gl_lds16(g30 + kt, l0 + 16384);
        gl_lds16(g31 + kt, l1 + 16384);
        gl_lds16(g30 + kt + Kp, l0 + 20480);
        gl_lds16(g31 + kt + Kp, l1 + 20480);
        __syncthreads();

        bf16x8 ahi[4], alo[4];
        #pragma unroll
        for (int i = 0; i < 4; ++i) {
            int ra = (wm + i * 16 + fr) * 32 + fk;
            ahi[i] = *(const bf16x8*)&lds[ra];
            alo[i] = *(const bf16x8*)&lds[4096 + ra];
        }
        #pragma unroll
        for (int j = 0; j < 4; ++j) {
            int rb = (wn + j * 16 + fr) * 32 + fk;
            bf16x8 w1h = *(const bf16x8*)&lds[8192 + rb];
            bf16x8 w1l = *(const bf16x8*)&lds[12288 + rb];
            bf16x8 w3h = *(const bf16x8*)&lds[16384 + rb];
            bf16x8 w3l = *(const bf16x8*)&lds[20480 + rb];
            #pragma unroll
            for (int i = 0; i < 4; ++i) {
                acc1[i][j] = __builtin_amdgcn_mfma_f32_16x16x32_bf16(ahi[i], w1h, acc1[i][j], 0, 0, 0);
                acc1[i][j] = __builtin_amdgcn_mfma_f32_16x16x32_bf16(ahi[i], w1l, acc1[i][j], 0, 0, 0);
                acc1[i][j] = __builtin_amdgcn_mfma_f32_16x16x32_bf16(alo[i], w1h, acc1[i][j], 0, 0, 0);
                acc3[i][j] = __builtin_amdgcn_mfma_f32_16x16x32_bf16(ahi[i], w3h, acc3[i][j], 0, 0, 0);
                acc3[i][j] = __builtin_amdgcn_mfma_f32_16x16x32_bf16(ahi[i], w3l, acc3[i][j], 0, 0, 0);
                acc3[i][j] = __builtin_amdgcn_mfma_f32_16x16x32_bf16(alo[i], w3h, acc3[i][j], 0, 0, 0);
            }
        }
        __syncthreads();
    }

    const int er = (l >> 4) * 4, ec = l & 15;
    #pragma unroll
    for (int i = 0; i < 4; ++i)
        #pragma unroll
        for (int j = 0; j < 4; ++j)
            #pragma unroll
            for (int r = 0; r < 4; ++r) {
                int gm = bm + wm + i * 16 + er + r;
                int gn = bn + wn + j * 16 + ec;
                if (gn < KP2) {
                    float u1 = acc1[i][j][r], u3 = acc3[i][j][r];
                    if (gn < DFF) { u1 += b1[gn]; u3 += b3[gn]; }
                    float g = silu_f(u1) * u3;
                    ushort_t hi, lo;
                    split2(g, hi, lo);
                    C2[(size_t)gm * (2 * KP2) + gn] = hi;
                    C2[(size_t)gm * (2 * KP2) + KP2 + gn] = lo;
                }
            }
}

// ---------------- per-token reductions ----------------------------------------
__device__ __forceinline__ float block_reduce_sum256(float v, float* red) {
    #pragma unroll
    for (int off = 32; off > 0; off >>= 1) v += __shfl_down(v, off, 64);
    int lane = threadIdx.x & 63, wid = threadIdx.x >> 6;
    if (lane == 0) red[wid] = v;
    __syncthreads();
    float s = red[0] + red[1] + red[2] + red[3];
    __syncthreads();
    return s;
}

__global__ __launch_bounds__(256)
void rms_kernel(const float* __restrict__ h, const float* __restrict__ w,
                ushort_t* __restrict__ out2) {
    __shared__ float red[4];
    int t = blockIdx.x, tid = threadIdx.x;
    float x0 = h[(size_t)t * 512 + tid];
    float x1 = h[(size_t)t * 512 + 256 + tid];
    float ss = block_reduce_sum256(x0 * x0 + x1 * x1, red);
    float inv = rsqrtf(ss * (1.0f / 512.0f) + 1.1920929e-07f);
    ushort_t hi, lo;
    split2(x0 * inv * w[tid], hi, lo);
    out2[(size_t)t * 1024 + tid] = hi;
    out2[(size_t)t * 1024 + 512 + tid] = lo;
    split2(x1 * inv * w[256 + tid], hi, lo);
    out2[(size_t)t * 1024 + 256 + tid] = hi;
    out2[(size_t)t * 1024 + 768 + tid] = lo;
}

__global__ __launch_bounds__(256)
void ln_silu_kernel(const float* __restrict__ h, const float* __restrict__ w,
                    const float* __restrict__ b, float* __restrict__ out) {
    __shared__ float red[4];
    int t = blockIdx.x, tid = threadIdx.x;
    float x0 = h[(size_t)t * 512 + tid];
    float x1 = h[(size_t)t * 512 + 256 + tid];
    float m = block_reduce_sum256(x0 + x1, red) * (1.0f / 512.0f);
    float d0 = x0 - m, d1 = x1 - m;
    float var = block_reduce_sum256(d0 * d0 + d1 * d1, red) * (1.0f / 512.0f);
    float inv = rsqrtf(var + 1e-5f);
    out[(size_t)t * 512 + tid] = silu_f(d0 * inv * w[tid] + b[tid]);
    out[(size_t)t * 512 + 256 + tid] = silu_f(d1 * inv * w[256 + tid] + b[256 + tid]);
}

// ---------------- local attention v2 ------------------------------------------
// qkv layout: [tok][which*512 + h*64 + d] (permuted weights).
// 256 thr: thread = (query qi = t>>1, half hf = t&1, 32 dims each).
__global__ __launch_bounds__(256)
void attn_kernel(const float* __restrict__ qkv, const float* __restrict__ ct,
                 const float* __restrict__ st, ushort_t* __restrict__ attn2) {
    int nb = blockIdx.x;
    int head = blockIdx.y;
    int b = blockIdx.z;
    int tid = threadIdx.x;
    int qi = tid >> 1, hf = tid & 1;
    __shared__ __align__(16) float Ks[64][64];
    __shared__ __align__(16) float Vs[64][64];

    int qtok = nb * WINSZ + qi;
    const float* qp = qkv + ((size_t)(b * LSEQ + qtok)) * 1536 + head * 64 + hf * 32;
    float q[32];
    #pragma unroll
    for (int d = 0; d < 32; d += 4) *(float4*)&q[d] = *(const float4*)&qp[d];
    {
        const float* cp = ct + qtok * 32 + hf * 16;
        const float* sp = st + qtok * 32 + hf * 16;
        #pragma unroll
        for (int p = 0; p < 16; ++p) {
            float cs = cp[p], sn = sp[p];
            float x1 = q[2 * p], x2 = q[2 * p + 1];
            q[2 * p] = (x1 * cs - x2 * sn) * 0.125f;
            q[2 * p + 1] = (x1 * sn + x2 * cs) * 0.125f;
        }
    }

    float o[32];
    #pragma unroll
    for (int d = 0; d < 32; ++d) o[d] = 0.0f;
    float m = -1e30f, lsum = 0.0f;

    int c0 = (nb == 0) ? 2 : 0;
    for (int c = c0; c < 4; ++c) {
        int r = tid >> 2, qd = tid & 3;
        int ktok = nb * WINSZ - WINSZ + c * 64 + r;
        const float* kb = qkv + ((size_t)(b * LSEQ + ktok)) * 1536 + 512 + head * 64 + qd * 16;
        const float* vb = kb + 512;
        float kk[16], vv[16];
        #pragma unroll
        for (int d = 0; d < 16; d += 4) {
            *(float4*)&kk[d] = *(const float4*)&kb[d];
            *(float4*)&vv[d] = *(const float4*)&vb[d];
        }
        {
            const float* cp = ct + ktok * 32 + qd * 8;
            const float* sp = st + ktok * 32 + qd * 8;
            #pragma unroll
            for (int p = 0; p < 8; ++p) {
                float cs = cp[p], sn = sp[p];
                float x1 = kk[2 * p], x2 = kk[2 * p + 1];
                kk[2 * p] = x1 * cs - x2 * sn;
                kk[2 * p + 1] = x1 * sn + x2 * cs;
            }
        }
        #pragma unroll
        for (int d = 0; d < 16; d += 4) {
            *(float4*)&Ks[r][qd * 16 + d] = *(const float4*)&kk[d];
            *(float4*)&Vs[r][qd * 16 + d] = *(const float4*)&vv[d];
        }
        __syncthreads();

        for (int jj = 0; jj < 64; ++jj) {
            int j = c * 64 + jj;
            float s32 = 0.0f;
            #pragma unroll
            for (int d = 0; d < 32; d += 4) {
                float4 kv = *(const float4*)&Ks[jj][hf * 32 + d];
                s32 += q[d] * kv.x + q[d + 1] * kv.y + q[d + 2] * kv.z + q[d + 3] * kv.w;
            }
            float s = s32 + __shfl_xor(s32, 1, 64);
            bool valid = (j >= qi) && (j <= qi + WINSZ);
            if (valid) {
                if (s > m) {
                    float al = __expf(m - s);
                    lsum *= al;
                    #pragma unroll
                    for (int d = 0; d < 32; ++d) o[d] *= al;
                    m = s;
                }
                float p = __expf(s - m);
                lsum += p;
                #pragma unroll
                for (int d = 0; d < 32; d += 4) {
                    float4 vv4 = *(const float4*)&Vs[jj][hf * 32 + d];
                    o[d]     += p * vv4.x;
                    o[d + 1] += p * vv4.y;
                    o[d + 2] += p * vv4.z;
                    o[d + 3] += p * vv4.w;
                }
            }
        }
        __syncthreads();
    }
    float invl = 1.0f / lsum;
    size_t ob = ((size_t)(b * LSEQ + qtok)) * 1024 + head * 64 + hf * 32;
    #pragma unroll
    for (int d = 0; d < 32; d += 4) {
        ushort4 hv, lv;
        ushort_t hi, lo;
        split2(o[d] * invl, hi, lo);     hv.x = hi; lv.x = lo;
        split2(o[d + 1] * invl, hi, lo); hv.y = hi; lv.y = lo;
        split2(o[d + 2] * invl, hi, lo); hv.z = hi; lv.z = lo;
        split2(o[d + 3] * invl, hi, lo); hv.w = hi; lv.w = lo;
        *(ushort4*)&attn2[ob + d] = hv;
        *(ushort4*)&attn2[ob + 512 + d] = lv;
    }
}

// ---------------- head + postprocess ------------------------------------------
__global__ __launch_bounds__(256)
void head_kernel(const float* __restrict__ hh, const float* __restrict__ head_w,
                 const float* __restrict__ head_b, float* __restrict__ out) {
    int wid = threadIdx.x >> 6, lane = threadIdx.x & 63;
    int t = blockIdx.x * 4 + wid;
    __shared__ float yv[4][32];
    const float* xr = hh + (size_t)t * 512;
    float xv[8];
    #pragma unroll
    for (int u = 0; u < 8; ++u) xv[u] = xr[u * 64 + lane];
    for (int j = 0; j < 31; ++j) {
        const float* wr = head_w + (size_t)j * 512;
        float p = 0.0f;
        #pragma unroll
        for (int u = 0; u < 8; ++u) p += xv[u] * wr[u * 64 + lane];
        #pragma unroll
        for (int off = 32; off > 0; off >>= 1) p += __shfl_down(p, off, 64);
        if (lane == 0) yv[wid][j] = p + head_b[j];
    }
    if (lane == 0) {
        float* y = yv[wid];
        float* op = out + (size_t)t * 40;
        int am = 0; float best = y[0];
        for (int j = 1; j < 11; ++j) if (y[j] > best) { best = y[j]; am = j; }
        float fc_reg = softplus_f(y[11]);
        op[0] = (am < 10) ? (float)(am + 1) : fc_reg;
        for (int j = 0; j < 11; ++j) op[1 + j] = y[j];
        op[12] = fc_reg;
        int am2 = 0; float best2 = y[12];
        for (int j = 1; j < 11; ++j) if (y[12 + j] > best2) { best2 = y[12 + j]; am2 = j; }
        float ec_reg = softplus_f(y[23]);
        op[13] = (am2 < 10) ? (float)(am2 + 1) : ec_reg;
        for (int j = 0; j < 11; ++j) op[14 + j] = y[12 + j];
        op[25] = ec_reg;
        float bm_log = y[24];
        op[26] = 1.0f / (1.0f + expf(-bm_log));
        float mi = fmaxf(y[25], fmaxf(y[26], y[27]));
        float e0 = expf(y[25] - mi), e1 = expf(y[26] - mi), e2 = expf(y[27] - mi);
        float si = e0 + e1 + e2;
        op[27] = e0 / si; op[28] = e1 / si; op[29] = e2 / si;
        float md = fmaxf(y[28], fmaxf(y[29], y[30]));
        float d0 = expf(y[28] - md), d1 = expf(y[29] - md), d2 = expf(y[30] - md);
        float sd = d0 + d1 + d2;
        op[30] = d0 / sd; op[31] = d1 / sd; op[32] = d2 / sd;
        op[33] = bm_log;
        op[34] = y[25]; op[35] = y[26]; op[36] = y[27];
        op[37] = y[28]; op[38] = y[29]; op[39] = y[30];
    }
}

// ---------------- launch -------------------------------------------------------
extern "C" void kernel_launch(void* const* d_in, const int* in_sizes, int n_in,
                              void* d_out, int out_size, void* d_ws, size_t ws_size,
                              hipStream_t stream) {
    const int*   x        = (const int*)d_in[0];
    const float* emb      = (const float*)d_in[1];
    const float* reg_w    = (const float*)d_in[2];
    const float* reg_b    = (const float*)d_in[3];
    const float* br_w     = (const float*)d_in[4];
    const float* br_b     = (const float*)d_in[5];
    const float* sh_w     = (const float*)d_in[6];
    const float* sh_b     = (const float*)d_in[7];
    const float* inst_w   = (const float*)d_in[8];
    const float* inst_b   = (const float*)d_in[9];
    const float* enc_ln_w = (const float*)d_in[10];
    const float* enc_ln_b = (const float*)d_in[11];
    const float* qkv_w    = (const float*)d_in[12];
    const float* out_w    = (const float*)d_in[13];
    const float* out_b    = (const float*)d_in[14];
    const float* w1_w     = (const float*)d_in[15];
    const float* w1_b     = (const float*)d_in[16];
    const float* w3_w     = (const float*)d_in[17];
    const float* w3_b     = (const float*)d_in[18];
    const float* w2_w     = (const float*)d_in[19];
    const float* w2_b     = (const float*)d_in[20];
    const float* n1_w     = (const float*)d_in[21];
    const float* n2_w     = (const float*)d_in[22];
    const float* hl_w     = (const float*)d_in[23];
    const float* hl_b     = (const float*)d_in[24];
    const float* head_w   = (const float*)d_in[25];
    const float* head_b   = (const float*)d_in[26];

    char* ws = (char*)d_ws;
    size_t off = 0;
    ushort_t* inst2 = (ushort_t*)(ws + off); off += (size_t)512 * 1536 * 2;
    ushort_t* qkv2  = (ushort_t*)(ws + off); off += (size_t)3 * 1536 * 1024 * 2;
    ushort_t* out2w = (ushort_t*)(ws + off); off += (size_t)3 * 512 * 1024 * 2;
    ushort_t* w1s   = (ushort_t*)(ws + off); off += (size_t)3 * DFFP * 1024 * 2;
    ushort_t* w3s   = (ushort_t*)(ws + off); off += (size_t)3 * DFFP * 1024 * 2;
    ushort_t* w2s   = (ushort_t*)(ws + off); off += (size_t)3 * 512 * (2 * KP2) * 2;
    float*    ct    = (float*)(ws + off);    off += (size_t)LSEQ * 32 * 4;
    float*    st    = (float*)(ws + off);    off += (size_t)LSEQ * 32 * 4;
    float*    h     = (float*)(ws + off);    off += (size_t)T_TOK * 512 * 4;
    ushort_t* x2    = (ushort_t*)(ws + off); off += (size_t)T_TOK * 1024 * 2;
    ushort_t* attn2 = (ushort_t*)(ws + off); off += (size_t)T_TOK * 1024 * 2;
    float*    qkvb  = (float*)(ws + off);    off += (size_t)T_TOK * 1536 * 4;
    ushort_t* cat2  = (ushort_t*)(ws + off); off += (size_t)T_TOK * (2 * KP2) * 2;
    ushort_t* g2    = cat2;
    float*    hh    = (float*)x2;

    rope_kernel<<<256, 256, 0, stream>>>(ct, st);
    splitw_kernel<<<dim3(3, 512), 256, 0, stream>>>(inst_w, inst2, 512, 768, 768);
    splitw_qkv_kernel<<<dim3(2, 1536, 3), 256, 0, stream>>>(qkv_w, qkv2);
    splitw_kernel<<<dim3(2, 3 * 512), 256, 0, stream>>>(out_w, out2w, 3 * 512, 512, 512);
    for (int l = 0; l < NLAYER; ++l) {
        splitw_kernel<<<dim3(2, DFFP), 256, 0, stream>>>(
            w1_w + (size_t)l * DFF * 512, w1s + (size_t)l * DFFP * 1024, DFF, 512, 512);
        splitw_kernel<<<dim3(2, DFFP), 256, 0, stream>>>(
            w3_w + (size_t)l * DFF * 512, w3s + (size_t)l * DFFP * 1024, DFF, 512, 512);
        splitw_kernel<<<dim3(6, 512), 256, 0, stream>>>(
            w2_w + (size_t)l * 512 * DFF, w2s + (size_t)l * 512 * (2 * KP2), 512, DFF, KP2);
    }

    encode_kernel<<<T_TOK, 256, 0, stream>>>(x, emb, reg_w, reg_b, br_w, br_b,
                                             sh_w, sh_b, cat2);
    gemm3_kernel<<<dim3(4, 64), 256, 0, stream>>>(
        cat2, 1536, inst2, 1536, inst_b, nullptr, h, 512, 768);
    ln_silu_kernel<<<T_TOK, 256, 0, stream>>>(h, enc_ln_w, enc_ln_b, h);

    for (int l = 0; l < NLAYER; ++l) {
        rms_kernel<<<T_TOK, 256, 0, stream>>>(h, n1_w + l * 512, x2);
        gemm3_kernel<<<dim3(12, 64), 256, 0, stream>>>(
            x2, 1024, qkv2 + (size_t)l * 1536 * 1024, 1024, nullptr, nullptr,
            qkvb, 1536, 512);
        {
            dim3 g(NBLK, NHEAD, BATCH);
            attn_kernel<<<g, 256, 0, stream>>>(qkvb, ct, st, attn2);
        }
        gemm3_kernel<<<dim3(4, 64), 256, 0, stream>>>(
            attn2, 1024, out2w + (size_t)l * 512 * 1024, 1024, out_b + l * 512,
            h, h, 512, 512);
        rms_kernel<<<T_TOK, 256, 0, stream>>>(h, n2_w + l * 512, x2);
        gemm_glu3<<<dim3(11, 64), 256, 0, stream>>>(
            x2, w1s + (size_t)l * DFFP * 1024, w3s + (size_t)l * DFFP * 1024,
            w1_b + l * DFF, w3_b + l * DFF, g2);
        gemm3_kernel<<<dim3(4, 64), 256, 0, stream>>>(
            g2, 2 * KP2, w2s + (size_t)l * 512 * (2 * KP2), 2 * KP2, w2_b + l * 512,
            h, h, 512, KP2);
    }

    ln_silu_kernel<<<T_TOK, 256, 0, stream>>>(h, hl_w, hl_b, hh);
    head_kernel<<<T_TOK / 4, 256, 0, stream>>>(hh, head_w, head_b, (float*)d_out);
}

// Round 4
// 1612.070 us; speedup vs baseline: 3.5223x; 1.1295x over previous
//
#include <hip/hip_runtime.h>
#include <hip/hip_bf16.h>
#include <math.h>

#define T_TOK 8192
#define DMODEL 512
#define NHEAD 8
#define TEDIM 192
#define DFF 1365
#define DFFP 1408
#define KP2 1376
#define NLAYER 3
#define WINSZ 128
#define NBLK 16
#define LSEQ 2048
#define BATCH 4

typedef unsigned short ushort_t;
typedef __bf16 bf16x8 __attribute__((ext_vector_type(8)));
typedef float f32x4 __attribute__((ext_vector_type(4)));

__device__ __forceinline__ float silu_f(float x) { return x / (1.0f + expf(-x)); }
__device__ __forceinline__ float softplus_f(float x) {
    return (x > 20.0f) ? x : log1pf(expf(x));
}

__device__ __forceinline__ ushort_t f2u(float x) {
    __hip_bfloat16 b = __float2bfloat16(x);
    return *reinterpret_cast<ushort_t*>(&b);
}
__device__ __forceinline__ float u2f(ushort_t u) {
    __hip_bfloat16 b = *reinterpret_cast<__hip_bfloat16*>(&u);
    return __bfloat162float(b);
}
__device__ __forceinline__ void split2(float x, ushort_t& hi, ushort_t& lo) {
    hi = f2u(x);
    lo = f2u(x - u2f(hi));
}

__device__ __forceinline__ void gl_lds16(const ushort_t* g, ushort_t* l) {
    __builtin_amdgcn_global_load_lds(
        (const __attribute__((address_space(1))) unsigned int*)g,
        (__attribute__((address_space(3))) unsigned int*)l, 16, 0, 0);
}

// ---------------- RoPE table: cos/sin[2048][32] -------------------------------
__global__ __launch_bounds__(256)
void rope_kernel(float* __restrict__ ct, float* __restrict__ st) {
    int idx = blockIdx.x * 256 + threadIdx.x;
    int tok = idx >> 5, p = idx & 31;
    float invf = powf(10000.0f, -(float)p * (1.0f / 32.0f));
    float sn, cs;
    sincosf((float)tok * invf, &sn, &cs);
    ct[idx] = cs;
    st[idx] = sn;
}

// ---------------- weight split: W[N][K] fp32 -> W2[Npad][2*Kp] bf16 hi|lo -----
__global__ __launch_bounds__(256)
void splitw_kernel(const float* __restrict__ W, ushort_t* __restrict__ W2,
                   int N, int K, int Kp) {
    int n = blockIdx.y;
    int k = blockIdx.x * 256 + threadIdx.x;
    if (k >= Kp) return;
    float v = (n < N && k < K) ? W[(size_t)n * K + k] : 0.0f;
    ushort_t hi, lo;
    split2(v, hi, lo);
    W2[(size_t)n * (2 * Kp) + k] = hi;
    W2[(size_t)n * (2 * Kp) + Kp + k] = lo;
}

// qkv weights: permute rows h*192+dk*3+which -> which*512+h*64+dk
__global__ __launch_bounds__(256)
void splitw_qkv_kernel(const float* __restrict__ W, ushort_t* __restrict__ W2) {
    int l = blockIdx.z;
    int rr = blockIdx.y;
    int k = blockIdx.x * 256 + threadIdx.x;
    int h = rr / 192, rem = rr % 192;
    int dk = rem / 3, which = rem % 3;
    int rp = which * 512 + h * 64 + dk;
    float v = W[((size_t)l * 1536 + rr) * 512 + k];
    ushort_t hi, lo;
    split2(v, hi, lo);
    W2[((size_t)l * 1536 + rp) * 1024 + k] = hi;
    W2[((size_t)l * 1536 + rp) * 1024 + 512 + k] = lo;
}

// ---------------- encoder-as-GEMM pieces --------------------------------------
// combined weight Wc2[640][2*288]: rows 0..191 reg(cols 0..63),
// 192..383 br(cols 256..287), 384..575 sh(cols 64..255), rest zero.
__global__ __launch_bounds__(256)
void build_encw(const float* __restrict__ reg_w, const float* __restrict__ reg_b,
                const float* __restrict__ br_w, const float* __restrict__ br_b,
                const float* __restrict__ sh_w, const float* __restrict__ sh_b,
                ushort_t* __restrict__ Wc2, float* __restrict__ bc) {
    int n = blockIdx.x;
    int tid = threadIdx.x;
    for (int k = tid; k < 288; k += 256) {
        float v = 0.0f;
        if (n < 192) {
            if (k < 64) v = reg_w[(size_t)n * 64 + k];
        } else if (n < 384) {
            if (k >= 256) v = br_w[(size_t)(n - 192) * 32 + (k - 256)];
        } else if (n < 576) {
            if (k >= 64 && k < 256) v = sh_w[(size_t)(n - 384) * 192 + (k - 64)];
        }
        ushort_t hi, lo;
        split2(v, hi, lo);
        Wc2[(size_t)n * 576 + k] = hi;
        Wc2[(size_t)n * 576 + 288 + k] = lo;
    }
    if (tid == 0) {
        float b = 0.0f;
        if (n < 192) b = reg_b[n];
        else if (n < 384) b = br_b[n - 192];
        else if (n < 576) b = sh_b[n - 384];
        bc[n] = b;
    }
}

// pack int features -> bf16 hi (exact), lo = 0.  X2[8192][2*288]
__global__ __launch_bounds__(256)
void pack_x(const int* __restrict__ x, ushort_t* __restrict__ X2) {
    int idx = blockIdx.x * 256 + threadIdx.x;     // 8192*288
    int tok = idx / 288, k = idx % 288;
    X2[(size_t)tok * 576 + k] = f2u((float)x[(size_t)tok * 289 + 1 + k]);
    X2[(size_t)tok * 576 + 288 + k] = 0;
}

// embedding gather + silu + split -> cat2 cols 0..191
__global__ __launch_bounds__(256)
void gather_emb(const int* __restrict__ x, const float* __restrict__ emb,
                ushort_t* __restrict__ cat2) {
    int idx = blockIdx.x * 256 + threadIdx.x;     // 8192*192
    int tok = idx / 192, c = idx % 192;
    int tokid = x[(size_t)tok * 289];
    float v = silu_f(emb[(size_t)tokid * TEDIM + c]);
    ushort_t hi, lo;
    split2(v, hi, lo);
    cat2[(size_t)tok * 1536 + c] = hi;
    cat2[(size_t)tok * 1536 + 768 + c] = lo;
}

// encoder GEMM: silu(X@Wc^T+bc) -> cat2 cols 192..767 (split)
__global__ __launch_bounds__(256)
void gemm3_enc(const ushort_t* __restrict__ A2, const ushort_t* __restrict__ B2,
               const float* __restrict__ bc, ushort_t* __restrict__ cat2) {
    __shared__ __align__(16) ushort_t lds[4 * 4096];
    const int tid = threadIdx.x;
    const int bm = blockIdx.y * 128, bn = blockIdx.x * 128;
    const int w = tid >> 6, l = tid & 63;
    const int wm = (w & 1) * 64, wn = (w >> 1) * 64;
    const int Kp = 288;

    f32x4 acc[4][4];
    #pragma unroll
    for (int i = 0; i < 4; ++i)
        #pragma unroll
        for (int j = 0; j < 4; ++j) acc[i][j] = (f32x4){0.f, 0.f, 0.f, 0.f};

    const int r0 = tid >> 2, k8 = (tid & 3) * 8;
    const ushort_t* gA0 = A2 + (size_t)(bm + r0) * 576 + k8;
    const ushort_t* gA1 = A2 + (size_t)(bm + 64 + r0) * 576 + k8;
    const ushort_t* gB0 = B2 + (size_t)(bn + r0) * 576 + k8;
    const ushort_t* gB1 = B2 + (size_t)(bn + 64 + r0) * 576 + k8;
    ushort_t* l0 = lds + tid * 8;
    ushort_t* l1 = lds + 2048 + tid * 8;
    const int fr = l & 15, fk = (l >> 4) * 8;

    for (int kt = 0; kt < Kp; kt += 32) {
        gl_lds16(gA0 + kt, l0);
        gl_lds16(gA1 + kt, l1);
        gl_lds16(gA0 + kt + Kp, l0 + 4096);
        gl_lds16(gA1 + kt + Kp, l1 + 4096);
        gl_lds16(gB0 + kt, l0 + 8192);
        gl_lds16(gB1 + kt, l1 + 8192);
        gl_lds16(gB0 + kt + Kp, l0 + 12288);
        gl_lds16(gB1 + kt + Kp, l1 + 12288);
        __syncthreads();
        bf16x8 ahi[4], alo[4], bhi[4], blo[4];
        #pragma unroll
        for (int i = 0; i < 4; ++i) {
            int ra = (wm + i * 16 + fr) * 32 + fk;
            int rb = (wn + i * 16 + fr) * 32 + fk;
            ahi[i] = *(const bf16x8*)&lds[ra];
            alo[i] = *(const bf16x8*)&lds[4096 + ra];
            bhi[i] = *(const bf16x8*)&lds[8192 + rb];
            blo[i] = *(const bf16x8*)&lds[12288 + rb];
        }
        #pragma unroll
        for (int i = 0; i < 4; ++i)
            #pragma unroll
            for (int j = 0; j < 4; ++j) {
                acc[i][j] = __builtin_amdgcn_mfma_f32_16x16x32_bf16(ahi[i], bhi[j], acc[i][j], 0, 0, 0);
                acc[i][j] = __builtin_amdgcn_mfma_f32_16x16x32_bf16(ahi[i], blo[j], acc[i][j], 0, 0, 0);
                acc[i][j] = __builtin_amdgcn_mfma_f32_16x16x32_bf16(alo[i], bhi[j], acc[i][j], 0, 0, 0);
            }
        __syncthreads();
    }

    const int er = (l >> 4) * 4, ec = l & 15;
    #pragma unroll
    for (int i = 0; i < 4; ++i)
        #pragma unroll
        for (int j = 0; j < 4; ++j)
            #pragma unroll
            for (int r = 0; r < 4; ++r) {
                int gm = bm + wm + i * 16 + er + r;
                int gn = bn + wn + j * 16 + ec;
                if (gn < 576) {
                    float v = silu_f(acc[i][j][r] + bc[gn]);
                    ushort_t hi, lo;
                    split2(v, hi, lo);
                    cat2[(size_t)gm * 1536 + 192 + gn] = hi;
                    cat2[(size_t)gm * 1536 + 960 + gn] = lo;
                }
            }
}

// ---------------- bf16x3 MFMA GEMM (fp32 out + bias/res) ----------------------
__global__ __launch_bounds__(256)
void gemm3_kernel(const ushort_t* __restrict__ A2, int rsA,
                  const ushort_t* __restrict__ B2, int rsB,
                  const float* __restrict__ bias,
                  const float* __restrict__ res,
                  float* __restrict__ Cf, int rsC, int Kp) {
    __shared__ __align__(16) ushort_t lds[4 * 4096];
    const int tid = threadIdx.x;
    const int bm = blockIdx.y * 128, bn = blockIdx.x * 128;
    const int w = tid >> 6, l = tid & 63;
    const int wm = (w & 1) * 64, wn = (w >> 1) * 64;

    f32x4 acc[4][4];
    #pragma unroll
    for (int i = 0; i < 4; ++i)
        #pragma unroll
        for (int j = 0; j < 4; ++j) acc[i][j] = (f32x4){0.f, 0.f, 0.f, 0.f};

    const int r0 = tid >> 2, k8 = (tid & 3) * 8;
    const ushort_t* gA0 = A2 + (size_t)(bm + r0) * rsA + k8;
    const ushort_t* gA1 = A2 + (size_t)(bm + 64 + r0) * rsA + k8;
    const ushort_t* gB0 = B2 + (size_t)(bn + r0) * rsB + k8;
    const ushort_t* gB1 = B2 + (size_t)(bn + 64 + r0) * rsB + k8;
    ushort_t* l0 = lds + tid * 8;
    ushort_t* l1 = lds + 2048 + tid * 8;
    const int fr = l & 15, fk = (l >> 4) * 8;

    for (int kt = 0; kt < Kp; kt += 32) {
        gl_lds16(gA0 + kt, l0);
        gl_lds16(gA1 + kt, l1);
        gl_lds16(gA0 + kt + Kp, l0 + 4096);
        gl_lds16(gA1 + kt + Kp, l1 + 4096);
        gl_lds16(gB0 + kt, l0 + 8192);
        gl_lds16(gB1 + kt, l1 + 8192);
        gl_lds16(gB0 + kt + Kp, l0 + 12288);
        gl_lds16(gB1 + kt + Kp, l1 + 12288);
        __syncthreads();

        bf16x8 ahi[4], alo[4], bhi[4], blo[4];
        #pragma unroll
        for (int i = 0; i < 4; ++i) {
            int ra = (wm + i * 16 + fr) * 32 + fk;
            int rb = (wn + i * 16 + fr) * 32 + fk;
            ahi[i] = *(const bf16x8*)&lds[ra];
            alo[i] = *(const bf16x8*)&lds[4096 + ra];
            bhi[i] = *(const bf16x8*)&lds[8192 + rb];
            blo[i] = *(const bf16x8*)&lds[12288 + rb];
        }
        #pragma unroll
        for (int i = 0; i < 4; ++i)
            #pragma unroll
            for (int j = 0; j < 4; ++j) {
                acc[i][j] = __builtin_amdgcn_mfma_f32_16x16x32_bf16(ahi[i], bhi[j], acc[i][j], 0, 0, 0);
                acc[i][j] = __builtin_amdgcn_mfma_f32_16x16x32_bf16(ahi[i], blo[j], acc[i][j], 0, 0, 0);
                acc[i][j] = __builtin_amdgcn_mfma_f32_16x16x32_bf16(alo[i], bhi[j], acc[i][j], 0, 0, 0);
            }
        __syncthreads();
    }

    const int er = (l >> 4) * 4, ec = l & 15;
    #pragma unroll
    for (int i = 0; i < 4; ++i)
        #pragma unroll
        for (int j = 0; j < 4; ++j)
            #pragma unroll
            for (int r = 0; r < 4; ++r) {
                int gm = bm + wm + i * 16 + er + r;
                int gn = bn + wn + j * 16 + ec;
                float v = acc[i][j][r];
                if (bias) v += bias[gn];
                if (res) v += res[(size_t)gm * rsC + gn];
                Cf[(size_t)gm * rsC + gn] = v;
            }
}

// ---------------- fused GLU GEMM: g = silu(x@W1^T+b1)*(x@W3^T+b3) -> split ----
__global__ __launch_bounds__(256)
void gemm_glu3(const ushort_t* __restrict__ A2,
               const ushort_t* __restrict__ W1, const ushort_t* __restrict__ W3,
               const float* __restrict__ b1, const float* __restrict__ b3,
               ushort_t* __restrict__ C2) {
    __shared__ __align__(16) ushort_t lds[6 * 4096];
    const int tid = threadIdx.x;
    const int bm = blockIdx.y * 128, bn = blockIdx.x * 128;
    const int w = tid >> 6, l = tid & 63;
    const int wm = (w & 1) * 64, wn = (w >> 1) * 64;
    const int Kp = 512;

    f32x4 acc1[4][4], acc3[4][4];
    #pragma unroll
    for (int i = 0; i < 4; ++i)
        #pragma unroll
        for (int j = 0; j < 4; ++j) {
            acc1[i][j] = (f32x4){0.f, 0.f, 0.f, 0.f};
            acc3[i][j] = (f32x4){0.f, 0.f, 0.f, 0.f};
        }

    const int r0 = tid >> 2, k8 = (tid & 3) * 8;
    const ushort_t* gA0 = A2 + (size_t)(bm + r0) * 1024 + k8;
    const ushort_t* gA1 = A2 + (size_t)(bm + 64 + r0) * 1024 + k8;
    const ushort_t* g10 = W1 + (size_t)(bn + r0) * 1024 + k8;
    const ushort_t* g11 = W1 + (size_t)(bn + 64 + r0) * 1024 + k8;
    const ushort_t* g30 = W3 + (size_t)(bn + r0) * 1024 + k8;
    const ushort_t* g31 = W3 + (size_t)(bn + 64 + r0) * 1024 + k8;
    ushort_t* l0 = lds + tid * 8;
    ushort_t* l1 = lds + 2048 + tid * 8;
    const int fr = l & 15, fk = (l >> 4) * 8;

    for (int kt = 0; kt < Kp; kt += 32) {
        gl_lds16(gA0 + kt, l0);
        gl_lds16(gA1 + kt, l1);
        gl_lds16(gA0 + kt + Kp, l0 + 4096);
        gl_lds16(gA1 + kt + Kp, l1 + 4096);
        gl_lds16(g10 + kt, l0 + 8192);
        gl_lds16(g11 + kt, l1 + 8192);
        gl_lds16(g10 + kt + Kp, l0 + 12288);
        gl_lds16(g11 + kt + Kp, l1 + 12288);
        gl_lds16(g30 + kt, l0 + 16384);
        gl_lds16(g31 + kt, l1 + 16384);
        gl_lds16(g30 + kt + Kp, l0 + 20480);
        gl_lds16(g31 + kt + Kp, l1 + 20480);
        __syncthreads();

        bf16x8 ahi[4], alo[4];
        #pragma unroll
        for (int i = 0; i < 4; ++i) {
            int ra = (wm + i * 16 + fr) * 32 + fk;
            ahi[i] = *(const bf16x8*)&lds[ra];
            alo[i] = *(const bf16x8*)&lds[4096 + ra];
        }
        #pragma unroll
        for (int j = 0; j < 4; ++j) {
            int rb = (wn + j * 16 + fr) * 32 + fk;
            bf16x8 w1h = *(const bf16x8*)&lds[8192 + rb];
            bf16x8 w1l = *(const bf16x8*)&lds[12288 + rb];
            bf16x8 w3h = *(const bf16x8*)&lds[16384 + rb];
            bf16x8 w3l = *(const bf16x8*)&lds[20480 + rb];
            #pragma unroll
            for (int i = 0; i < 4; ++i) {
                acc1[i][j] = __builtin_amdgcn_mfma_f32_16x16x32_bf16(ahi[i], w1h, acc1[i][j], 0, 0, 0);
                acc1[i][j] = __builtin_amdgcn_mfma_f32_16x16x32_bf16(ahi[i], w1l, acc1[i][j], 0, 0, 0);
                acc1[i][j] = __builtin_amdgcn_mfma_f32_16x16x32_bf16(alo[i], w1h, acc1[i][j], 0, 0, 0);
                acc3[i][j] = __builtin_amdgcn_mfma_f32_16x16x32_bf16(ahi[i], w3h, acc3[i][j], 0, 0, 0);
                acc3[i][j] = __builtin_amdgcn_mfma_f32_16x16x32_bf16(ahi[i], w3l, acc3[i][j], 0, 0, 0);
                acc3[i][j] = __builtin_amdgcn_mfma_f32_16x16x32_bf16(alo[i], w3h, acc3[i][j], 0, 0, 0);
            }
        }
        __syncthreads();
    }

    const int er = (l >> 4) * 4, ec = l & 15;
    #pragma unroll
    for (int i = 0; i < 4; ++i)
        #pragma unroll
        for (int j = 0; j < 4; ++j)
            #pragma unroll
            for (int r = 0; r < 4; ++r) {
                int gm = bm + wm + i * 16 + er + r;
                int gn = bn + wn + j * 16 + ec;
                if (gn < KP2) {
                    float u1 = acc1[i][j][r], u3 = acc3[i][j][r];
                    if (gn < DFF) { u1 += b1[gn]; u3 += b3[gn]; }
                    float g = silu_f(u1) * u3;
                    ushort_t hi, lo;
                    split2(g, hi, lo);
                    C2[(size_t)gm * (2 * KP2) + gn] = hi;
                    C2[(size_t)gm * (2 * KP2) + KP2 + gn] = lo;
                }
            }
}

// ---------------- per-token reductions (wave-per-token) -----------------------
__global__ __launch_bounds__(256)
void rms_kernel(const float* __restrict__ h, const float* __restrict__ w,
                ushort_t* __restrict__ out2) {
    int wid = threadIdx.x >> 6, lane = threadIdx.x & 63;
    int t = blockIdx.x * 4 + wid;
    const float* hp = h + (size_t)t * 512;
    float xv[8];
    float ss = 0.0f;
    #pragma unroll
    for (int u = 0; u < 8; ++u) { xv[u] = hp[u * 64 + lane]; ss += xv[u] * xv[u]; }
    #pragma unroll
    for (int off = 32; off > 0; off >>= 1) ss += __shfl_xor(ss, off, 64);
    float inv = rsqrtf(ss * (1.0f / 512.0f) + 1.1920929e-07f);
    ushort_t* op = out2 + (size_t)t * 1024;
    #pragma unroll
    for (int u = 0; u < 8; ++u) {
        ushort_t hi, lo;
        split2(xv[u] * inv * w[u * 64 + lane], hi, lo);
        op[u * 64 + lane] = hi;
        op[512 + u * 64 + lane] = lo;
    }
}

__global__ __launch_bounds__(256)
void ln_silu_kernel(const float* __restrict__ h, const float* __restrict__ w,
                    const float* __restrict__ b, float* __restrict__ out) {
    int wid = threadIdx.x >> 6, lane = threadIdx.x & 63;
    int t = blockIdx.x * 4 + wid;
    const float* hp = h + (size_t)t * 512;
    float xv[8];
    float s = 0.0f;
    #pragma unroll
    for (int u = 0; u < 8; ++u) { xv[u] = hp[u * 64 + lane]; s += xv[u]; }
    #pragma unroll
    for (int off = 32; off > 0; off >>= 1) s += __shfl_xor(s, off, 64);
    float m = s * (1.0f / 512.0f);
    float v = 0.0f;
    #pragma unroll
    for (int u = 0; u < 8; ++u) { xv[u] -= m; v += xv[u] * xv[u]; }
    #pragma unroll
    for (int off = 32; off > 0; off >>= 1) v += __shfl_xor(v, off, 64);
    float inv = rsqrtf(v * (1.0f / 512.0f) + 1e-5f);
    float* op = out + (size_t)t * 512;
    #pragma unroll
    for (int u = 0; u < 8; ++u)
        op[u * 64 + lane] = silu_f(xv[u] * inv * w[u * 64 + lane] + b[u * 64 + lane]);
}

// ---------------- local attention ---------------------------------------------
__global__ __launch_bounds__(256)
void attn_kernel(const float* __restrict__ qkv, const float* __restrict__ ct,
                 const float* __restrict__ st, ushort_t* __restrict__ attn2) {
    int nb = blockIdx.x;
    int head = blockIdx.y;
    int b = blockIdx.z;
    int tid = threadIdx.x;
    int qi = tid >> 1, hf = tid & 1;
    __shared__ __align__(16) float Ks[64][64];
    __shared__ __align__(16) float Vs[64][64];

    int qtok = nb * WINSZ + qi;
    const float* qp = qkv + ((size_t)(b * LSEQ + qtok)) * 1536 + head * 64 + hf * 32;
    float q[32];
    #pragma unroll
    for (int d = 0; d < 32; d += 4) *(float4*)&q[d] = *(const float4*)&qp[d];
    {
        const float* cp = ct + qtok * 32 + hf * 16;
        const float* sp = st + qtok * 32 + hf * 16;
        #pragma unroll
        for (int p = 0; p < 16; ++p) {
            float cs = cp[p], sn = sp[p];
            float x1 = q[2 * p], x2 = q[2 * p + 1];
            q[2 * p] = (x1 * cs - x2 * sn) * 0.125f;
            q[2 * p + 1] = (x1 * sn + x2 * cs) * 0.125f;
        }
    }

    float o[32];
    #pragma unroll
    for (int d = 0; d < 32; ++d) o[d] = 0.0f;
    float m = -1e30f, lsum = 0.0f;

    int c0 = (nb == 0) ? 2 : 0;
    for (int c = c0; c < 4; ++c) {
        int r = tid >> 2, qd = tid & 3;
        int ktok = nb * WINSZ - WINSZ + c * 64 + r;
        const float* kb = qkv + ((size_t)(b * LSEQ + ktok)) * 1536 + 512 + head * 64 + qd * 16;
        const float* vb = kb + 512;
        float kk[16], vv[16];
        #pragma unroll
        for (int d = 0; d < 16; d += 4) {
            *(float4*)&kk[d] = *(const float4*)&kb[d];
            *(float4*)&vv[d] = *(const float4*)&vb[d];
        }
        {
            const float* cp = ct + ktok * 32 + qd * 8;
            const float* sp = st + ktok * 32 + qd * 8;
            #pragma unroll
            for (int p = 0; p < 8; ++p) {
                float cs = cp[p], sn = sp[p];
                float x1 = kk[2 * p], x2 = kk[2 * p + 1];
                kk[2 * p] = x1 * cs - x2 * sn;
                kk[2 * p + 1] = x1 * sn + x2 * cs;
            }
        }
        #pragma unroll
        for (int d = 0; d < 16; d += 4) {
            *(float4*)&Ks[r][qd * 16 + d] = *(const float4*)&kk[d];
            *(float4*)&Vs[r][qd * 16 + d] = *(const float4*)&vv[d];
        }
        __syncthreads();

        for (int jj = 0; jj < 64; ++jj) {
            int j = c * 64 + jj;
            float s32 = 0.0f;
            #pragma unroll
            for (int d = 0; d < 32; d += 4) {
                float4 kv = *(const float4*)&Ks[jj][hf * 32 + d];
                s32 += q[d] * kv.x + q[d + 1] * kv.y + q[d + 2] * kv.z + q[d + 3] * kv.w;
            }
            float s = s32 + __shfl_xor(s32, 1, 64);
            bool valid = (j >= qi) && (j <= qi + WINSZ);
            if (valid) {
                if (s > m) {
                    float al = __expf(m - s);
                    lsum *= al;
                    #pragma unroll
                    for (int d = 0; d < 32; ++d) o[d] *= al;
                    m = s;
                }
                float p = __expf(s - m);
                lsum += p;
                #pragma unroll
                for (int d = 0; d < 32; d += 4) {
                    float4 vv4 = *(const float4*)&Vs[jj][hf * 32 + d];
                    o[d]     += p * vv4.x;
                    o[d + 1] += p * vv4.y;
                    o[d + 2] += p * vv4.z;
                    o[d + 3] += p * vv4.w;
                }
            }
        }
        __syncthreads();
    }
    float invl = 1.0f / lsum;
    size_t ob = ((size_t)(b * LSEQ + qtok)) * 1024 + head * 64 + hf * 32;
    #pragma unroll
    for (int d = 0; d < 32; d += 4) {
        ushort4 hv, lv;
        ushort_t hi, lo;
        split2(o[d] * invl, hi, lo);     hv.x = hi; lv.x = lo;
        split2(o[d + 1] * invl, hi, lo); hv.y = hi; lv.y = lo;
        split2(o[d + 2] * invl, hi, lo); hv.z = hi; lv.z = lo;
        split2(o[d + 3] * invl, hi, lo); hv.w = hi; lv.w = lo;
        *(ushort4*)&attn2[ob + d] = hv;
        *(ushort4*)&attn2[ob + 512 + d] = lv;
    }
}

// ---------------- head: LN + silu + 31-dim head + postprocess -----------------
__global__ __launch_bounds__(256)
void head_kernel(const float* __restrict__ h, const float* __restrict__ lw,
                 const float* __restrict__ lb, const float* __restrict__ head_w,
                 const float* __restrict__ head_b, float* __restrict__ out) {
    int wid = threadIdx.x >> 6, lane = threadIdx.x & 63;
    int t = blockIdx.x * 4 + wid;
    __shared__ float yv[4][32];
    const float* xr = h + (size_t)t * 512;
    float xv[8];
    float s = 0.0f;
    #pragma unroll
    for (int u = 0; u < 8; ++u) { xv[u] = xr[u * 64 + lane]; s += xv[u]; }
    #pragma unroll
    for (int off = 32; off > 0; off >>= 1) s += __shfl_xor(s, off, 64);
    float m = s * (1.0f / 512.0f);
    float var = 0.0f;
    #pragma unroll
    for (int u = 0; u < 8; ++u) { xv[u] -= m; var += xv[u] * xv[u]; }
    #pragma unroll
    for (int off = 32; off > 0; off >>= 1) var += __shfl_xor(var, off, 64);
    float inv = rsqrtf(var * (1.0f / 512.0f) + 1e-5f);
    #pragma unroll
    for (int u = 0; u < 8; ++u)
        xv[u] = silu_f(xv[u] * inv * lw[u * 64 + lane] + lb[u * 64 + lane]);

    for (int j = 0; j < 31; ++j) {
        const float* wr = head_w + (size_t)j * 512;
        float p = 0.0f;
        #pragma unroll
        for (int u = 0; u < 8; ++u) p += xv[u] * wr[u * 64 + lane];
        #pragma unroll
        for (int off = 32; off > 0; off >>= 1) p += __shfl_down(p, off, 64);
        if (lane == 0) yv[wid][j] = p + head_b[j];
    }
    if (lane == 0) {
        float* y = yv[wid];
        float* op = out + (size_t)t * 40;
        int am = 0; float best = y[0];
        for (int j = 1; j < 11; ++j) if (y[j] > best) { best = y[j]; am = j; }
        float fc_reg = softplus_f(y[11]);
        op[0] = (am < 10) ? (float)(am + 1) : fc_reg;
        for (int j = 0; j < 11; ++j) op[1 + j] = y[j];
        op[12] = fc_reg;
        int am2 = 0; float best2 = y[12];
        for (int j = 1; j < 11; ++j) if (y[12 + j] > best2) { best2 = y[12 + j]; am2 = j; }
        float ec_reg = softplus_f(y[23]);
        op[13] = (am2 < 10) ? (float)(am2 + 1) : ec_reg;
        for (int j = 0; j < 11; ++j) op[14 + j] = y[12 + j];
        op[25] = ec_reg;
        float bm_log = y[24];
        op[26] = 1.0f / (1.0f + expf(-bm_log));
        float mi = fmaxf(y[25], fmaxf(y[26], y[27]));
        float e0 = expf(y[25] - mi), e1 = expf(y[26] - mi), e2 = expf(y[27] - mi);
        float si = e0 + e1 + e2;
        op[27] = e0 / si; op[28] = e1 / si; op[29] = e2 / si;
        float md = fmaxf(y[28], fmaxf(y[29], y[30]));
        float d0 = expf(y[28] - md), d1 = expf(y[29] - md), d2 = expf(y[30] - md);
        float sd = d0 + d1 + d2;
        op[30] = d0 / sd; op[31] = d1 / sd; op[32] = d2 / sd;
        op[33] = bm_log;
        op[34] = y[25]; op[35] = y[26]; op[36] = y[27];
        op[37] = y[28]; op[38] = y[29]; op[39] = y[30];
    }
}

// ---------------- launch -------------------------------------------------------
extern "C" void kernel_launch(void* const* d_in, const int* in_sizes, int n_in,
                              void* d_out, int out_size, void* d_ws, size_t ws_size,
                              hipStream_t stream) {
    const int*   x        = (const int*)d_in[0];
    const float* emb      = (const float*)d_in[1];
    const float* reg_w    = (const float*)d_in[2];
    const float* reg_b    = (const float*)d_in[3];
    const float* br_w     = (const float*)d_in[4];
    const float* br_b     = (const float*)d_in[5];
    const float* sh_w     = (const float*)d_in[6];
    const float* sh_b     = (const float*)d_in[7];
    const float* inst_w   = (const float*)d_in[8];
    const float* inst_b   = (const float*)d_in[9];
    const float* enc_ln_w = (const float*)d_in[10];
    const float* enc_ln_b = (const float*)d_in[11];
    const float* qkv_w    = (const float*)d_in[12];
    const float* out_w    = (const float*)d_in[13];
    const float* out_b    = (const float*)d_in[14];
    const float* w1_w     = (const float*)d_in[15];
    const float* w1_b     = (const float*)d_in[16];
    const float* w3_w     = (const float*)d_in[17];
    const float* w3_b     = (const float*)d_in[18];
    const float* w2_w     = (const float*)d_in[19];
    const float* w2_b     = (const float*)d_in[20];
    const float* n1_w     = (const float*)d_in[21];
    const float* n2_w     = (const float*)d_in[22];
    const float* hl_w     = (const float*)d_in[23];
    const float* hl_b     = (const float*)d_in[24];
    const float* head_w   = (const float*)d_in[25];
    const float* head_b   = (const float*)d_in[26];

    char* ws = (char*)d_ws;
    size_t off = 0;
    ushort_t* inst2 = (ushort_t*)(ws + off); off += (size_t)512 * 1536 * 2;
    ushort_t* qkv2  = (ushort_t*)(ws + off); off += (size_t)3 * 1536 * 1024 * 2;
    ushort_t* out2w = (ushort_t*)(ws + off); off += (size_t)3 * 512 * 1024 * 2;
    ushort_t* w1s   = (ushort_t*)(ws + off); off += (size_t)3 * DFFP * 1024 * 2;
    ushort_t* w3s   = (ushort_t*)(ws + off); off += (size_t)3 * DFFP * 1024 * 2;
    ushort_t* w2s   = (ushort_t*)(ws + off); off += (size_t)3 * 512 * (2 * KP2) * 2;
    float*    ct    = (float*)(ws + off);    off += (size_t)LSEQ * 32 * 4;
    float*    st    = (float*)(ws + off);    off += (size_t)LSEQ * 32 * 4;
    float*    h     = (float*)(ws + off);    off += (size_t)T_TOK * 512 * 4;
    ushort_t* x2    = (ushort_t*)(ws + off); off += (size_t)T_TOK * 1024 * 2;
    ushort_t* attn2 = (ushort_t*)(ws + off); off += (size_t)T_TOK * 1024 * 2;
    float*    qkvb  = (float*)(ws + off);    off += (size_t)T_TOK * 1536 * 4;
    ushort_t* cat2  = (ushort_t*)(ws + off); off += (size_t)T_TOK * (2 * KP2) * 2;
    ushort_t* Wc2   = (ushort_t*)(ws + off); off += (size_t)640 * 576 * 2;
    float*    bc    = (float*)(ws + off);    off += 640 * 4;
    ushort_t* g2    = cat2;
    ushort_t* X2    = (ushort_t*)qkvb;   // 8192*576*2 = 9.4MB < qkvb region

    rope_kernel<<<256, 256, 0, stream>>>(ct, st);
    build_encw<<<640, 256, 0, stream>>>(reg_w, reg_b, br_w, br_b, sh_w, sh_b, Wc2, bc);
    pack_x<<<(T_TOK * 288) / 256, 256, 0, stream>>>(x, X2);
    gather_emb<<<(T_TOK * 192) / 256, 256, 0, stream>>>(x, emb, cat2);
    splitw_kernel<<<dim3(3, 512), 256, 0, stream>>>(inst_w, inst2, 512, 768, 768);
    splitw_qkv_kernel<<<dim3(2, 1536, 3), 256, 0, stream>>>(qkv_w, qkv2);
    splitw_kernel<<<dim3(2, 3 * 512), 256, 0, stream>>>(out_w, out2w, 3 * 512, 512, 512);
    for (int l = 0; l < NLAYER; ++l) {
        splitw_kernel<<<dim3(2, DFFP), 256, 0, stream>>>(
            w1_w + (size_t)l * DFF * 512, w1s + (size_t)l * DFFP * 1024, DFF, 512, 512);
        splitw_kernel<<<dim3(2, DFFP), 256, 0, stream>>>(
            w3_w + (size_t)l * DFF * 512, w3s + (size_t)l * DFFP * 1024, DFF, 512, 512);
        splitw_kernel<<<dim3(6, 512), 256, 0, stream>>>(
            w2_w + (size_t)l * 512 * DFF, w2s + (size_t)l * 512 * (2 * KP2), 512, DFF, KP2);
    }

    gemm3_enc<<<dim3(5, 64), 256, 0, stream>>>(X2, Wc2, bc, cat2);
    gemm3_kernel<<<dim3(4, 64), 256, 0, stream>>>(
        cat2, 1536, inst2, 1536, inst_b, nullptr, h, 512, 768);
    ln_silu_kernel<<<T_TOK / 4, 256, 0, stream>>>(h, enc_ln_w, enc_ln_b, h);

    for (int l = 0; l < NLAYER; ++l) {
        rms_kernel<<<T_TOK / 4, 256, 0, stream>>>(h, n1_w + l * 512, x2);
        gemm3_kernel<<<dim3(12, 64), 256, 0, stream>>>(
            x2, 1024, qkv2 + (size_t)l * 1536 * 1024, 1024, nullptr, nullptr,
            qkvb, 1536, 512);
        {
            dim3 g(NBLK, NHEAD, BATCH);
            attn_kernel<<<g, 256, 0, stream>>>(qkvb, ct, st, attn2);
        }
        gemm3_kernel<<<dim3(4, 64), 256, 0, stream>>>(
            attn2, 1024, out2w + (size_t)l * 512 * 1024, 1024, out_b + l * 512,
            h, h, 512, 512);
        rms_kernel<<<T_TOK / 4, 256, 0, stream>>>(h, n2_w + l * 512, x2);
        gemm_glu3<<<dim3(11, 64), 256, 0, stream>>>(
            x2, w1s + (size_t)l * DFFP * 1024, w3s + (size_t)l * DFFP * 1024,
            w1_b + l * DFF, w3_b + l * DFF, g2);
        gemm3_kernel<<<dim3(4, 64), 256, 0, stream>>>(
            g2, 2 * KP2, w2s + (size_t)l * 512 * (2 * KP2), 2 * KP2, w2_b + l * 512,
            h, h, 512, KP2);
    }

    head_kernel<<<T_TOK / 4, 256, 0, stream>>>(h, hl_w, hl_b, head_w, head_b,
                                               (float*)d_out);
}

// Round 5
// 1404.092 us; speedup vs baseline: 4.0440x; 1.1481x over previous
//
#include <hip/hip_runtime.h>
#include <hip/hip_bf16.h>
#include <math.h>

#define T_TOK 8192
#define DMODEL 512
#define NHEAD 8
#define TEDIM 192
#define DFF 1365
#define DFFP 1408
#define KP2 1376
#define NLAYER 3
#define WINSZ 128
#define NBLK 16
#define LSEQ 2048
#define BATCH 4

typedef unsigned short ushort_t;
typedef __bf16 bf16x8 __attribute__((ext_vector_type(8)));
typedef float f32x4 __attribute__((ext_vector_type(4)));

__device__ __forceinline__ float silu_f(float x) { return x / (1.0f + expf(-x)); }
__device__ __forceinline__ float softplus_f(float x) {
    return (x > 20.0f) ? x : log1pf(expf(x));
}

__device__ __forceinline__ ushort_t f2u(float x) {
    __hip_bfloat16 b = __float2bfloat16(x);
    return *reinterpret_cast<ushort_t*>(&b);
}
__device__ __forceinline__ float u2f(ushort_t u) {
    __hip_bfloat16 b = *reinterpret_cast<__hip_bfloat16*>(&u);
    return __bfloat162float(b);
}
__device__ __forceinline__ void split2(float x, ushort_t& hi, ushort_t& lo) {
    hi = f2u(x);
    lo = f2u(x - u2f(hi));
}

__device__ __forceinline__ void gl_lds16(const ushort_t* g, ushort_t* l) {
    __builtin_amdgcn_global_load_lds(
        (const __attribute__((address_space(1))) unsigned int*)g,
        (__attribute__((address_space(3))) unsigned int*)l, 16, 0, 0);
}

// ---------------- RoPE table: cos/sin[2048][32] -------------------------------
__global__ __launch_bounds__(256)
void rope_kernel(float* __restrict__ ct, float* __restrict__ st) {
    int idx = blockIdx.x * 256 + threadIdx.x;
    int tok = idx >> 5, p = idx & 31;
    float invf = powf(10000.0f, -(float)p * (1.0f / 32.0f));
    float sn, cs;
    sincosf((float)tok * invf, &sn, &cs);
    ct[idx] = cs;
    st[idx] = sn;
}

// ---------------- weight split: W[N][K] fp32 -> W2[Npad][2*Kp] bf16 hi|lo -----
__global__ __launch_bounds__(256)
void splitw_kernel(const float* __restrict__ W, ushort_t* __restrict__ W2,
                   int N, int K, int Kp) {
    int n = blockIdx.y;
    int k = blockIdx.x * 256 + threadIdx.x;
    if (k >= Kp) return;
    float v = (n < N && k < K) ? W[(size_t)n * K + k] : 0.0f;
    ushort_t hi, lo;
    split2(v, hi, lo);
    W2[(size_t)n * (2 * Kp) + k] = hi;
    W2[(size_t)n * (2 * Kp) + Kp + k] = lo;
}

// qkv weights: permute rows h*192+dk*3+which -> which*512+h*64+dk
__global__ __launch_bounds__(256)
void splitw_qkv_kernel(const float* __restrict__ W, ushort_t* __restrict__ W2) {
    int l = blockIdx.z;
    int rr = blockIdx.y;
    int k = blockIdx.x * 256 + threadIdx.x;
    int h = rr / 192, rem = rr % 192;
    int dk = rem / 3, which = rem % 3;
    int rp = which * 512 + h * 64 + dk;
    float v = W[((size_t)l * 1536 + rr) * 512 + k];
    ushort_t hi, lo;
    split2(v, hi, lo);
    W2[((size_t)l * 1536 + rp) * 1024 + k] = hi;
    W2[((size_t)l * 1536 + rp) * 1024 + 512 + k] = lo;
}

// ---------------- encoder-as-GEMM pieces --------------------------------------
__global__ __launch_bounds__(256)
void build_encw(const float* __restrict__ reg_w, const float* __restrict__ reg_b,
                const float* __restrict__ br_w, const float* __restrict__ br_b,
                const float* __restrict__ sh_w, const float* __restrict__ sh_b,
                ushort_t* __restrict__ Wc2, float* __restrict__ bc) {
    int n = blockIdx.x;
    int tid = threadIdx.x;
    for (int k = tid; k < 288; k += 256) {
        float v = 0.0f;
        if (n < 192) {
            if (k < 64) v = reg_w[(size_t)n * 64 + k];
        } else if (n < 384) {
            if (k >= 256) v = br_w[(size_t)(n - 192) * 32 + (k - 256)];
        } else if (n < 576) {
            if (k >= 64 && k < 256) v = sh_w[(size_t)(n - 384) * 192 + (k - 64)];
        }
        ushort_t hi, lo;
        split2(v, hi, lo);
        Wc2[(size_t)n * 576 + k] = hi;
        Wc2[(size_t)n * 576 + 288 + k] = lo;
    }
    if (tid == 0) {
        float b = 0.0f;
        if (n < 192) b = reg_b[n];
        else if (n < 384) b = br_b[n - 192];
        else if (n < 576) b = sh_b[n - 384];
        bc[n] = b;
    }
}

__global__ __launch_bounds__(256)
void pack_x(const int* __restrict__ x, ushort_t* __restrict__ X2) {
    int idx = blockIdx.x * 256 + threadIdx.x;
    int tok = idx / 288, k = idx % 288;
    X2[(size_t)tok * 576 + k] = f2u((float)x[(size_t)tok * 289 + 1 + k]);
    X2[(size_t)tok * 576 + 288 + k] = 0;
}

__global__ __launch_bounds__(256)
void gather_emb(const int* __restrict__ x, const float* __restrict__ emb,
                ushort_t* __restrict__ cat2) {
    int idx = blockIdx.x * 256 + threadIdx.x;
    int tok = idx / 192, c = idx % 192;
    int tokid = x[(size_t)tok * 289];
    float v = silu_f(emb[(size_t)tokid * TEDIM + c]);
    ushort_t hi, lo;
    split2(v, hi, lo);
    cat2[(size_t)tok * 1536 + c] = hi;
    cat2[(size_t)tok * 1536 + 768 + c] = lo;
}

__global__ __launch_bounds__(256)
void gemm3_enc(const ushort_t* __restrict__ A2, const ushort_t* __restrict__ B2,
               const float* __restrict__ bc, ushort_t* __restrict__ cat2) {
    __shared__ __align__(16) ushort_t lds[4 * 4096];
    const int tid = threadIdx.x;
    const int bm = blockIdx.y * 128, bn = blockIdx.x * 128;
    const int w = tid >> 6, l = tid & 63;
    const int wm = (w & 1) * 64, wn = (w >> 1) * 64;
    const int Kp = 288;

    f32x4 acc[4][4];
    #pragma unroll
    for (int i = 0; i < 4; ++i)
        #pragma unroll
        for (int j = 0; j < 4; ++j) acc[i][j] = (f32x4){0.f, 0.f, 0.f, 0.f};

    const int r0 = tid >> 2, k8 = (tid & 3) * 8;
    const ushort_t* gA0 = A2 + (size_t)(bm + r0) * 576 + k8;
    const ushort_t* gA1 = A2 + (size_t)(bm + 64 + r0) * 576 + k8;
    const ushort_t* gB0 = B2 + (size_t)(bn + r0) * 576 + k8;
    const ushort_t* gB1 = B2 + (size_t)(bn + 64 + r0) * 576 + k8;
    ushort_t* l0 = lds + tid * 8;
    ushort_t* l1 = lds + 2048 + tid * 8;
    const int fr = l & 15, fk = (l >> 4) * 8;

    for (int kt = 0; kt < Kp; kt += 32) {
        gl_lds16(gA0 + kt, l0);
        gl_lds16(gA1 + kt, l1);
        gl_lds16(gA0 + kt + Kp, l0 + 4096);
        gl_lds16(gA1 + kt + Kp, l1 + 4096);
        gl_lds16(gB0 + kt, l0 + 8192);
        gl_lds16(gB1 + kt, l1 + 8192);
        gl_lds16(gB0 + kt + Kp, l0 + 12288);
        gl_lds16(gB1 + kt + Kp, l1 + 12288);
        __syncthreads();
        bf16x8 ahi[4], alo[4], bhi[4], blo[4];
        #pragma unroll
        for (int i = 0; i < 4; ++i) {
            int ra = (wm + i * 16 + fr) * 32 + fk;
            int rb = (wn + i * 16 + fr) * 32 + fk;
            ahi[i] = *(const bf16x8*)&lds[ra];
            alo[i] = *(const bf16x8*)&lds[4096 + ra];
            bhi[i] = *(const bf16x8*)&lds[8192 + rb];
            blo[i] = *(const bf16x8*)&lds[12288 + rb];
        }
        #pragma unroll
        for (int i = 0; i < 4; ++i)
            #pragma unroll
            for (int j = 0; j < 4; ++j) {
                acc[i][j] = __builtin_amdgcn_mfma_f32_16x16x32_bf16(ahi[i], bhi[j], acc[i][j], 0, 0, 0);
                acc[i][j] = __builtin_amdgcn_mfma_f32_16x16x32_bf16(ahi[i], blo[j], acc[i][j], 0, 0, 0);
                acc[i][j] = __builtin_amdgcn_mfma_f32_16x16x32_bf16(alo[i], bhi[j], acc[i][j], 0, 0, 0);
            }
        __syncthreads();
    }

    const int er = (l >> 4) * 4, ec = l & 15;
    #pragma unroll
    for (int i = 0; i < 4; ++i)
        #pragma unroll
        for (int j = 0; j < 4; ++j)
            #pragma unroll
            for (int r = 0; r < 4; ++r) {
                int gm = bm + wm + i * 16 + er + r;
                int gn = bn + wn + j * 16 + ec;
                if (gn < 576) {
                    float v = silu_f(acc[i][j][r] + bc[gn]);
                    ushort_t hi, lo;
                    split2(v, hi, lo);
                    cat2[(size_t)gm * 1536 + 192 + gn] = hi;
                    cat2[(size_t)gm * 1536 + 960 + gn] = lo;
                }
            }
}

// ---------------- bf16x3 MFMA GEMM (fp32 out + bias/res) ----------------------
__global__ __launch_bounds__(256)
void gemm3_kernel(const ushort_t* __restrict__ A2, int rsA,
                  const ushort_t* __restrict__ B2, int rsB,
                  const float* __restrict__ bias,
                  const float* __restrict__ res,
                  float* __restrict__ Cf, int rsC, int Kp) {
    __shared__ __align__(16) ushort_t lds[4 * 4096];
    const int tid = threadIdx.x;
    const int bm = blockIdx.y * 128, bn = blockIdx.x * 128;
    const int w = tid >> 6, l = tid & 63;
    const int wm = (w & 1) * 64, wn = (w >> 1) * 64;

    f32x4 acc[4][4];
    #pragma unroll
    for (int i = 0; i < 4; ++i)
        #pragma unroll
        for (int j = 0; j < 4; ++j) acc[i][j] = (f32x4){0.f, 0.f, 0.f, 0.f};

    const int r0 = tid >> 2, k8 = (tid & 3) * 8;
    const ushort_t* gA0 = A2 + (size_t)(bm + r0) * rsA + k8;
    const ushort_t* gA1 = A2 + (size_t)(bm + 64 + r0) * rsA + k8;
    const ushort_t* gB0 = B2 + (size_t)(bn + r0) * rsB + k8;
    const ushort_t* gB1 = B2 + (size_t)(bn + 64 + r0) * rsB + k8;
    ushort_t* l0 = lds + tid * 8;
    ushort_t* l1 = lds + 2048 + tid * 8;
    const int fr = l & 15, fk = (l >> 4) * 8;

    for (int kt = 0; kt < Kp; kt += 32) {
        gl_lds16(gA0 + kt, l0);
        gl_lds16(gA1 + kt, l1);
        gl_lds16(gA0 + kt + Kp, l0 + 4096);
        gl_lds16(gA1 + kt + Kp, l1 + 4096);
        gl_lds16(gB0 + kt, l0 + 8192);
        gl_lds16(gB1 + kt, l1 + 8192);
        gl_lds16(gB0 + kt + Kp, l0 + 12288);
        gl_lds16(gB1 + kt + Kp, l1 + 12288);
        __syncthreads();

        bf16x8 ahi[4], alo[4], bhi[4], blo[4];
        #pragma unroll
        for (int i = 0; i < 4; ++i) {
            int ra = (wm + i * 16 + fr) * 32 + fk;
            int rb = (wn + i * 16 + fr) * 32 + fk;
            ahi[i] = *(const bf16x8*)&lds[ra];
            alo[i] = *(const bf16x8*)&lds[4096 + ra];
            bhi[i] = *(const bf16x8*)&lds[8192 + rb];
            blo[i] = *(const bf16x8*)&lds[12288 + rb];
        }
        #pragma unroll
        for (int i = 0; i < 4; ++i)
            #pragma unroll
            for (int j = 0; j < 4; ++j) {
                acc[i][j] = __builtin_amdgcn_mfma_f32_16x16x32_bf16(ahi[i], bhi[j], acc[i][j], 0, 0, 0);
                acc[i][j] = __builtin_amdgcn_mfma_f32_16x16x32_bf16(ahi[i], blo[j], acc[i][j], 0, 0, 0);
                acc[i][j] = __builtin_amdgcn_mfma_f32_16x16x32_bf16(alo[i], bhi[j], acc[i][j], 0, 0, 0);
            }
        __syncthreads();
    }

    const int er = (l >> 4) * 4, ec = l & 15;
    #pragma unroll
    for (int i = 0; i < 4; ++i)
        #pragma unroll
        for (int j = 0; j < 4; ++j)
            #pragma unroll
            for (int r = 0; r < 4; ++r) {
                int gm = bm + wm + i * 16 + er + r;
                int gn = bn + wn + j * 16 + ec;
                float v = acc[i][j][r];
                if (bias) v += bias[gn];
                if (res) v += res[(size_t)gm * rsC + gn];
                Cf[(size_t)gm * rsC + gn] = v;
            }
}

// ---------------- fused GLU GEMM ----------------------------------------------
__global__ __launch_bounds__(256)
void gemm_glu3(const ushort_t* __restrict__ A2,
               const ushort_t* __restrict__ W1, const ushort_t* __restrict__ W3,
               const float* __restrict__ b1, const float* __restrict__ b3,
               ushort_t* __restrict__ C2) {
    __shared__ __align__(16) ushort_t lds[6 * 4096];
    const int tid = threadIdx.x;
    const int bm = blockIdx.y * 128, bn = blockIdx.x * 128;
    const int w = tid >> 6, l = tid & 63;
    const int wm = (w & 1) * 64, wn = (w >> 1) * 64;
    const int Kp = 512;

    f32x4 acc1[4][4], acc3[4][4];
    #pragma unroll
    for (int i = 0; i < 4; ++i)
        #pragma unroll
        for (int j = 0; j < 4; ++j) {
            acc1[i][j] = (f32x4){0.f, 0.f, 0.f, 0.f};
            acc3[i][j] = (f32x4){0.f, 0.f, 0.f, 0.f};
        }

    const int r0 = tid >> 2, k8 = (tid & 3) * 8;
    const ushort_t* gA0 = A2 + (size_t)(bm + r0) * 1024 + k8;
    const ushort_t* gA1 = A2 + (size_t)(bm + 64 + r0) * 1024 + k8;
    const ushort_t* g10 = W1 + (size_t)(bn + r0) * 1024 + k8;
    const ushort_t* g11 = W1 + (size_t)(bn + 64 + r0) * 1024 + k8;
    const ushort_t* g30 = W3 + (size_t)(bn + r0) * 1024 + k8;
    const ushort_t* g31 = W3 + (size_t)(bn + 64 + r0) * 1024 + k8;
    ushort_t* l0 = lds + tid * 8;
    ushort_t* l1 = lds + 2048 + tid * 8;
    const int fr = l & 15, fk = (l >> 4) * 8;

    for (int kt = 0; kt < Kp; kt += 32) {
        gl_lds16(gA0 + kt, l0);
        gl_lds16(gA1 + kt, l1);
        gl_lds16(gA0 + kt + Kp, l0 + 4096);
        gl_lds16(gA1 + kt + Kp, l1 + 4096);
        gl_lds16(g10 + kt, l0 + 8192);
        gl_lds16(g11 + kt, l1 + 8192);
        gl_lds16(g10 + kt + Kp, l0 + 12288);
        gl_lds16(g11 + kt + Kp, l1 + 12288);
        gl_lds16(g30 + kt, l0 + 16384);
        gl_lds16(g31 + kt, l1 + 16384);
        gl_lds16(g30 + kt + Kp, l0 + 20480);
        gl_lds16(g31 + kt + Kp, l1 + 20480);
        __syncthreads();

        bf16x8 ahi[4], alo[4];
        #pragma unroll
        for (int i = 0; i < 4; ++i) {
            int ra = (wm + i * 16 + fr) * 32 + fk;
            ahi[i] = *(const bf16x8*)&lds[ra];
            alo[i] = *(const bf16x8*)&lds[4096 + ra];
        }
        #pragma unroll
        for (int j = 0; j < 4; ++j) {
            int rb = (wn + j * 16 + fr) * 32 + fk;
            bf16x8 w1h = *(const bf16x8*)&lds[8192 + rb];
            bf16x8 w1l = *(const bf16x8*)&lds[12288 + rb];
            bf16x8 w3h = *(const bf16x8*)&lds[16384 + rb];
            bf16x8 w3l = *(const bf16x8*)&lds[20480 + rb];
            #pragma unroll
            for (int i = 0; i < 4; ++i) {
                acc1[i][j] = __builtin_amdgcn_mfma_f32_16x16x32_bf16(ahi[i], w1h, acc1[i][j], 0, 0, 0);
                acc1[i][j] = __builtin_amdgcn_mfma_f32_16x16x32_bf16(ahi[i], w1l, acc1[i][j], 0, 0, 0);
                acc1[i][j] = __builtin_amdgcn_mfma_f32_16x16x32_bf16(alo[i], w1h, acc1[i][j], 0, 0, 0);
                acc3[i][j] = __builtin_amdgcn_mfma_f32_16x16x32_bf16(ahi[i], w3h, acc3[i][j], 0, 0, 0);
                acc3[i][j] = __builtin_amdgcn_mfma_f32_16x16x32_bf16(ahi[i], w3l, acc3[i][j], 0, 0, 0);
                acc3[i][j] = __builtin_amdgcn_mfma_f32_16x16x32_bf16(alo[i], w3h, acc3[i][j], 0, 0, 0);
            }
        }
        __syncthreads();
    }

    const int er = (l >> 4) * 4, ec = l & 15;
    #pragma unroll
    for (int i = 0; i < 4; ++i)
        #pragma unroll
        for (int j = 0; j < 4; ++j)
            #pragma unroll
            for (int r = 0; r < 4; ++r) {
                int gm = bm + wm + i * 16 + er + r;
                int gn = bn + wn + j * 16 + ec;
                if (gn < KP2) {
                    float u1 = acc1[i][j][r], u3 = acc3[i][j][r];
                    if (gn < DFF) { u1 += b1[gn]; u3 += b3[gn]; }
                    float g = silu_f(u1) * u3;
                    ushort_t hi, lo;
                    split2(g, hi, lo);
                    C2[(size_t)gm * (2 * KP2) + gn] = hi;
                    C2[(size_t)gm * (2 * KP2) + KP2 + gn] = lo;
                }
            }
}

// ---------------- per-token reductions (wave-per-token) -----------------------
__global__ __launch_bounds__(256)
void rms_kernel(const float* __restrict__ h, const float* __restrict__ w,
                ushort_t* __restrict__ out2) {
    int wid = threadIdx.x >> 6, lane = threadIdx.x & 63;
    int t = blockIdx.x * 4 + wid;
    const float* hp = h + (size_t)t * 512;
    float xv[8];
    float ss = 0.0f;
    #pragma unroll
    for (int u = 0; u < 8; ++u) { xv[u] = hp[u * 64 + lane]; ss += xv[u] * xv[u]; }
    #pragma unroll
    for (int off = 32; off > 0; off >>= 1) ss += __shfl_xor(ss, off, 64);
    float inv = rsqrtf(ss * (1.0f / 512.0f) + 1.1920929e-07f);
    ushort_t* op = out2 + (size_t)t * 1024;
    #pragma unroll
    for (int u = 0; u < 8; ++u) {
        ushort_t hi, lo;
        split2(xv[u] * inv * w[u * 64 + lane], hi, lo);
        op[u * 64 + lane] = hi;
        op[512 + u * 64 + lane] = lo;
    }
}

__global__ __launch_bounds__(256)
void ln_silu_kernel(const float* __restrict__ h, const float* __restrict__ w,
                    const float* __restrict__ b, float* __restrict__ out) {
    int wid = threadIdx.x >> 6, lane = threadIdx.x & 63;
    int t = blockIdx.x * 4 + wid;
    const float* hp = h + (size_t)t * 512;
    float xv[8];
    float s = 0.0f;
    #pragma unroll
    for (int u = 0; u < 8; ++u) { xv[u] = hp[u * 64 + lane]; s += xv[u]; }
    #pragma unroll
    for (int off = 32; off > 0; off >>= 1) s += __shfl_xor(s, off, 64);
    float m = s * (1.0f / 512.0f);
    float v = 0.0f;
    #pragma unroll
    for (int u = 0; u < 8; ++u) { xv[u] -= m; v += xv[u] * xv[u]; }
    #pragma unroll
    for (int off = 32; off > 0; off >>= 1) v += __shfl_xor(v, off, 64);
    float inv = rsqrtf(v * (1.0f / 512.0f) + 1e-5f);
    float* op = out + (size_t)t * 512;
    #pragma unroll
    for (int u = 0; u < 8; ++u)
        op[u * 64 + lane] = silu_f(xv[u] * inv * w[u * 64 + lane] + b[u * 64 + lane]);
}

// ---------------- MFMA local attention ----------------------------------------
// grid (16,8,4), 256 thr = 4 waves x 32 queries. bf16x3 QK^T and PV; online
// softmax in C-layout; P through per-wave LDS region (C->A layout round trip).
__global__ __launch_bounds__(256)
void attn_kernel(const float* __restrict__ qkv, const float* __restrict__ ct,
                 const float* __restrict__ st, ushort_t* __restrict__ attn2) {
    __shared__ __align__(16) ushort_t Khi[32 * 64], Klo[32 * 64];
    __shared__ __align__(16) ushort_t Vthi[64 * 32], Vtlo[64 * 32];
    __shared__ __align__(16) ushort_t Phi[128 * 32], Plo[128 * 32];
    const int nb = blockIdx.x, head = blockIdx.y, b = blockIdx.z;
    const int tid = threadIdx.x;
    const int w = tid >> 6, lane = tid & 63;
    const int quad = lane >> 4, lc = lane & 15;

    // Q fragments (A-layout) with RoPE + 1/8 scale, split hi/lo
    bf16x8 qhi[2][2], qlo[2][2];
    #pragma unroll
    for (int i = 0; i < 2; ++i) {
        int qtok = nb * 128 + w * 32 + i * 16 + lc;
        const float* qp = qkv + ((size_t)(b * LSEQ + qtok)) * 1536 + head * 64;
        #pragma unroll
        for (int s = 0; s < 2; ++s) {
            float4 a = *(const float4*)&qp[s * 32 + quad * 8];
            float4 bq = *(const float4*)&qp[s * 32 + quad * 8 + 4];
            float4 c4 = *(const float4*)&ct[qtok * 32 + s * 16 + quad * 4];
            float4 s4 = *(const float4*)&st[qtok * 32 + s * 16 + quad * 4];
            float e[8];
            e[0] = (a.x * c4.x - a.y * s4.x) * 0.125f;
            e[1] = (a.x * s4.x + a.y * c4.x) * 0.125f;
            e[2] = (a.z * c4.y - a.w * s4.y) * 0.125f;
            e[3] = (a.z * s4.y + a.w * c4.y) * 0.125f;
            e[4] = (bq.x * c4.z - bq.y * s4.z) * 0.125f;
            e[5] = (bq.x * s4.z + bq.y * c4.z) * 0.125f;
            e[6] = (bq.z * c4.w - bq.w * s4.w) * 0.125f;
            e[7] = (bq.z * s4.w + bq.w * c4.w) * 0.125f;
            union { bf16x8 v; ushort_t u[8]; } hh, ll;
            #pragma unroll
            for (int d = 0; d < 8; ++d) split2(e[d], hh.u[d], ll.u[d]);
            qhi[i][s] = hh.v;
            qlo[i][s] = ll.v;
        }
    }

    f32x4 acc[2][4];
    float mrun[2][4], lrun[2][4];
    #pragma unroll
    for (int i = 0; i < 2; ++i) {
        #pragma unroll
        for (int j = 0; j < 4; ++j) acc[i][j] = (f32x4){0.f, 0.f, 0.f, 0.f};
        #pragma unroll
        for (int r = 0; r < 4; ++r) { mrun[i][r] = -1e30f; lrun[i][r] = 0.0f; }
    }

    const int c0 = (nb == 0) ? 4 : 0;
    for (int c = c0; c < 8; ++c) {
        // ---- stage: K rows (RoPE'd) + V^T, swizzled ----
        {
            int key = tid >> 3, g = tid & 7;
            int ktok = nb * 128 - 128 + c * 32 + key;
            const float* kp = qkv + ((size_t)(b * LSEQ + ktok)) * 1536 + 512 + head * 64 + g * 8;
            float4 a = *(const float4*)kp;
            float4 bq = *(const float4*)(kp + 4);
            float4 c4 = *(const float4*)&ct[ktok * 32 + g * 4];
            float4 s4 = *(const float4*)&st[ktok * 32 + g * 4];
            float e[8];
            e[0] = a.x * c4.x - a.y * s4.x;
            e[1] = a.x * s4.x + a.y * c4.x;
            e[2] = a.z * c4.y - a.w * s4.y;
            e[3] = a.z * s4.y + a.w * c4.y;
            e[4] = bq.x * c4.z - bq.y * s4.z;
            e[5] = bq.x * s4.z + bq.y * c4.z;
            e[6] = bq.z * c4.w - bq.w * s4.w;
            e[7] = bq.z * s4.w + bq.w * c4.w;
            union { bf16x8 v; ushort_t u[8]; } hh, ll;
            #pragma unroll
            for (int d = 0; d < 8; ++d) split2(e[d], hh.u[d], ll.u[d]);
            int sg = g ^ (key & 7);
            *(bf16x8*)&Khi[key * 64 + sg * 8] = hh.v;
            *(bf16x8*)&Klo[key * 64 + sg * 8] = ll.v;

            const float* vp = kp + 512;
            float4 va = *(const float4*)vp;
            float4 vb = *(const float4*)(vp + 4);
            float ve[8] = {va.x, va.y, va.z, va.w, vb.x, vb.y, vb.z, vb.w};
            int kg = key >> 3, k7 = key & 7;
            #pragma unroll
            for (int d = 0; d < 8; ++d) {
                ushort_t vh, vl;
                split2(ve[d], vh, vl);
                int dim = g * 8 + d;
                int addr = dim * 32 + (((kg + (dim >> 1)) & 3) * 8) + k7;
                Vthi[addr] = vh;
                Vtlo[addr] = vl;
            }
        }
        __syncthreads();

        // ---- S = Q K^T ----
        f32x4 sf[2][2];
        #pragma unroll
        for (int i = 0; i < 2; ++i)
            #pragma unroll
            for (int t = 0; t < 2; ++t) sf[i][t] = (f32x4){0.f, 0.f, 0.f, 0.f};
        #pragma unroll
        for (int t = 0; t < 2; ++t) {
            #pragma unroll
            for (int s = 0; s < 2; ++s) {
                int row = t * 16 + lc;
                int sg = (s * 4 + quad) ^ (row & 7);
                bf16x8 kh = *(const bf16x8*)&Khi[row * 64 + sg * 8];
                bf16x8 kl = *(const bf16x8*)&Klo[row * 64 + sg * 8];
                #pragma unroll
                for (int i = 0; i < 2; ++i) {
                    sf[i][t] = __builtin_amdgcn_mfma_f32_16x16x32_bf16(qhi[i][s], kh, sf[i][t], 0, 0, 0);
                    sf[i][t] = __builtin_amdgcn_mfma_f32_16x16x32_bf16(qhi[i][s], kl, sf[i][t], 0, 0, 0);
                    sf[i][t] = __builtin_amdgcn_mfma_f32_16x16x32_bf16(qlo[i][s], kh, sf[i][t], 0, 0, 0);
                }
            }
        }

        // ---- masked online softmax, write split P ----
        #pragma unroll
        for (int i = 0; i < 2; ++i) {
            #pragma unroll
            for (int r = 0; r < 4; ++r) {
                int qq = w * 32 + i * 16 + quad * 4 + r;
                float rm = -1e30f;
                #pragma unroll
                for (int t = 0; t < 2; ++t) {
                    int key = c * 32 + t * 16 + lc;
                    bool valid = (key >= qq) && (key <= qq + 128) && (nb > 0 || key >= 128);
                    float sv = valid ? sf[i][t][r] : -1e30f;
                    sf[i][t][r] = sv;
                    rm = fmaxf(rm, sv);
                }
                #pragma unroll
                for (int xm = 1; xm < 16; xm <<= 1)
                    rm = fmaxf(rm, __shfl_xor(rm, xm, 64));
                float mn = fmaxf(mrun[i][r], rm);
                float alpha = __expf(mrun[i][r] - mn);
                lrun[i][r] *= alpha;
                #pragma unroll
                for (int j = 0; j < 4; ++j) acc[i][j][r] *= alpha;
                float rs = 0.0f;
                #pragma unroll
                for (int t = 0; t < 2; ++t) {
                    int key = c * 32 + t * 16 + lc;
                    bool valid = (key >= qq) && (key <= qq + 128) && (nb > 0 || key >= 128);
                    float p = valid ? __expf(sf[i][t][r] - mn) : 0.0f;
                    rs += p;
                    ushort_t ph, pl;
                    split2(p, ph, pl);
                    int col = t * 16 + lc;
                    int addr = qq * 32 + ((((col >> 3) + (qq >> 1)) & 3) * 8) + (col & 7);
                    Phi[addr] = ph;
                    Plo[addr] = pl;
                }
                #pragma unroll
                for (int xm = 1; xm < 16; xm <<= 1)
                    rs += __shfl_xor(rs, xm, 64);
                lrun[i][r] += rs;
                mrun[i][r] = mn;
            }
        }

        // ---- O += P V ----
        bf16x8 ph[2], pl[2];
        #pragma unroll
        for (int i = 0; i < 2; ++i) {
            int row = w * 32 + i * 16 + lc;
            int sg = (quad + (row >> 1)) & 3;
            ph[i] = *(const bf16x8*)&Phi[row * 32 + sg * 8];
            pl[i] = *(const bf16x8*)&Plo[row * 32 + sg * 8];
        }
        #pragma unroll
        for (int j = 0; j < 4; ++j) {
            int dim = j * 16 + lc;
            int sg = (quad + (dim >> 1)) & 3;
            bf16x8 vh = *(const bf16x8*)&Vthi[dim * 32 + sg * 8];
            bf16x8 vl = *(const bf16x8*)&Vtlo[dim * 32 + sg * 8];
            #pragma unroll
            for (int i = 0; i < 2; ++i) {
                acc[i][j] = __builtin_amdgcn_mfma_f32_16x16x32_bf16(ph[i], vh, acc[i][j], 0, 0, 0);
                acc[i][j] = __builtin_amdgcn_mfma_f32_16x16x32_bf16(ph[i], vl, acc[i][j], 0, 0, 0);
                acc[i][j] = __builtin_amdgcn_mfma_f32_16x16x32_bf16(pl[i], vh, acc[i][j], 0, 0, 0);
            }
        }
        __syncthreads();
    }

    // ---- epilogue: normalize, split, store ----
    #pragma unroll
    for (int i = 0; i < 2; ++i) {
        #pragma unroll
        for (int r = 0; r < 4; ++r) {
            int qtok = nb * 128 + w * 32 + i * 16 + quad * 4 + r;
            size_t base = ((size_t)(b * LSEQ + qtok)) * 1024 + head * 64;
            float inv = 1.0f / lrun[i][r];
            #pragma unroll
            for (int j = 0; j < 4; ++j) {
                float v = acc[i][j][r] * inv;
                ushort_t hi, lo;
                split2(v, hi, lo);
                attn2[base + j * 16 + lc] = hi;
                attn2[base + 512 + j * 16 + lc] = lo;
            }
        }
    }
}

// ---------------- head: LN + silu + 31-dim head + postprocess -----------------
__global__ __launch_bounds__(256)
void head_kernel(const float* __restrict__ h, const float* __restrict__ lw,
                 const float* __restrict__ lb, const float* __restrict__ head_w,
                 const float* __restrict__ head_b, float* __restrict__ out) {
    int wid = threadIdx.x >> 6, lane = threadIdx.x & 63;
    int t = blockIdx.x * 4 + wid;
    __shared__ float yv[4][32];
    const float* xr = h + (size_t)t * 512;
    float xv[8];
    float s = 0.0f;
    #pragma unroll
    for (int u = 0; u < 8; ++u) { xv[u] = xr[u * 64 + lane]; s += xv[u]; }
    #pragma unroll
    for (int off = 32; off > 0; off >>= 1) s += __shfl_xor(s, off, 64);
    float m = s * (1.0f / 512.0f);
    float var = 0.0f;
    #pragma unroll
    for (int u = 0; u < 8; ++u) { xv[u] -= m; var += xv[u] * xv[u]; }
    #pragma unroll
    for (int off = 32; off > 0; off >>= 1) var += __shfl_xor(var, off, 64);
    float inv = rsqrtf(var * (1.0f / 512.0f) + 1e-5f);
    #pragma unroll
    for (int u = 0; u < 8; ++u)
        xv[u] = silu_f(xv[u] * inv * lw[u * 64 + lane] + lb[u * 64 + lane]);

    for (int j = 0; j < 31; ++j) {
        const float* wr = head_w + (size_t)j * 512;
        float p = 0.0f;
        #pragma unroll
        for (int u = 0; u < 8; ++u) p += xv[u] * wr[u * 64 + lane];
        #pragma unroll
        for (int off = 32; off > 0; off >>= 1) p += __shfl_down(p, off, 64);
        if (lane == 0) yv[wid][j] = p + head_b[j];
    }
    if (lane == 0) {
        float* y = yv[wid];
        float* op = out + (size_t)t * 40;
        int am = 0; float best = y[0];
        for (int j = 1; j < 11; ++j) if (y[j] > best) { best = y[j]; am = j; }
        float fc_reg = softplus_f(y[11]);
        op[0] = (am < 10) ? (float)(am + 1) : fc_reg;
        for (int j = 0; j < 11; ++j) op[1 + j] = y[j];
        op[12] = fc_reg;
        int am2 = 0; float best2 = y[12];
        for (int j = 1; j < 11; ++j) if (y[12 + j] > best2) { best2 = y[12 + j]; am2 = j; }
        float ec_reg = softplus_f(y[23]);
        op[13] = (am2 < 10) ? (float)(am2 + 1) : ec_reg;
        for (int j = 0; j < 11; ++j) op[14 + j] = y[12 + j];
        op[25] = ec_reg;
        float bm_log = y[24];
        op[26] = 1.0f / (1.0f + expf(-bm_log));
        float mi = fmaxf(y[25], fmaxf(y[26], y[27]));
        float e0 = expf(y[25] - mi), e1 = expf(y[26] - mi), e2 = expf(y[27] - mi);
        float si = e0 + e1 + e2;
        op[27] = e0 / si; op[28] = e1 / si; op[29] = e2 / si;
        float md = fmaxf(y[28], fmaxf(y[29], y[30]));
        float d0 = expf(y[28] - md), d1 = expf(y[29] - md), d2 = expf(y[30] - md);
        float sd = d0 + d1 + d2;
        op[30] = d0 / sd; op[31] = d1 / sd; op[32] = d2 / sd;
        op[33] = bm_log;
        op[34] = y[25]; op[35] = y[26]; op[36] = y[27];
        op[37] = y[28]; op[38] = y[29]; op[39] = y[30];
    }
}

// ---------------- launch -------------------------------------------------------
extern "C" void kernel_launch(void* const* d_in, const int* in_sizes, int n_in,
                              void* d_out, int out_size, void* d_ws, size_t ws_size,
                              hipStream_t stream) {
    const int*   x        = (const int*)d_in[0];
    const float* emb      = (const float*)d_in[1];
    const float* reg_w    = (const float*)d_in[2];
    const float* reg_b    = (const float*)d_in[3];
    const float* br_w     = (const float*)d_in[4];
    const float* br_b     = (const float*)d_in[5];
    const float* sh_w     = (const float*)d_in[6];
    const float* sh_b     = (const float*)d_in[7];
    const float* inst_w   = (const float*)d_in[8];
    const float* inst_b   = (const float*)d_in[9];
    const float* enc_ln_w = (const float*)d_in[10];
    const float* enc_ln_b = (const float*)d_in[11];
    const float* qkv_w    = (const float*)d_in[12];
    const float* out_w    = (const float*)d_in[13];
    const float* out_b    = (const float*)d_in[14];
    const float* w1_w     = (const float*)d_in[15];
    const float* w1_b     = (const float*)d_in[16];
    const float* w3_w     = (const float*)d_in[17];
    const float* w3_b     = (const float*)d_in[18];
    const float* w2_w     = (const float*)d_in[19];
    const float* w2_b     = (const float*)d_in[20];
    const float* n1_w     = (const float*)d_in[21];
    const float* n2_w     = (const float*)d_in[22];
    const float* hl_w     = (const float*)d_in[23];
    const float* hl_b     = (const float*)d_in[24];
    const float* head_w   = (const float*)d_in[25];
    const float* head_b   = (const float*)d_in[26];

    char* ws = (char*)d_ws;
    size_t off = 0;
    ushort_t* inst2 = (ushort_t*)(ws + off); off += (size_t)512 * 1536 * 2;
    ushort_t* qkv2  = (ushort_t*)(ws + off); off += (size_t)3 * 1536 * 1024 * 2;
    ushort_t* out2w = (ushort_t*)(ws + off); off += (size_t)3 * 512 * 1024 * 2;
    ushort_t* w1s   = (ushort_t*)(ws + off); off += (size_t)3 * DFFP * 1024 * 2;
    ushort_t* w3s   = (ushort_t*)(ws + off); off += (size_t)3 * DFFP * 1024 * 2;
    ushort_t* w2s   = (ushort_t*)(ws + off); off += (size_t)3 * 512 * (2 * KP2) * 2;
    float*    ct    = (float*)(ws + off);    off += (size_t)LSEQ * 32 * 4;
    float*    st    = (float*)(ws + off);    off += (size_t)LSEQ * 32 * 4;
    float*    h     = (float*)(ws + off);    off += (size_t)T_TOK * 512 * 4;
    ushort_t* x2    = (ushort_t*)(ws + off); off += (size_t)T_TOK * 1024 * 2;
    ushort_t* attn2 = (ushort_t*)(ws + off); off += (size_t)T_TOK * 1024 * 2;
    float*    qkvb  = (float*)(ws + off);    off += (size_t)T_TOK * 1536 * 4;
    ushort_t* cat2  = (ushort_t*)(ws + off); off += (size_t)T_TOK * (2 * KP2) * 2;
    ushort_t* Wc2   = (ushort_t*)(ws + off); off += (size_t)640 * 576 * 2;
    float*    bc    = (float*)(ws + off);    off += 640 * 4;
    ushort_t* g2    = cat2;
    ushort_t* X2    = (ushort_t*)qkvb;

    rope_kernel<<<256, 256, 0, stream>>>(ct, st);
    build_encw<<<640, 256, 0, stream>>>(reg_w, reg_b, br_w, br_b, sh_w, sh_b, Wc2, bc);
    pack_x<<<(T_TOK * 288) / 256, 256, 0, stream>>>(x, X2);
    gather_emb<<<(T_TOK * 192) / 256, 256, 0, stream>>>(x, emb, cat2);
    splitw_kernel<<<dim3(3, 512), 256, 0, stream>>>(inst_w, inst2, 512, 768, 768);
    splitw_qkv_kernel<<<dim3(2, 1536, 3), 256, 0, stream>>>(qkv_w, qkv2);
    splitw_kernel<<<dim3(2, 3 * 512), 256, 0, stream>>>(out_w, out2w, 3 * 512, 512, 512);
    for (int l = 0; l < NLAYER; ++l) {
        splitw_kernel<<<dim3(2, DFFP), 256, 0, stream>>>(
            w1_w + (size_t)l * DFF * 512, w1s + (size_t)l * DFFP * 1024, DFF, 512, 512);
        splitw_kernel<<<dim3(2, DFFP), 256, 0, stream>>>(
            w3_w + (size_t)l * DFF * 512, w3s + (size_t)l * DFFP * 1024, DFF, 512, 512);
        splitw_kernel<<<dim3(6, 512), 256, 0, stream>>>(
            w2_w + (size_t)l * 512 * DFF, w2s + (size_t)l * 512 * (2 * KP2), 512, DFF, KP2);
    }

    gemm3_enc<<<dim3(5, 64), 256, 0, stream>>>(X2, Wc2, bc, cat2);
    gemm3_kernel<<<dim3(4, 64), 256, 0, stream>>>(
        cat2, 1536, inst2, 1536, inst_b, nullptr, h, 512, 768);
    ln_silu_kernel<<<T_TOK / 4, 256, 0, stream>>>(h, enc_ln_w, enc_ln_b, h);

    for (int l = 0; l < NLAYER; ++l) {
        rms_kernel<<<T_TOK / 4, 256, 0, stream>>>(h, n1_w + l * 512, x2);
        gemm3_kernel<<<dim3(12, 64), 256, 0, stream>>>(
            x2, 1024, qkv2 + (size_t)l * 1536 * 1024, 1024, nullptr, nullptr,
            qkvb, 1536, 512);
        {
            dim3 g(NBLK, NHEAD, BATCH);
            attn_kernel<<<g, 256, 0, stream>>>(qkvb, ct, st, attn2);
        }
        gemm3_kernel<<<dim3(4, 64), 256, 0, stream>>>(
            attn2, 1024, out2w + (size_t)l * 512 * 1024, 1024, out_b + l * 512,
            h, h, 512, 512);
        rms_kernel<<<T_TOK / 4, 256, 0, stream>>>(h, n2_w + l * 512, x2);
        gemm_glu3<<<dim3(11, 64), 256, 0, stream>>>(
            x2, w1s + (size_t)l * DFFP * 1024, w3s + (size_t)l * DFFP * 1024,
            w1_b + l * DFF, w3_b + l * DFF, g2);
        gemm3_kernel<<<dim3(4, 64), 256, 0, stream>>>(
            g2, 2 * KP2, w2s + (size_t)l * 512 * (2 * KP2), 2 * KP2, w2_b + l * 512,
            h, h, 512, KP2);
    }

    head_kernel<<<T_TOK / 4, 256, 0, stream>>>(h, hl_w, hl_b, head_w, head_b,
                                               (float*)d_out);
}

// Round 6
// 1346.141 us; speedup vs baseline: 4.2181x; 1.0430x over previous
//
#include <hip/hip_runtime.h>
#include <hip/hip_bf16.h>
#include <math.h>

#define T_TOK 8192
#define DMODEL 512
#define NHEAD 8
#define TEDIM 192
#define DFF 1365
#define DFFP 1408
#define KP2 1376
#define NLAYER 3
#define WINSZ 128
#define NBLK 16
#define LSEQ 2048
#define BATCH 4

typedef unsigned short ushort_t;
typedef __bf16 bf16x8 __attribute__((ext_vector_type(8)));
typedef float f32x4 __attribute__((ext_vector_type(4)));
typedef float f32x16 __attribute__((ext_vector_type(16)));

__device__ __forceinline__ float silu_f(float x) { return x / (1.0f + expf(-x)); }
__device__ __forceinline__ float softplus_f(float x) {
    return (x > 20.0f) ? x : log1pf(expf(x));
}

__device__ __forceinline__ ushort_t f2u(float x) {
    __hip_bfloat16 b = __float2bfloat16(x);
    return *reinterpret_cast<ushort_t*>(&b);
}
__device__ __forceinline__ float u2f(ushort_t u) {
    __hip_bfloat16 b = *reinterpret_cast<__hip_bfloat16*>(&u);
    return __bfloat162float(b);
}
__device__ __forceinline__ void split2(float x, ushort_t& hi, ushort_t& lo) {
    hi = f2u(x);
    lo = f2u(x - u2f(hi));
}

__device__ __forceinline__ void gl_lds16(const ushort_t* g, ushort_t* l) {
    __builtin_amdgcn_global_load_lds(
        (const __attribute__((address_space(1))) unsigned int*)g,
        (__attribute__((address_space(3))) unsigned int*)l, 16, 0, 0);
}

// ---------------- RoPE table ---------------------------------------------------
__global__ __launch_bounds__(256)
void rope_kernel(float* __restrict__ ct, float* __restrict__ st) {
    int idx = blockIdx.x * 256 + threadIdx.x;
    int tok = idx >> 5, p = idx & 31;
    float invf = powf(10000.0f, -(float)p * (1.0f / 32.0f));
    float sn, cs;
    sincosf((float)tok * invf, &sn, &cs);
    ct[idx] = cs;
    st[idx] = sn;
}

// ---------------- weight splits ------------------------------------------------
__global__ __launch_bounds__(256)
void splitw_kernel(const float* __restrict__ W, ushort_t* __restrict__ W2,
                   int N, int K, int Kp) {
    int n = blockIdx.y;
    int k = blockIdx.x * 256 + threadIdx.x;
    if (k >= Kp) return;
    float v = (n < N && k < K) ? W[(size_t)n * K + k] : 0.0f;
    ushort_t hi, lo;
    split2(v, hi, lo);
    W2[(size_t)n * (2 * Kp) + k] = hi;
    W2[(size_t)n * (2 * Kp) + Kp + k] = lo;
}

__global__ __launch_bounds__(256)
void splitw_qkv_kernel(const float* __restrict__ W, ushort_t* __restrict__ W2) {
    int l = blockIdx.z;
    int rr = blockIdx.y;
    int k = blockIdx.x * 256 + threadIdx.x;
    int h = rr / 192, rem = rr % 192;
    int dk = rem / 3, which = rem % 3;
    int rp = which * 512 + h * 64 + dk;
    float v = W[((size_t)l * 1536 + rr) * 512 + k];
    ushort_t hi, lo;
    split2(v, hi, lo);
    W2[((size_t)l * 1536 + rp) * 1024 + k] = hi;
    W2[((size_t)l * 1536 + rp) * 1024 + 512 + k] = lo;
}

// w1+w3, all layers in one launch. rows rr in [0, 3*DFFP)
__global__ __launch_bounds__(256)
void splitw_ffn(const float* __restrict__ w1, const float* __restrict__ w3,
                ushort_t* __restrict__ W1s, ushort_t* __restrict__ W3s) {
    int rr = blockIdx.y;
    int k = blockIdx.x * 256 + threadIdx.x;   // 0..511
    int lyr = rr / DFFP, n = rr % DFFP;
    bool ok = (n < DFF);
    float v1 = ok ? w1[((size_t)lyr * DFF + n) * 512 + k] : 0.0f;
    float v3 = ok ? w3[((size_t)lyr * DFF + n) * 512 + k] : 0.0f;
    ushort_t hi, lo;
    split2(v1, hi, lo);
    W1s[(size_t)rr * 1024 + k] = hi;
    W1s[(size_t)rr * 1024 + 512 + k] = lo;
    split2(v3, hi, lo);
    W3s[(size_t)rr * 1024 + k] = hi;
    W3s[(size_t)rr * 1024 + 512 + k] = lo;
}

// w2 all layers. rows rr in [0, 3*512)
__global__ __launch_bounds__(256)
void splitw_w2(const float* __restrict__ W, ushort_t* __restrict__ W2) {
    int rr = blockIdx.y;
    int k = blockIdx.x * 256 + threadIdx.x;
    if (k >= KP2) return;
    int lyr = rr >> 9, n = rr & 511;
    float v = (k < DFF) ? W[((size_t)lyr * 512 + n) * DFF + k] : 0.0f;
    ushort_t hi, lo;
    split2(v, hi, lo);
    W2[(size_t)rr * (2 * KP2) + k] = hi;
    W2[(size_t)rr * (2 * KP2) + KP2 + k] = lo;
}

// ---------------- encoder prep -------------------------------------------------
__global__ __launch_bounds__(256)
void build_encw(const float* __restrict__ reg_w, const float* __restrict__ reg_b,
                const float* __restrict__ br_w, const float* __restrict__ br_b,
                const float* __restrict__ sh_w, const float* __restrict__ sh_b,
                ushort_t* __restrict__ Wc2, float* __restrict__ bc) {
    int n = blockIdx.x;
    int tid = threadIdx.x;
    for (int k = tid; k < 288; k += 256) {
        float v = 0.0f;
        if (n < 192) {
            if (k < 64) v = reg_w[(size_t)n * 64 + k];
        } else if (n < 384) {
            if (k >= 256) v = br_w[(size_t)(n - 192) * 32 + (k - 256)];
        } else if (n < 576) {
            if (k >= 64 && k < 256) v = sh_w[(size_t)(n - 384) * 192 + (k - 64)];
        }
        ushort_t hi, lo;
        split2(v, hi, lo);
        Wc2[(size_t)n * 576 + k] = hi;
        Wc2[(size_t)n * 576 + 288 + k] = lo;
    }
    if (tid == 0) {
        float b = 0.0f;
        if (n < 192) b = reg_b[n];
        else if (n < 384) b = br_b[n - 192];
        else if (n < 576) b = sh_b[n - 384];
        bc[n] = b;
    }
}

// pack int features + gather embedding, one block per token
__global__ __launch_bounds__(256)
void prep_tok(const int* __restrict__ x, const float* __restrict__ emb,
              ushort_t* __restrict__ X2, ushort_t* __restrict__ cat2) {
    int tok = blockIdx.x;
    int tid = threadIdx.x;
    const int* xp = x + (size_t)tok * 289;
    for (int k = tid; k < 288; k += 256) {
        X2[(size_t)tok * 576 + k] = f2u((float)xp[1 + k]);
        X2[(size_t)tok * 576 + 288 + k] = 0;
    }
    int tokid = xp[0];
    for (int c = tid; c < 192; c += 256) {
        float v = silu_f(emb[(size_t)tokid * TEDIM + c]);
        ushort_t hi, lo;
        split2(v, hi, lo);
        cat2[(size_t)tok * 1536 + c] = hi;
        cat2[(size_t)tok * 1536 + 768 + c] = lo;
    }
}

// ======== 32x32x16 bf16x3 GEMM machinery ======================================
// LDS layout per buffer: [128 rows][32 k] ushort, with k-chunk (16B) XOR-swizzle
// by row&3 applied on the GLOBAL side at staging and compensated at frag read,
// keeping both global_load_lds (fixed lane-contiguous dst) and 32-row frag
// reads bank-conflict-free.
// C/D layout (verified): col = lane&31, row = (reg&3) + 8*(reg>>2) + 4*(lane>>5).

#define MFMA32(a, b, c) __builtin_amdgcn_mfma_f32_32x32x16_bf16(a, b, c, 0, 0, 0)

// ---------------- generic GEMM (fp32 out + bias/res); grid (64, Ntiles) -------
__global__ __launch_bounds__(256)
void gemm3_kernel(const ushort_t* __restrict__ A2, int rsA,
                  const ushort_t* __restrict__ B2, int rsB,
                  const float* __restrict__ bias,
                  const float* __restrict__ res,
                  float* __restrict__ Cf, int rsC, int Kp) {
    __shared__ __align__(16) ushort_t lds[4 * 4096];
    const int tid = threadIdx.x;
    const int bm = blockIdx.x * 128, bn = blockIdx.y * 128;
    const int w = tid >> 6, l = tid & 63;
    const int wm = (w & 1) * 64, wn = (w >> 1) * 64;

    f32x16 acc[2][2];
    #pragma unroll
    for (int i = 0; i < 2; ++i)
        #pragma unroll
        for (int j = 0; j < 2; ++j)
            #pragma unroll
            for (int r = 0; r < 16; ++r) acc[i][j][r] = 0.0f;

    const int r0 = tid >> 2;
    const int k8 = (((tid & 3) ^ (r0 & 3)) * 8);      // swizzled global chunk
    const ushort_t* gA0 = A2 + (size_t)(bm + r0) * rsA + k8;
    const ushort_t* gA1 = A2 + (size_t)(bm + 64 + r0) * rsA + k8;
    const ushort_t* gB0 = B2 + (size_t)(bn + r0) * rsB + k8;
    const ushort_t* gB1 = B2 + (size_t)(bn + 64 + r0) * rsB + k8;
    ushort_t* l0 = lds + tid * 8;
    ushort_t* l1 = lds + 2048 + tid * 8;

    const int ar = l & 31, qh = l >> 5;

    for (int kt = 0; kt < Kp; kt += 32) {
        gl_lds16(gA0 + kt, l0);
        gl_lds16(gA1 + kt, l1);
        gl_lds16(gA0 + kt + Kp, l0 + 4096);
        gl_lds16(gA1 + kt + Kp, l1 + 4096);
        gl_lds16(gB0 + kt, l0 + 8192);
        gl_lds16(gB1 + kt, l1 + 8192);
        gl_lds16(gB0 + kt + Kp, l0 + 12288);
        gl_lds16(gB1 + kt + Kp, l1 + 12288);
        __syncthreads();

        #pragma unroll
        for (int kh = 0; kh < 2; ++kh) {
            const int kq = kh * 2 + qh;
            bf16x8 ah[2], al_[2], bh[2], bl[2];
            #pragma unroll
            for (int i = 0; i < 2; ++i) {
                int row = wm + i * 32 + ar;
                int ba = row * 32 + ((kq ^ (row & 3)) * 8);
                ah[i]  = *(const bf16x8*)&lds[ba];
                al_[i] = *(const bf16x8*)&lds[4096 + ba];
            }
            #pragma unroll
            for (int j = 0; j < 2; ++j) {
                int row = wn + j * 32 + ar;
                int bb = row * 32 + ((kq ^ (row & 3)) * 8);
                bh[j] = *(const bf16x8*)&lds[8192 + bb];
                bl[j] = *(const bf16x8*)&lds[12288 + bb];
            }
            #pragma unroll
            for (int i = 0; i < 2; ++i)
                #pragma unroll
                for (int j = 0; j < 2; ++j) {
                    acc[i][j] = MFMA32(ah[i], bh[j], acc[i][j]);
                    acc[i][j] = MFMA32(ah[i], bl[j], acc[i][j]);
                    acc[i][j] = MFMA32(al_[i], bh[j], acc[i][j]);
                }
        }
        __syncthreads();
    }

    const int ec = l & 31, rb = (l >> 5) * 4;
    #pragma unroll
    for (int i = 0; i < 2; ++i)
        #pragma unroll
        for (int j = 0; j < 2; ++j) {
            int gn = bn + wn + j * 32 + ec;
            float bv = bias ? bias[gn] : 0.0f;
            #pragma unroll
            for (int r = 0; r < 16; ++r) {
                int gm = bm + wm + i * 32 + rb + (r & 3) + 8 * (r >> 2);
                float v = acc[i][j][r] + bv;
                if (res) v += res[(size_t)gm * rsC + gn];
                Cf[(size_t)gm * rsC + gn] = v;
            }
        }
}

// ---------------- encoder GEMM: silu(X@Wc^T+bc) -> cat2 cols 192.. -------------
__global__ __launch_bounds__(256)
void gemm3_enc(const ushort_t* __restrict__ A2, const ushort_t* __restrict__ B2,
               const float* __restrict__ bc, ushort_t* __restrict__ cat2) {
    __shared__ __align__(16) ushort_t lds[4 * 4096];
    const int tid = threadIdx.x;
    const int bm = blockIdx.x * 128, bn = blockIdx.y * 128;
    const int w = tid >> 6, l = tid & 63;
    const int wm = (w & 1) * 64, wn = (w >> 1) * 64;
    const int Kp = 288;

    f32x16 acc[2][2];
    #pragma unroll
    for (int i = 0; i < 2; ++i)
        #pragma unroll
        for (int j = 0; j < 2; ++j)
            #pragma unroll
            for (int r = 0; r < 16; ++r) acc[i][j][r] = 0.0f;

    const int r0 = tid >> 2;
    const int k8 = (((tid & 3) ^ (r0 & 3)) * 8);
    const ushort_t* gA0 = A2 + (size_t)(bm + r0) * 576 + k8;
    const ushort_t* gA1 = A2 + (size_t)(bm + 64 + r0) * 576 + k8;
    const ushort_t* gB0 = B2 + (size_t)(bn + r0) * 576 + k8;
    const ushort_t* gB1 = B2 + (size_t)(bn + 64 + r0) * 576 + k8;
    ushort_t* l0 = lds + tid * 8;
    ushort_t* l1 = lds + 2048 + tid * 8;
    const int ar = l & 31, qh = l >> 5;

    for (int kt = 0; kt < Kp; kt += 32) {
        gl_lds16(gA0 + kt, l0);
        gl_lds16(gA1 + kt, l1);
        gl_lds16(gA0 + kt + Kp, l0 + 4096);
        gl_lds16(gA1 + kt + Kp, l1 + 4096);
        gl_lds16(gB0 + kt, l0 + 8192);
        gl_lds16(gB1 + kt, l1 + 8192);
        gl_lds16(gB0 + kt + Kp, l0 + 12288);
        gl_lds16(gB1 + kt + Kp, l1 + 12288);
        __syncthreads();
        #pragma unroll
        for (int kh = 0; kh < 2; ++kh) {
            const int kq = kh * 2 + qh;
            bf16x8 ah[2], al_[2], bh[2], bl[2];
            #pragma unroll
            for (int i = 0; i < 2; ++i) {
                int row = wm + i * 32 + ar;
                int ba = row * 32 + ((kq ^ (row & 3)) * 8);
                ah[i]  = *(const bf16x8*)&lds[ba];
                al_[i] = *(const bf16x8*)&lds[4096 + ba];
            }
            #pragma unroll
            for (int j = 0; j < 2; ++j) {
                int row = wn + j * 32 + ar;
                int bb = row * 32 + ((kq ^ (row & 3)) * 8);
                bh[j] = *(const bf16x8*)&lds[8192 + bb];
                bl[j] = *(const bf16x8*)&lds[12288 + bb];
            }
            #pragma unroll
            for (int i = 0; i < 2; ++i)
                #pragma unroll
                for (int j = 0; j < 2; ++j) {
                    acc[i][j] = MFMA32(ah[i], bh[j], acc[i][j]);
                    acc[i][j] = MFMA32(ah[i], bl[j], acc[i][j]);
                    acc[i][j] = MFMA32(al_[i], bh[j], acc[i][j]);
                }
        }
        __syncthreads();
    }

    const int ec = l & 31, rb = (l >> 5) * 4;
    #pragma unroll
    for (int i = 0; i < 2; ++i)
        #pragma unroll
        for (int j = 0; j < 2; ++j) {
            int gn = bn + wn + j * 32 + ec;
            if (gn < 576) {
                float bv = bc[gn];
                #pragma unroll
                for (int r = 0; r < 16; ++r) {
                    int gm = bm + wm + i * 32 + rb + (r & 3) + 8 * (r >> 2);
                    float v = silu_f(acc[i][j][r] + bv);
                    ushort_t hi, lo;
                    split2(v, hi, lo);
                    cat2[(size_t)gm * 1536 + 192 + gn] = hi;
                    cat2[(size_t)gm * 1536 + 960 + gn] = lo;
                }
            }
        }
}

// ---------------- fused GLU GEMM ----------------------------------------------
__global__ __launch_bounds__(256)
void gemm_glu3(const ushort_t* __restrict__ A2,
               const ushort_t* __restrict__ W1, const ushort_t* __restrict__ W3,
               const float* __restrict__ b1, const float* __restrict__ b3,
               ushort_t* __restrict__ C2) {
    __shared__ __align__(16) ushort_t lds[6 * 4096];
    const int tid = threadIdx.x;
    const int bm = blockIdx.x * 128, bn = blockIdx.y * 128;
    const int w = tid >> 6, l = tid & 63;
    const int wm = (w & 1) * 64, wn = (w >> 1) * 64;
    const int Kp = 512;

    f32x16 acc1[2][2], acc3[2][2];
    #pragma unroll
    for (int i = 0; i < 2; ++i)
        #pragma unroll
        for (int j = 0; j < 2; ++j)
            #pragma unroll
            for (int r = 0; r < 16; ++r) { acc1[i][j][r] = 0.0f; acc3[i][j][r] = 0.0f; }

    const int r0 = tid >> 2;
    const int k8 = (((tid & 3) ^ (r0 & 3)) * 8);
    const ushort_t* gA0 = A2 + (size_t)(bm + r0) * 1024 + k8;
    const ushort_t* gA1 = A2 + (size_t)(bm + 64 + r0) * 1024 + k8;
    const ushort_t* g10 = W1 + (size_t)(bn + r0) * 1024 + k8;
    const ushort_t* g11 = W1 + (size_t)(bn + 64 + r0) * 1024 + k8;
    const ushort_t* g30 = W3 + (size_t)(bn + r0) * 1024 + k8;
    const ushort_t* g31 = W3 + (size_t)(bn + 64 + r0) * 1024 + k8;
    ushort_t* l0 = lds + tid * 8;
    ushort_t* l1 = lds + 2048 + tid * 8;
    const int ar = l & 31, qh = l >> 5;

    for (int kt = 0; kt < Kp; kt += 32) {
        gl_lds16(gA0 + kt, l0);
        gl_lds16(gA1 + kt, l1);
        gl_lds16(gA0 + kt + Kp, l0 + 4096);
        gl_lds16(gA1 + kt + Kp, l1 + 4096);
        gl_lds16(g10 + kt, l0 + 8192);
        gl_lds16(g11 + kt, l1 + 8192);
        gl_lds16(g10 + kt + Kp, l0 + 12288);
        gl_lds16(g11 + kt + Kp, l1 + 12288);
        gl_lds16(g30 + kt, l0 + 16384);
        gl_lds16(g31 + kt, l1 + 16384);
        gl_lds16(g30 + kt + Kp, l0 + 20480);
        gl_lds16(g31 + kt + Kp, l1 + 20480);
        __syncthreads();

        #pragma unroll
        for (int kh = 0; kh < 2; ++kh) {
            const int kq = kh * 2 + qh;
            bf16x8 ah[2], al_[2];
            #pragma unroll
            for (int i = 0; i < 2; ++i) {
                int row = wm + i * 32 + ar;
                int ba = row * 32 + ((kq ^ (row & 3)) * 8);
                ah[i]  = *(const bf16x8*)&lds[ba];
                al_[i] = *(const bf16x8*)&lds[4096 + ba];
            }
            #pragma unroll
            for (int j = 0; j < 2; ++j) {
                int row = wn + j * 32 + ar;
                int bb = row * 32 + ((kq ^ (row & 3)) * 8);
                bf16x8 w1h = *(const bf16x8*)&lds[8192 + bb];
                bf16x8 w1l = *(const bf16x8*)&lds[12288 + bb];
                bf16x8 w3h = *(const bf16x8*)&lds[16384 + bb];
                bf16x8 w3l = *(const bf16x8*)&lds[20480 + bb];
                #pragma unroll
                for (int i = 0; i < 2; ++i) {
                    acc1[i][j] = MFMA32(ah[i], w1h, acc1[i][j]);
                    acc1[i][j] = MFMA32(ah[i], w1l, acc1[i][j]);
                    acc1[i][j] = MFMA32(al_[i], w1h, acc1[i][j]);
                    acc3[i][j] = MFMA32(ah[i], w3h, acc3[i][j]);
                    acc3[i][j] = MFMA32(ah[i], w3l, acc3[i][j]);
                    acc3[i][j] = MFMA32(al_[i], w3h, acc3[i][j]);
                }
            }
        }
        __syncthreads();
    }

    const int ec = l & 31, rb = (l >> 5) * 4;
    #pragma unroll
    for (int i = 0; i < 2; ++i)
        #pragma unroll
        for (int j = 0; j < 2; ++j) {
            int gn = bn + wn + j * 32 + ec;
            if (gn < KP2) {
                float bv1 = (gn < DFF) ? b1[gn] : 0.0f;
                float bv3 = (gn < DFF) ? b3[gn] : 0.0f;
                #pragma unroll
                for (int r = 0; r < 16; ++r) {
                    int gm = bm + wm + i * 32 + rb + (r & 3) + 8 * (r >> 2);
                    float g = silu_f(acc1[i][j][r] + bv1) * (acc3[i][j][r] + bv3);
                    ushort_t hi, lo;
                    split2(g, hi, lo);
                    C2[(size_t)gm * (2 * KP2) + gn] = hi;
                    C2[(size_t)gm * (2 * KP2) + KP2 + gn] = lo;
                }
            }
        }
}

// ---------------- per-token reductions (wave-per-token) -----------------------
__global__ __launch_bounds__(256)
void rms_kernel(const float* __restrict__ h, const float* __restrict__ w,
                ushort_t* __restrict__ out2) {
    int wid = threadIdx.x >> 6, lane = threadIdx.x & 63;
    int t = blockIdx.x * 4 + wid;
    const float* hp = h + (size_t)t * 512;
    float xv[8];
    float ss = 0.0f;
    #pragma unroll
    for (int u = 0; u < 8; ++u) { xv[u] = hp[u * 64 + lane]; ss += xv[u] * xv[u]; }
    #pragma unroll
    for (int off = 32; off > 0; off >>= 1) ss += __shfl_xor(ss, off, 64);
    float inv = rsqrtf(ss * (1.0f / 512.0f) + 1.1920929e-07f);
    ushort_t* op = out2 + (size_t)t * 1024;
    #pragma unroll
    for (int u = 0; u < 8; ++u) {
        ushort_t hi, lo;
        split2(xv[u] * inv * w[u * 64 + lane], hi, lo);
        op[u * 64 + lane] = hi;
        op[512 + u * 64 + lane] = lo;
    }
}

__global__ __launch_bounds__(256)
void ln_silu_kernel(const float* __restrict__ h, const float* __restrict__ w,
                    const float* __restrict__ b, float* __restrict__ out) {
    int wid = threadIdx.x >> 6, lane = threadIdx.x & 63;
    int t = blockIdx.x * 4 + wid;
    const float* hp = h + (size_t)t * 512;
    float xv[8];
    float s = 0.0f;
    #pragma unroll
    for (int u = 0; u < 8; ++u) { xv[u] = hp[u * 64 + lane]; s += xv[u]; }
    #pragma unroll
    for (int off = 32; off > 0; off >>= 1) s += __shfl_xor(s, off, 64);
    float m = s * (1.0f / 512.0f);
    float v = 0.0f;
    #pragma unroll
    for (int u = 0; u < 8; ++u) { xv[u] -= m; v += xv[u] * xv[u]; }
    #pragma unroll
    for (int off = 32; off > 0; off >>= 1) v += __shfl_xor(v, off, 64);
    float inv = rsqrtf(v * (1.0f / 512.0f) + 1e-5f);
    float* op = out + (size_t)t * 512;
    #pragma unroll
    for (int u = 0; u < 8; ++u)
        op[u * 64 + lane] = silu_f(xv[u] * inv * w[u * 64 + lane] + b[u * 64 + lane]);
}

// ---------------- MFMA local attention (16x16 path, unchanged) ----------------
__global__ __launch_bounds__(256)
void attn_kernel(const float* __restrict__ qkv, const float* __restrict__ ct,
                 const float* __restrict__ st, ushort_t* __restrict__ attn2) {
    __shared__ __align__(16) ushort_t Khi[32 * 64], Klo[32 * 64];
    __shared__ __align__(16) ushort_t Vthi[64 * 32], Vtlo[64 * 32];
    __shared__ __align__(16) ushort_t Phi[128 * 32], Plo[128 * 32];
    const int nb = blockIdx.x, head = blockIdx.y, b = blockIdx.z;
    const int tid = threadIdx.x;
    const int w = tid >> 6, lane = tid & 63;
    const int quad = lane >> 4, lc = lane & 15;

    bf16x8 qhi[2][2], qlo[2][2];
    #pragma unroll
    for (int i = 0; i < 2; ++i) {
        int qtok = nb * 128 + w * 32 + i * 16 + lc;
        const float* qp = qkv + ((size_t)(b * LSEQ + qtok)) * 1536 + head * 64;
        #pragma unroll
        for (int s = 0; s < 2; ++s) {
            float4 a = *(const float4*)&qp[s * 32 + quad * 8];
            float4 bq = *(const float4*)&qp[s * 32 + quad * 8 + 4];
            float4 c4 = *(const float4*)&ct[qtok * 32 + s * 16 + quad * 4];
            float4 s4 = *(const float4*)&st[qtok * 32 + s * 16 + quad * 4];
            float e[8];
            e[0] = (a.x * c4.x - a.y * s4.x) * 0.125f;
            e[1] = (a.x * s4.x + a.y * c4.x) * 0.125f;
            e[2] = (a.z * c4.y - a.w * s4.y) * 0.125f;
            e[3] = (a.z * s4.y + a.w * c4.y) * 0.125f;
            e[4] = (bq.x * c4.z - bq.y * s4.z) * 0.125f;
            e[5] = (bq.x * s4.z + bq.y * c4.z) * 0.125f;
            e[6] = (bq.z * c4.w - bq.w * s4.w) * 0.125f;
            e[7] = (bq.z * s4.w + bq.w * c4.w) * 0.125f;
            union { bf16x8 v; ushort_t u[8]; } hh, ll;
            #pragma unroll
            for (int d = 0; d < 8; ++d) split2(e[d], hh.u[d], ll.u[d]);
            qhi[i][s] = hh.v;
            qlo[i][s] = ll.v;
        }
    }

    f32x4 acc[2][4];
    float mrun[2][4], lrun[2][4];
    #pragma unroll
    for (int i = 0; i < 2; ++i) {
        #pragma unroll
        for (int j = 0; j < 4; ++j) acc[i][j] = (f32x4){0.f, 0.f, 0.f, 0.f};
        #pragma unroll
        for (int r = 0; r < 4; ++r) { mrun[i][r] = -1e30f; lrun[i][r] = 0.0f; }
    }

    const int c0 = (nb == 0) ? 4 : 0;
    for (int c = c0; c < 8; ++c) {
        {
            int key = tid >> 3, g = tid & 7;
            int ktok = nb * 128 - 128 + c * 32 + key;
            const float* kp = qkv + ((size_t)(b * LSEQ + ktok)) * 1536 + 512 + head * 64 + g * 8;
            float4 a = *(const float4*)kp;
            float4 bq = *(const float4*)(kp + 4);
            float4 c4 = *(const float4*)&ct[ktok * 32 + g * 4];
            float4 s4 = *(const float4*)&st[ktok * 32 + g * 4];
            float e[8];
            e[0] = a.x * c4.x - a.y * s4.x;
            e[1] = a.x * s4.x + a.y * c4.x;
            e[2] = a.z * c4.y - a.w * s4.y;
            e[3] = a.z * s4.y + a.w * c4.y;
            e[4] = bq.x * c4.z - bq.y * s4.z;
            e[5] = bq.x * s4.z + bq.y * c4.z;
            e[6] = bq.z * c4.w - bq.w * s4.w;
            e[7] = bq.z * s4.w + bq.w * c4.w;
            union { bf16x8 v; ushort_t u[8]; } hh, ll;
            #pragma unroll
            for (int d = 0; d < 8; ++d) split2(e[d], hh.u[d], ll.u[d]);
            int sg = g ^ (key & 7);
            *(bf16x8*)&Khi[key * 64 + sg * 8] = hh.v;
            *(bf16x8*)&Klo[key * 64 + sg * 8] = ll.v;

            const float* vp = kp + 512;
            float4 va = *(const float4*)vp;
            float4 vb = *(const float4*)(vp + 4);
            float ve[8] = {va.x, va.y, va.z, va.w, vb.x, vb.y, vb.z, vb.w};
            int kg = key >> 3, k7 = key & 7;
            #pragma unroll
            for (int d = 0; d < 8; ++d) {
                ushort_t vh, vl;
                split2(ve[d], vh, vl);
                int dim = g * 8 + d;
                int addr = dim * 32 + (((kg + (dim >> 1)) & 3) * 8) + k7;
                Vthi[addr] = vh;
                Vtlo[addr] = vl;
            }
        }
        __syncthreads();

        f32x4 sf[2][2];
        #pragma unroll
        for (int i = 0; i < 2; ++i)
            #pragma unroll
            for (int t = 0; t < 2; ++t) sf[i][t] = (f32x4){0.f, 0.f, 0.f, 0.f};
        #pragma unroll
        for (int t = 0; t < 2; ++t) {
            #pragma unroll
            for (int s = 0; s < 2; ++s) {
                int row = t * 16 + lc;
                int sg = (s * 4 + quad) ^ (row & 7);
                bf16x8 kh = *(const bf16x8*)&Khi[row * 64 + sg * 8];
                bf16x8 kl = *(const bf16x8*)&Klo[row * 64 + sg * 8];
                #pragma unroll
                for (int i = 0; i < 2; ++i) {
                    sf[i][t] = __builtin_amdgcn_mfma_f32_16x16x32_bf16(qhi[i][s], kh, sf[i][t], 0, 0, 0);
                    sf[i][t] = __builtin_amdgcn_mfma_f32_16x16x32_bf16(qhi[i][s], kl, sf[i][t], 0, 0, 0);
                    sf[i][t] = __builtin_amdgcn_mfma_f32_16x16x32_bf16(qlo[i][s], kh, sf[i][t], 0, 0, 0);
                }
            }
        }

        #pragma unroll
        for (int i = 0; i < 2; ++i) {
            #pragma unroll
            for (int r = 0; r < 4; ++r) {
                int qq = w * 32 + i * 16 + quad * 4 + r;
                float rm = -1e30f;
                #pragma unroll
                for (int t = 0; t < 2; ++t) {
                    int key = c * 32 + t * 16 + lc;
                    bool valid = (key >= qq) && (key <= qq + 128) && (nb > 0 || key >= 128);
                    float sv = valid ? sf[i][t][r] : -1e30f;
                    sf[i][t][r] = sv;
                    rm = fmaxf(rm, sv);
                }
                #pragma unroll
                for (int xm = 1; xm < 16; xm <<= 1)
                    rm = fmaxf(rm, __shfl_xor(rm, xm, 64));
                float mn = fmaxf(mrun[i][r], rm);
                float alpha = __expf(mrun[i][r] - mn);
                lrun[i][r] *= alpha;
                #pragma unroll
                for (int j = 0; j < 4; ++j) acc[i][j][r] *= alpha;
                float rs = 0.0f;
                #pragma unroll
                for (int t = 0; t < 2; ++t) {
                    int key = c * 32 + t * 16 + lc;
                    bool valid = (key >= qq) && (key <= qq + 128) && (nb > 0 || key >= 128);
                    float p = valid ? __expf(sf[i][t][r] - mn) : 0.0f;
                    rs += p;
                    ushort_t ph, pl;
                    split2(p, ph, pl);
                    int col = t * 16 + lc;
                    int addr = qq * 32 + ((((col >> 3) + (qq >> 1)) & 3) * 8) + (col & 7);
                    Phi[addr] = ph;
                    Plo[addr] = pl;
                }
                #pragma unroll
                for (int xm = 1; xm < 16; xm <<= 1)
                    rs += __shfl_xor(rs, xm, 64);
                lrun[i][r] += rs;
                mrun[i][r] = mn;
            }
        }

        bf16x8 ph[2], pl[2];
        #pragma unroll
        for (int i = 0; i < 2; ++i) {
            int row = w * 32 + i * 16 + lc;
            int sg = (quad + (row >> 1)) & 3;
            ph[i] = *(const bf16x8*)&Phi[row * 32 + sg * 8];
            pl[i] = *(const bf16x8*)&Plo[row * 32 + sg * 8];
        }
        #pragma unroll
        for (int j = 0; j < 4; ++j) {
            int dim = j * 16 + lc;
            int sg = (quad + (dim >> 1)) & 3;
            bf16x8 vh = *(const bf16x8*)&Vthi[dim * 32 + sg * 8];
            bf16x8 vl = *(const bf16x8*)&Vtlo[dim * 32 + sg * 8];
            #pragma unroll
            for (int i = 0; i < 2; ++i) {
                acc[i][j] = __builtin_amdgcn_mfma_f32_16x16x32_bf16(ph[i], vh, acc[i][j], 0, 0, 0);
                acc[i][j] = __builtin_amdgcn_mfma_f32_16x16x32_bf16(ph[i], vl, acc[i][j], 0, 0, 0);
                acc[i][j] = __builtin_amdgcn_mfma_f32_16x16x32_bf16(pl[i], vh, acc[i][j], 0, 0, 0);
            }
        }
        __syncthreads();
    }

    #pragma unroll
    for (int i = 0; i < 2; ++i) {
        #pragma unroll
        for (int r = 0; r < 4; ++r) {
            int qtok = nb * 128 + w * 32 + i * 16 + quad * 4 + r;
            size_t base = ((size_t)(b * LSEQ + qtok)) * 1024 + head * 64;
            float inv = 1.0f / lrun[i][r];
            #pragma unroll
            for (int j = 0; j < 4; ++j) {
                float v = acc[i][j][r] * inv;
                ushort_t hi, lo;
                split2(v, hi, lo);
                attn2[base + j * 16 + lc] = hi;
                attn2[base + 512 + j * 16 + lc] = lo;
            }
        }
    }
}

// ---------------- head: LN + silu + 31-dim head + postprocess -----------------
__global__ __launch_bounds__(256)
void head_kernel(const float* __restrict__ h, const float* __restrict__ lw,
                 const float* __restrict__ lb, const float* __restrict__ head_w,
                 const float* __restrict__ head_b, float* __restrict__ out) {
    int wid = threadIdx.x >> 6, lane = threadIdx.x & 63;
    int t = blockIdx.x * 4 + wid;
    __shared__ float yv[4][32];
    const float* xr = h + (size_t)t * 512;
    float xv[8];
    float s = 0.0f;
    #pragma unroll
    for (int u = 0; u < 8; ++u) { xv[u] = xr[u * 64 + lane]; s += xv[u]; }
    #pragma unroll
    for (int off = 32; off > 0; off >>= 1) s += __shfl_xor(s, off, 64);
    float m = s * (1.0f / 512.0f);
    float var = 0.0f;
    #pragma unroll
    for (int u = 0; u < 8; ++u) { xv[u] -= m; var += xv[u] * xv[u]; }
    #pragma unroll
    for (int off = 32; off > 0; off >>= 1) var += __shfl_xor(var, off, 64);
    float inv = rsqrtf(var * (1.0f / 512.0f) + 1e-5f);
    #pragma unroll
    for (int u = 0; u < 8; ++u)
        xv[u] = silu_f(xv[u] * inv * lw[u * 64 + lane] + lb[u * 64 + lane]);

    for (int j = 0; j < 31; ++j) {
        const float* wr = head_w + (size_t)j * 512;
        float p = 0.0f;
        #pragma unroll
        for (int u = 0; u < 8; ++u) p += xv[u] * wr[u * 64 + lane];
        #pragma unroll
        for (int off = 32; off > 0; off >>= 1) p += __shfl_down(p, off, 64);
        if (lane == 0) yv[wid][j] = p + head_b[j];
    }
    if (lane == 0) {
        float* y = yv[wid];
        float* op = out + (size_t)t * 40;
        int am = 0; float best = y[0];
        for (int j = 1; j < 11; ++j) if (y[j] > best) { best = y[j]; am = j; }
        float fc_reg = softplus_f(y[11]);
        op[0] = (am < 10) ? (float)(am + 1) : fc_reg;
        for (int j = 0; j < 11; ++j) op[1 + j] = y[j];
        op[12] = fc_reg;
        int am2 = 0; float best2 = y[12];
        for (int j = 1; j < 11; ++j) if (y[12 + j] > best2) { best2 = y[12 + j]; am2 = j; }
        float ec_reg = softplus_f(y[23]);
        op[13] = (am2 < 10) ? (float)(am2 + 1) : ec_reg;
        for (int j = 0; j < 11; ++j) op[14 + j] = y[12 + j];
        op[25] = ec_reg;
        float bm_log = y[24];
        op[26] = 1.0f / (1.0f + expf(-bm_log));
        float mi = fmaxf(y[25], fmaxf(y[26], y[27]));
        float e0 = expf(y[25] - mi), e1 = expf(y[26] - mi), e2 = expf(y[27] - mi);
        float si = e0 + e1 + e2;
        op[27] = e0 / si; op[28] = e1 / si; op[29] = e2 / si;
        float md = fmaxf(y[28], fmaxf(y[29], y[30]));
        float d0 = expf(y[28] - md), d1 = expf(y[29] - md), d2 = expf(y[30] - md);
        float sd = d0 + d1 + d2;
        op[30] = d0 / sd; op[31] = d1 / sd; op[32] = d2 / sd;
        op[33] = bm_log;
        op[34] = y[25]; op[35] = y[26]; op[36] = y[27];
        op[37] = y[28]; op[38] = y[29]; op[39] = y[30];
    }
}

// ---------------- launch -------------------------------------------------------
extern "C" void kernel_launch(void* const* d_in, const int* in_sizes, int n_in,
                              void* d_out, int out_size, void* d_ws, size_t ws_size,
                              hipStream_t stream) {
    const int*   x        = (const int*)d_in[0];
    const float* emb      = (const float*)d_in[1];
    const float* reg_w    = (const float*)d_in[2];
    const float* reg_b    = (const float*)d_in[3];
    const float* br_w     = (const float*)d_in[4];
    const float* br_b     = (const float*)d_in[5];
    const float* sh_w     = (const float*)d_in[6];
    const float* sh_b     = (const float*)d_in[7];
    const float* inst_w   = (const float*)d_in[8];
    const float* inst_b   = (const float*)d_in[9];
    const float* enc_ln_w = (const float*)d_in[10];
    const float* enc_ln_b = (const float*)d_in[11];
    const float* qkv_w    = (const float*)d_in[12];
    const float* out_w    = (const float*)d_in[13];
    const float* out_b    = (const float*)d_in[14];
    const float* w1_w     = (const float*)d_in[15];
    const float* w1_b     = (const float*)d_in[16];
    const float* w3_w     = (const float*)d_in[17];
    const float* w3_b     = (const float*)d_in[18];
    const float* w2_w     = (const float*)d_in[19];
    const float* w2_b     = (const float*)d_in[20];
    const float* n1_w     = (const float*)d_in[21];
    const float* n2_w     = (const float*)d_in[22];
    const float* hl_w     = (const float*)d_in[23];
    const float* hl_b     = (const float*)d_in[24];
    const float* head_w   = (const float*)d_in[25];
    const float* head_b   = (const float*)d_in[26];

    char* ws = (char*)d_ws;
    size_t off = 0;
    ushort_t* inst2 = (ushort_t*)(ws + off); off += (size_t)512 * 1536 * 2;
    ushort_t* qkv2  = (ushort_t*)(ws + off); off += (size_t)3 * 1536 * 1024 * 2;
    ushort_t* out2w = (ushort_t*)(ws + off); off += (size_t)3 * 512 * 1024 * 2;
    ushort_t* w1s   = (ushort_t*)(ws + off); off += (size_t)3 * DFFP * 1024 * 2;
    ushort_t* w3s   = (ushort_t*)(ws + off); off += (size_t)3 * DFFP * 1024 * 2;
    ushort_t* w2s   = (ushort_t*)(ws + off); off += (size_t)3 * 512 * (2 * KP2) * 2;
    float*    ct    = (float*)(ws + off);    off += (size_t)LSEQ * 32 * 4;
    float*    st    = (float*)(ws + off);    off += (size_t)LSEQ * 32 * 4;
    float*    h     = (float*)(ws + off);    off += (size_t)T_TOK * 512 * 4;
    ushort_t* x2    = (ushort_t*)(ws + off); off += (size_t)T_TOK * 1024 * 2;
    ushort_t* attn2 = (ushort_t*)(ws + off); off += (size_t)T_TOK * 1024 * 2;
    float*    qkvb  = (float*)(ws + off);    off += (size_t)T_TOK * 1536 * 4;
    ushort_t* cat2  = (ushort_t*)(ws + off); off += (size_t)T_TOK * (2 * KP2) * 2;
    ushort_t* Wc2   = (ushort_t*)(ws + off); off += (size_t)640 * 576 * 2;
    float*    bc    = (float*)(ws + off);    off += 640 * 4;
    ushort_t* g2    = cat2;
    ushort_t* X2    = (ushort_t*)qkvb;

    rope_kernel<<<256, 256, 0, stream>>>(ct, st);
    build_encw<<<640, 256, 0, stream>>>(reg_w, reg_b, br_w, br_b, sh_w, sh_b, Wc2, bc);
    prep_tok<<<T_TOK, 256, 0, stream>>>(x, emb, X2, cat2);
    splitw_kernel<<<dim3(3, 512), 256, 0, stream>>>(inst_w, inst2, 512, 768, 768);
    splitw_qkv_kernel<<<dim3(2, 1536, 3), 256, 0, stream>>>(qkv_w, qkv2);
    splitw_kernel<<<dim3(2, 3 * 512), 256, 0, stream>>>(out_w, out2w, 3 * 512, 512, 512);
    splitw_ffn<<<dim3(2, 3 * DFFP), 256, 0, stream>>>(w1_w, w3_w, w1s, w3s);
    splitw_w2<<<dim3(6, 3 * 512), 256, 0, stream>>>(w2_w, w2s);

    gemm3_enc<<<dim3(64, 5), 256, 0, stream>>>(X2, Wc2, bc, cat2);
    gemm3_kernel<<<dim3(64, 4), 256, 0, stream>>>(
        cat2, 1536, inst2, 1536, inst_b, nullptr, h, 512, 768);
    ln_silu_kernel<<<T_TOK / 4, 256, 0, stream>>>(h, enc_ln_w, enc_ln_b, h);

    for (int l = 0; l < NLAYER; ++l) {
        rms_kernel<<<T_TOK / 4, 256, 0, stream>>>(h, n1_w + l * 512, x2);
        gemm3_kernel<<<dim3(64, 12), 256, 0, stream>>>(
            x2, 1024, qkv2 + (size_t)l * 1536 * 1024, 1024, nullptr, nullptr,
            qkvb, 1536, 512);
        {
            dim3 g(NBLK, NHEAD, BATCH);
            attn_kernel<<<g, 256, 0, stream>>>(qkvb, ct, st, attn2);
        }
        gemm3_kernel<<<dim3(64, 4), 256, 0, stream>>>(
            attn2, 1024, out2w + (size_t)l * 512 * 1024, 1024, out_b + l * 512,
            h, h, 512, 512);
        rms_kernel<<<T_TOK / 4, 256, 0, stream>>>(h, n2_w + l * 512, x2);
        gemm_glu3<<<dim3(64, 11), 256, 0, stream>>>(
            x2, w1s + (size_t)l * DFFP * 1024, w3s + (size_t)l * DFFP * 1024,
            w1_b + l * DFF, w3_b + l * DFF, g2);
        gemm3_kernel<<<dim3(64, 4), 256, 0, stream>>>(
            g2, 2 * KP2, w2s + (size_t)l * 512 * (2 * KP2), 2 * KP2, w2_b + l * 512,
            h, h, 512, KP2);
    }

    head_kernel<<<T_TOK / 4, 256, 0, stream>>>(h, hl_w, hl_b, head_w, head_b,
                                               (float*)d_out);
}

// Round 7
// 1277.692 us; speedup vs baseline: 4.4441x; 1.0536x over previous
//
#include <hip/hip_runtime.h>
#include <hip/hip_bf16.h>
#include <math.h>

#define T_TOK 8192
#define DMODEL 512
#define NHEAD 8
#define TEDIM 192
#define DFF 1365
#define DFFP 1408
#define KP2 1376
#define NLAYER 3
#define WINSZ 128
#define NBLK 16
#define LSEQ 2048
#define BATCH 4

typedef unsigned short ushort_t;
typedef __bf16 bf16x8 __attribute__((ext_vector_type(8)));
typedef float f32x4 __attribute__((ext_vector_type(4)));
typedef float f32x16 __attribute__((ext_vector_type(16)));

__device__ __forceinline__ float silu_f(float x) { return x / (1.0f + expf(-x)); }
__device__ __forceinline__ float softplus_f(float x) {
    return (x > 20.0f) ? x : log1pf(expf(x));
}

__device__ __forceinline__ ushort_t f2u(float x) {
    __hip_bfloat16 b = __float2bfloat16(x);
    return *reinterpret_cast<ushort_t*>(&b);
}
__device__ __forceinline__ float u2f(ushort_t u) {
    __hip_bfloat16 b = *reinterpret_cast<__hip_bfloat16*>(&u);
    return __bfloat162float(b);
}
__device__ __forceinline__ void split2(float x, ushort_t& hi, ushort_t& lo) {
    hi = f2u(x);
    lo = f2u(x - u2f(hi));
}

__device__ __forceinline__ void gl_lds16(const ushort_t* g, ushort_t* l) {
    __builtin_amdgcn_global_load_lds(
        (const __attribute__((address_space(1))) unsigned int*)g,
        (__attribute__((address_space(3))) unsigned int*)l, 16, 0, 0);
}

// ---------------- RoPE table ---------------------------------------------------
__global__ __launch_bounds__(256)
void rope_kernel(float* __restrict__ ct, float* __restrict__ st) {
    int idx = blockIdx.x * 256 + threadIdx.x;
    int tok = idx >> 5, p = idx & 31;
    float invf = powf(10000.0f, -(float)p * (1.0f / 32.0f));
    float sn, cs;
    sincosf((float)tok * invf, &sn, &cs);
    ct[idx] = cs;
    st[idx] = sn;
}

// ---------------- weight splits ------------------------------------------------
__global__ __launch_bounds__(256)
void splitw_kernel(const float* __restrict__ W, ushort_t* __restrict__ W2,
                   int N, int K, int Kp) {
    int n = blockIdx.y;
    int k = blockIdx.x * 256 + threadIdx.x;
    if (k >= Kp) return;
    float v = (n < N && k < K) ? W[(size_t)n * K + k] : 0.0f;
    ushort_t hi, lo;
    split2(v, hi, lo);
    W2[(size_t)n * (2 * Kp) + k] = hi;
    W2[(size_t)n * (2 * Kp) + Kp + k] = lo;
}

__global__ __launch_bounds__(256)
void splitw_qkv_kernel(const float* __restrict__ W, ushort_t* __restrict__ W2) {
    int l = blockIdx.z;
    int rr = blockIdx.y;
    int k = blockIdx.x * 256 + threadIdx.x;
    int h = rr / 192, rem = rr % 192;
    int dk = rem / 3, which = rem % 3;
    int rp = which * 512 + h * 64 + dk;
    float v = W[((size_t)l * 1536 + rr) * 512 + k];
    ushort_t hi, lo;
    split2(v, hi, lo);
    W2[((size_t)l * 1536 + rp) * 1024 + k] = hi;
    W2[((size_t)l * 1536 + rp) * 1024 + 512 + k] = lo;
}

// w1+w3, all layers in one launch. rows rr in [0, 3*DFFP)
__global__ __launch_bounds__(256)
void splitw_ffn(const float* __restrict__ w1, const float* __restrict__ w3,
                ushort_t* __restrict__ W1s, ushort_t* __restrict__ W3s) {
    int rr = blockIdx.y;
    int k = blockIdx.x * 256 + threadIdx.x;   // 0..511
    int lyr = rr / DFFP, n = rr % DFFP;
    bool ok = (n < DFF);
    float v1 = ok ? w1[((size_t)lyr * DFF + n) * 512 + k] : 0.0f;
    float v3 = ok ? w3[((size_t)lyr * DFF + n) * 512 + k] : 0.0f;
    ushort_t hi, lo;
    split2(v1, hi, lo);
    W1s[(size_t)rr * 1024 + k] = hi;
    W1s[(size_t)rr * 1024 + 512 + k] = lo;
    split2(v3, hi, lo);
    W3s[(size_t)rr * 1024 + k] = hi;
    W3s[(size_t)rr * 1024 + 512 + k] = lo;
}

// w2 all layers. rows rr in [0, 3*512)
__global__ __launch_bounds__(256)
void splitw_w2(const float* __restrict__ W, ushort_t* __restrict__ W2) {
    int rr = blockIdx.y;
    int k = blockIdx.x * 256 + threadIdx.x;
    if (k >= KP2) return;
    int lyr = rr >> 9, n = rr & 511;
    float v = (k < DFF) ? W[((size_t)lyr * 512 + n) * DFF + k] : 0.0f;
    ushort_t hi, lo;
    split2(v, hi, lo);
    W2[(size_t)rr * (2 * KP2) + k] = hi;
    W2[(size_t)rr * (2 * KP2) + KP2 + k] = lo;
}

// ---------------- encoder prep -------------------------------------------------
__global__ __launch_bounds__(256)
void build_encw(const float* __restrict__ reg_w, const float* __restrict__ reg_b,
                const float* __restrict__ br_w, const float* __restrict__ br_b,
                const float* __restrict__ sh_w, const float* __restrict__ sh_b,
                ushort_t* __restrict__ Wc2, float* __restrict__ bc) {
    int n = blockIdx.x;
    int tid = threadIdx.x;
    for (int k = tid; k < 288; k += 256) {
        float v = 0.0f;
        if (n < 192) {
            if (k < 64) v = reg_w[(size_t)n * 64 + k];
        } else if (n < 384) {
            if (k >= 256) v = br_w[(size_t)(n - 192) * 32 + (k - 256)];
        } else if (n < 576) {
            if (k >= 64 && k < 256) v = sh_w[(size_t)(n - 384) * 192 + (k - 64)];
        }
        ushort_t hi, lo;
        split2(v, hi, lo);
        Wc2[(size_t)n * 576 + k] = hi;
        Wc2[(size_t)n * 576 + 288 + k] = lo;
    }
    if (tid == 0) {
        float b = 0.0f;
        if (n < 192) b = reg_b[n];
        else if (n < 384) b = br_b[n - 192];
        else if (n < 576) b = sh_b[n - 384];
        bc[n] = b;
    }
}

// pack int features + gather embedding, one block per token
__global__ __launch_bounds__(256)
void prep_tok(const int* __restrict__ x, const float* __restrict__ emb,
              ushort_t* __restrict__ X2, ushort_t* __restrict__ cat2) {
    int tok = blockIdx.x;
    int tid = threadIdx.x;
    const int* xp = x + (size_t)tok * 289;
    for (int k = tid; k < 288; k += 256) {
        X2[(size_t)tok * 576 + k] = f2u((float)xp[1 + k]);
        X2[(size_t)tok * 576 + 288 + k] = 0;
    }
    int tokid = xp[0];
    for (int c = tid; c < 192; c += 256) {
        float v = silu_f(emb[(size_t)tokid * TEDIM + c]);
        ushort_t hi, lo;
        split2(v, hi, lo);
        cat2[(size_t)tok * 1536 + c] = hi;
        cat2[(size_t)tok * 1536 + 768 + c] = lo;
    }
}

// ======== 32x32x16 bf16x3 GEMM machinery ======================================
// LDS: [128 rows][4 x 16B k-chunks]. Chunk c of row r stored at slot
// (c + (r>>1)) & 3  -> s = 4r + slot; s%8 = 4(r&1) + ((c+(r>>1))&3) covers all
// 8 bank-quads over any 8 consecutive rows => conflict-free frag reads.
// Staging (DMA dst = tid*16B): lane tid fetches global chunk
// c = ((tid&3) - (tid>>3)) & 3 of row tid>>2 (64B-coalesced per 4 lanes).
// C/D layout (verified): col = lane&31, row = (reg&3) + 8*(reg>>2) + 4*(lane>>5).

#define MFMA32(a, b, c) __builtin_amdgcn_mfma_f32_32x32x16_bf16(a, b, c, 0, 0, 0)

// ---------------- generic GEMM (fp32 out + bias/res); grid (64, Ntiles) -------
__global__ __launch_bounds__(256)
void gemm3_kernel(const ushort_t* __restrict__ A2, int rsA,
                  const ushort_t* __restrict__ B2, int rsB,
                  const float* __restrict__ bias,
                  const float* __restrict__ res,
                  float* __restrict__ Cf, int rsC, int Kp) {
    __shared__ __align__(16) ushort_t lds[4 * 4096];
    const int tid = threadIdx.x;
    const int bm = blockIdx.x * 128, bn = blockIdx.y * 128;
    const int w = tid >> 6, l = tid & 63;
    const int wm = (w & 1) * 64, wn = (w >> 1) * 64;

    f32x16 acc[2][2];
    #pragma unroll
    for (int i = 0; i < 2; ++i)
        #pragma unroll
        for (int j = 0; j < 2; ++j)
            #pragma unroll
            for (int r = 0; r < 16; ++r) acc[i][j][r] = 0.0f;

    const int r0 = tid >> 2;
    const int k8 = (((tid & 3) - (tid >> 3)) & 3) * 8;   // rotation swizzle
    const ushort_t* gA0 = A2 + (size_t)(bm + r0) * rsA + k8;
    const ushort_t* gA1 = A2 + (size_t)(bm + 64 + r0) * rsA + k8;
    const ushort_t* gB0 = B2 + (size_t)(bn + r0) * rsB + k8;
    const ushort_t* gB1 = B2 + (size_t)(bn + 64 + r0) * rsB + k8;
    ushort_t* l0 = lds + tid * 8;
    ushort_t* l1 = lds + 2048 + tid * 8;

    const int ar = l & 31, qh = l >> 5;

    for (int kt = 0; kt < Kp; kt += 32) {
        gl_lds16(gA0 + kt, l0);
        gl_lds16(gA1 + kt, l1);
        gl_lds16(gA0 + kt + Kp, l0 + 4096);
        gl_lds16(gA1 + kt + Kp, l1 + 4096);
        gl_lds16(gB0 + kt, l0 + 8192);
        gl_lds16(gB1 + kt, l1 + 8192);
        gl_lds16(gB0 + kt + Kp, l0 + 12288);
        gl_lds16(gB1 + kt + Kp, l1 + 12288);
        __syncthreads();

        #pragma unroll
        for (int kh = 0; kh < 2; ++kh) {
            const int kq = kh * 2 + qh;
            bf16x8 ah[2], al_[2], bh[2], bl[2];
            #pragma unroll
            for (int i = 0; i < 2; ++i) {
                int row = wm + i * 32 + ar;
                int ba = row * 32 + (((kq + (row >> 1)) & 3) * 8);
                ah[i]  = *(const bf16x8*)&lds[ba];
                al_[i] = *(const bf16x8*)&lds[4096 + ba];
            }
            #pragma unroll
            for (int j = 0; j < 2; ++j) {
                int row = wn + j * 32 + ar;
                int bb = row * 32 + (((kq + (row >> 1)) & 3) * 8);
                bh[j] = *(const bf16x8*)&lds[8192 + bb];
                bl[j] = *(const bf16x8*)&lds[12288 + bb];
            }
            #pragma unroll
            for (int i = 0; i < 2; ++i)
                #pragma unroll
                for (int j = 0; j < 2; ++j) {
                    acc[i][j] = MFMA32(ah[i], bh[j], acc[i][j]);
                    acc[i][j] = MFMA32(ah[i], bl[j], acc[i][j]);
                    acc[i][j] = MFMA32(al_[i], bh[j], acc[i][j]);
                }
        }
        __syncthreads();
    }

    const int ec = l & 31, rb = (l >> 5) * 4;
    #pragma unroll
    for (int i = 0; i < 2; ++i)
        #pragma unroll
        for (int j = 0; j < 2; ++j) {
            int gn = bn + wn + j * 32 + ec;
            float bv = bias ? bias[gn] : 0.0f;
            #pragma unroll
            for (int r = 0; r < 16; ++r) {
                int gm = bm + wm + i * 32 + rb + (r & 3) + 8 * (r >> 2);
                float v = acc[i][j][r] + bv;
                if (res) v += res[(size_t)gm * rsC + gn];
                Cf[(size_t)gm * rsC + gn] = v;
            }
        }
}

// ---------------- encoder GEMM: silu(X@Wc^T+bc) -> cat2 cols 192.. -------------
__global__ __launch_bounds__(256)
void gemm3_enc(const ushort_t* __restrict__ A2, const ushort_t* __restrict__ B2,
               const float* __restrict__ bc, ushort_t* __restrict__ cat2) {
    __shared__ __align__(16) ushort_t lds[4 * 4096];
    const int tid = threadIdx.x;
    const int bm = blockIdx.x * 128, bn = blockIdx.y * 128;
    const int w = tid >> 6, l = tid & 63;
    const int wm = (w & 1) * 64, wn = (w >> 1) * 64;
    const int Kp = 288;

    f32x16 acc[2][2];
    #pragma unroll
    for (int i = 0; i < 2; ++i)
        #pragma unroll
        for (int j = 0; j < 2; ++j)
            #pragma unroll
            for (int r = 0; r < 16; ++r) acc[i][j][r] = 0.0f;

    const int r0 = tid >> 2;
    const int k8 = (((tid & 3) - (tid >> 3)) & 3) * 8;
    const ushort_t* gA0 = A2 + (size_t)(bm + r0) * 576 + k8;
    const ushort_t* gA1 = A2 + (size_t)(bm + 64 + r0) * 576 + k8;
    const ushort_t* gB0 = B2 + (size_t)(bn + r0) * 576 + k8;
    const ushort_t* gB1 = B2 + (size_t)(bn + 64 + r0) * 576 + k8;
    ushort_t* l0 = lds + tid * 8;
    ushort_t* l1 = lds + 2048 + tid * 8;
    const int ar = l & 31, qh = l >> 5;

    for (int kt = 0; kt < Kp; kt += 32) {
        gl_lds16(gA0 + kt, l0);
        gl_lds16(gA1 + kt, l1);
        gl_lds16(gA0 + kt + Kp, l0 + 4096);
        gl_lds16(gA1 + kt + Kp, l1 + 4096);
        gl_lds16(gB0 + kt, l0 + 8192);
        gl_lds16(gB1 + kt, l1 + 8192);
        gl_lds16(gB0 + kt + Kp, l0 + 12288);
        gl_lds16(gB1 + kt + Kp, l1 + 12288);
        __syncthreads();
        #pragma unroll
        for (int kh = 0; kh < 2; ++kh) {
            const int kq = kh * 2 + qh;
            bf16x8 ah[2], al_[2], bh[2], bl[2];
            #pragma unroll
            for (int i = 0; i < 2; ++i) {
                int row = wm + i * 32 + ar;
                int ba = row * 32 + (((kq + (row >> 1)) & 3) * 8);
                ah[i]  = *(const bf16x8*)&lds[ba];
                al_[i] = *(const bf16x8*)&lds[4096 + ba];
            }
            #pragma unroll
            for (int j = 0; j < 2; ++j) {
                int row = wn + j * 32 + ar;
                int bb = row * 32 + (((kq + (row >> 1)) & 3) * 8);
                bh[j] = *(const bf16x8*)&lds[8192 + bb];
                bl[j] = *(const bf16x8*)&lds[12288 + bb];
            }
            #pragma unroll
            for (int i = 0; i < 2; ++i)
                #pragma unroll
                for (int j = 0; j < 2; ++j) {
                    acc[i][j] = MFMA32(ah[i], bh[j], acc[i][j]);
                    acc[i][j] = MFMA32(ah[i], bl[j], acc[i][j]);
                    acc[i][j] = MFMA32(al_[i], bh[j], acc[i][j]);
                }
        }
        __syncthreads();
    }

    const int ec = l & 31, rb = (l >> 5) * 4;
    #pragma unroll
    for (int i = 0; i < 2; ++i)
        #pragma unroll
        for (int j = 0; j < 2; ++j) {
            int gn = bn + wn + j * 32 + ec;
            if (gn < 576) {
                float bv = bc[gn];
                #pragma unroll
                for (int r = 0; r < 16; ++r) {
                    int gm = bm + wm + i * 32 + rb + (r & 3) + 8 * (r >> 2);
                    float v = silu_f(acc[i][j][r] + bv);
                    ushort_t hi, lo;
                    split2(v, hi, lo);
                    cat2[(size_t)gm * 1536 + 192 + gn] = hi;
                    cat2[(size_t)gm * 1536 + 960 + gn] = lo;
                }
            }
        }
}

// ---------------- fused GLU GEMM ----------------------------------------------
__global__ __launch_bounds__(256)
void gemm_glu3(const ushort_t* __restrict__ A2,
               const ushort_t* __restrict__ W1, const ushort_t* __restrict__ W3,
               const float* __restrict__ b1, const float* __restrict__ b3,
               ushort_t* __restrict__ C2) {
    __shared__ __align__(16) ushort_t lds[6 * 4096];
    const int tid = threadIdx.x;
    const int bm = blockIdx.x * 128, bn = blockIdx.y * 128;
    const int w = tid >> 6, l = tid & 63;
    const int wm = (w & 1) * 64, wn = (w >> 1) * 64;
    const int Kp = 512;

    f32x16 acc1[2][2], acc3[2][2];
    #pragma unroll
    for (int i = 0; i < 2; ++i)
        #pragma unroll
        for (int j = 0; j < 2; ++j)
            #pragma unroll
            for (int r = 0; r < 16; ++r) { acc1[i][j][r] = 0.0f; acc3[i][j][r] = 0.0f; }

    const int r0 = tid >> 2;
    const int k8 = (((tid & 3) - (tid >> 3)) & 3) * 8;
    const ushort_t* gA0 = A2 + (size_t)(bm + r0) * 1024 + k8;
    const ushort_t* gA1 = A2 + (size_t)(bm + 64 + r0) * 1024 + k8;
    const ushort_t* g10 = W1 + (size_t)(bn + r0) * 1024 + k8;
    const ushort_t* g11 = W1 + (size_t)(bn + 64 + r0) * 1024 + k8;
    const ushort_t* g30 = W3 + (size_t)(bn + r0) * 1024 + k8;
    const ushort_t* g31 = W3 + (size_t)(bn + 64 + r0) * 1024 + k8;
    ushort_t* l0 = lds + tid * 8;
    ushort_t* l1 = lds + 2048 + tid * 8;
    const int ar = l & 31, qh = l >> 5;

    for (int kt = 0; kt < Kp; kt += 32) {
        gl_lds16(gA0 + kt, l0);
        gl_lds16(gA1 + kt, l1);
        gl_lds16(gA0 + kt + Kp, l0 + 4096);
        gl_lds16(gA1 + kt + Kp, l1 + 4096);
        gl_lds16(g10 + kt, l0 + 8192);
        gl_lds16(g11 + kt, l1 + 8192);
        gl_lds16(g10 + kt + Kp, l0 + 12288);
        gl_lds16(g11 + kt + Kp, l1 + 12288);
        gl_lds16(g30 + kt, l0 + 16384);
        gl_lds16(g31 + kt, l1 + 16384);
        gl_lds16(g30 + kt + Kp, l0 + 20480);
        gl_lds16(g31 + kt + Kp, l1 + 20480);
        __syncthreads();

        #pragma unroll
        for (int kh = 0; kh < 2; ++kh) {
            const int kq = kh * 2 + qh;
            bf16x8 ah[2], al_[2];
            #pragma unroll
            for (int i = 0; i < 2; ++i) {
                int row = wm + i * 32 + ar;
                int ba = row * 32 + (((kq + (row >> 1)) & 3) * 8);
                ah[i]  = *(const bf16x8*)&lds[ba];
                al_[i] = *(const bf16x8*)&lds[4096 + ba];
            }
            #pragma unroll
            for (int j = 0; j < 2; ++j) {
                int row = wn + j * 32 + ar;
                int bb = row * 32 + (((kq + (row >> 1)) & 3) * 8);
                bf16x8 w1h = *(const bf16x8*)&lds[8192 + bb];
                bf16x8 w1l = *(const bf16x8*)&lds[12288 + bb];
                bf16x8 w3h = *(const bf16x8*)&lds[16384 + bb];
                bf16x8 w3l = *(const bf16x8*)&lds[20480 + bb];
                #pragma unroll
                for (int i = 0; i < 2; ++i) {
                    acc1[i][j] = MFMA32(ah[i], w1h, acc1[i][j]);
                    acc1[i][j] = MFMA32(ah[i], w1l, acc1[i][j]);
                    acc1[i][j] = MFMA32(al_[i], w1h, acc1[i][j]);
                    acc3[i][j] = MFMA32(ah[i], w3h, acc3[i][j]);
                    acc3[i][j] = MFMA32(ah[i], w3l, acc3[i][j]);
                    acc3[i][j] = MFMA32(al_[i], w3h, acc3[i][j]);
                }
            }
        }
        __syncthreads();
    }

    const int ec = l & 31, rb = (l >> 5) * 4;
    #pragma unroll
    for (int i = 0; i < 2; ++i)
        #pragma unroll
        for (int j = 0; j < 2; ++j) {
            int gn = bn + wn + j * 32 + ec;
            if (gn < KP2) {
                float bv1 = (gn < DFF) ? b1[gn] : 0.0f;
                float bv3 = (gn < DFF) ? b3[gn] : 0.0f;
                #pragma unroll
                for (int r = 0; r < 16; ++r) {
                    int gm = bm + wm + i * 32 + rb + (r & 3) + 8 * (r >> 2);
                    float g = silu_f(acc1[i][j][r] + bv1) * (acc3[i][j][r] + bv3);
                    ushort_t hi, lo;
                    split2(g, hi, lo);
                    C2[(size_t)gm * (2 * KP2) + gn] = hi;
                    C2[(size_t)gm * (2 * KP2) + KP2 + gn] = lo;
                }
            }
        }
}

// ---------------- per-token reductions (wave-per-token) -----------------------
__global__ __launch_bounds__(256)
void rms_kernel(const float* __restrict__ h, const float* __restrict__ w,
                ushort_t* __restrict__ out2) {
    int wid = threadIdx.x >> 6, lane = threadIdx.x & 63;
    int t = blockIdx.x * 4 + wid;
    const float* hp = h + (size_t)t * 512;
    float xv[8];
    float ss = 0.0f;
    #pragma unroll
    for (int u = 0; u < 8; ++u) { xv[u] = hp[u * 64 + lane]; ss += xv[u] * xv[u]; }
    #pragma unroll
    for (int off = 32; off > 0; off >>= 1) ss += __shfl_xor(ss, off, 64);
    float inv = rsqrtf(ss * (1.0f / 512.0f) + 1.1920929e-07f);
    ushort_t* op = out2 + (size_t)t * 1024;
    #pragma unroll
    for (int u = 0; u < 8; ++u) {
        ushort_t hi, lo;
        split2(xv[u] * inv * w[u * 64 + lane], hi, lo);
        op[u * 64 + lane] = hi;
        op[512 + u * 64 + lane] = lo;
    }
}

__global__ __launch_bounds__(256)
void ln_silu_kernel(const float* __restrict__ h, const float* __restrict__ w,
                    const float* __restrict__ b, float* __restrict__ out) {
    int wid = threadIdx.x >> 6, lane = threadIdx.x & 63;
    int t = blockIdx.x * 4 + wid;
    const float* hp = h + (size_t)t * 512;
    float xv[8];
    float s = 0.0f;
    #pragma unroll
    for (int u = 0; u < 8; ++u) { xv[u] = hp[u * 64 + lane]; s += xv[u]; }
    #pragma unroll
    for (int off = 32; off > 0; off >>= 1) s += __shfl_xor(s, off, 64);
    float m = s * (1.0f / 512.0f);
    float v = 0.0f;
    #pragma unroll
    for (int u = 0; u < 8; ++u) { xv[u] -= m; v += xv[u] * xv[u]; }
    #pragma unroll
    for (int off = 32; off > 0; off >>= 1) v += __shfl_xor(v, off, 64);
    float inv = rsqrtf(v * (1.0f / 512.0f) + 1e-5f);
    float* op = out + (size_t)t * 512;
    #pragma unroll
    for (int u = 0; u < 8; ++u)
        op[u * 64 + lane] = silu_f(xv[u] * inv * w[u * 64 + lane] + b[u * 64 + lane]);
}

// ---------------- MFMA local attention (16x16 path) ---------------------------
__global__ __launch_bounds__(256)
void attn_kernel(const float* __restrict__ qkv, const float* __restrict__ ct,
                 const float* __restrict__ st, ushort_t* __restrict__ attn2) {
    __shared__ __align__(16) ushort_t Khi[32 * 64], Klo[32 * 64];
    __shared__ __align__(16) ushort_t Vthi[64 * 32], Vtlo[64 * 32];
    __shared__ __align__(16) ushort_t Phi[128 * 32], Plo[128 * 32];
    const int nb = blockIdx.x, head = blockIdx.y, b = blockIdx.z;
    const int tid = threadIdx.x;
    const int w = tid >> 6, lane = tid & 63;
    const int quad = lane >> 4, lc = lane & 15;

    bf16x8 qhi[2][2], qlo[2][2];
    #pragma unroll
    for (int i = 0; i < 2; ++i) {
        int qtok = nb * 128 + w * 32 + i * 16 + lc;
        const float* qp = qkv + ((size_t)(b * LSEQ + qtok)) * 1536 + head * 64;
        #pragma unroll
        for (int s = 0; s < 2; ++s) {
            float4 a = *(const float4*)&qp[s * 32 + quad * 8];
            float4 bq = *(const float4*)&qp[s * 32 + quad * 8 + 4];
            float4 c4 = *(const float4*)&ct[qtok * 32 + s * 16 + quad * 4];
            float4 s4 = *(const float4*)&st[qtok * 32 + s * 16 + quad * 4];
            float e[8];
            e[0] = (a.x * c4.x - a.y * s4.x) * 0.125f;
            e[1] = (a.x * s4.x + a.y * c4.x) * 0.125f;
            e[2] = (a.z * c4.y - a.w * s4.y) * 0.125f;
            e[3] = (a.z * s4.y + a.w * c4.y) * 0.125f;
            e[4] = (bq.x * c4.z - bq.y * s4.z) * 0.125f;
            e[5] = (bq.x * s4.z + bq.y * c4.z) * 0.125f;
            e[6] = (bq.z * c4.w - bq.w * s4.w) * 0.125f;
            e[7] = (bq.z * s4.w + bq.w * c4.w) * 0.125f;
            union { bf16x8 v; ushort_t u[8]; } hh, ll;
            #pragma unroll
            for (int d = 0; d < 8; ++d) split2(e[d], hh.u[d], ll.u[d]);
            qhi[i][s] = hh.v;
            qlo[i][s] = ll.v;
        }
    }

    f32x4 acc[2][4];
    float mrun[2][4], lrun[2][4];
    #pragma unroll
    for (int i = 0; i < 2; ++i) {
        #pragma unroll
        for (int j = 0; j < 4; ++j) acc[i][j] = (f32x4){0.f, 0.f, 0.f, 0.f};
        #pragma unroll
        for (int r = 0; r < 4; ++r) { mrun[i][r] = -1e30f; lrun[i][r] = 0.0f; }
    }

    const int c0 = (nb == 0) ? 4 : 0;
    for (int c = c0; c < 8; ++c) {
        {
            int key = tid >> 3, g = tid & 7;
            int ktok = nb * 128 - 128 + c * 32 + key;
            const float* kp = qkv + ((size_t)(b * LSEQ + ktok)) * 1536 + 512 + head * 64 + g * 8;
            float4 a = *(const float4*)kp;
            float4 bq = *(const float4*)(kp + 4);
            float4 c4 = *(const float4*)&ct[ktok * 32 + g * 4];
            float4 s4 = *(const float4*)&st[ktok * 32 + g * 4];
            float e[8];
            e[0] = a.x * c4.x - a.y * s4.x;
            e[1] = a.x * s4.x + a.y * c4.x;
            e[2] = a.z * c4.y - a.w * s4.y;
            e[3] = a.z * s4.y + a.w * c4.y;
            e[4] = bq.x * c4.z - bq.y * s4.z;
            e[5] = bq.x * s4.z + bq.y * c4.z;
            e[6] = bq.z * c4.w - bq.w * s4.w;
            e[7] = bq.z * s4.w + bq.w * c4.w;
            union { bf16x8 v; ushort_t u[8]; } hh, ll;
            #pragma unroll
            for (int d = 0; d < 8; ++d) split2(e[d], hh.u[d], ll.u[d]);
            int sg = g ^ (key & 7);
            *(bf16x8*)&Khi[key * 64 + sg * 8] = hh.v;
            *(bf16x8*)&Klo[key * 64 + sg * 8] = ll.v;

            const float* vp = kp + 512;
            float4 va = *(const float4*)vp;
            float4 vb = *(const float4*)(vp + 4);
            float ve[8] = {va.x, va.y, va.z, va.w, vb.x, vb.y, vb.z, vb.w};
            int kg = key >> 3, k7 = key & 7;
            #pragma unroll
            for (int d = 0; d < 8; ++d) {
                ushort_t vh, vl;
                split2(ve[d], vh, vl);
                int dim = g * 8 + d;
                int addr = dim * 32 + (((kg + (dim >> 1)) & 3) * 8) + k7;
                Vthi[addr] = vh;
                Vtlo[addr] = vl;
            }
        }
        __syncthreads();

        f32x4 sf[2][2];
        #pragma unroll
        for (int i = 0; i < 2; ++i)
            #pragma unroll
            for (int t = 0; t < 2; ++t) sf[i][t] = (f32x4){0.f, 0.f, 0.f, 0.f};
        #pragma unroll
        for (int t = 0; t < 2; ++t) {
            #pragma unroll
            for (int s = 0; s < 2; ++s) {
                int row = t * 16 + lc;
                int sg = (s * 4 + quad) ^ (row & 7);
                bf16x8 kh = *(const bf16x8*)&Khi[row * 64 + sg * 8];
                bf16x8 kl = *(const bf16x8*)&Klo[row * 64 + sg * 8];
                #pragma unroll
                for (int i = 0; i < 2; ++i) {
                    sf[i][t] = __builtin_amdgcn_mfma_f32_16x16x32_bf16(qhi[i][s], kh, sf[i][t], 0, 0, 0);
                    sf[i][t] = __builtin_amdgcn_mfma_f32_16x16x32_bf16(qhi[i][s], kl, sf[i][t], 0, 0, 0);
                    sf[i][t] = __builtin_amdgcn_mfma_f32_16x16x32_bf16(qlo[i][s], kh, sf[i][t], 0, 0, 0);
                }
            }
        }

        #pragma unroll
        for (int i = 0; i < 2; ++i) {
            #pragma unroll
            for (int r = 0; r < 4; ++r) {
                int qq = w * 32 + i * 16 + quad * 4 + r;
                float rm = -1e30f;
                #pragma unroll
                for (int t = 0; t < 2; ++t) {
                    int key = c * 32 + t * 16 + lc;
                    bool valid = (key >= qq) && (key <= qq + 128) && (nb > 0 || key >= 128);
                    float sv = valid ? sf[i][t][r] : -1e30f;
                    sf[i][t][r] = sv;
                    rm = fmaxf(rm, sv);
                }
                #pragma unroll
                for (int xm = 1; xm < 16; xm <<= 1)
                    rm = fmaxf(rm, __shfl_xor(rm, xm, 64));
                float mn = fmaxf(mrun[i][r], rm);
                float alpha = __expf(mrun[i][r] - mn);
                lrun[i][r] *= alpha;
                #pragma unroll
                for (int j = 0; j < 4; ++j) acc[i][j][r] *= alpha;
                float rs = 0.0f;
                #pragma unroll
                for (int t = 0; t < 2; ++t) {
                    int key = c * 32 + t * 16 + lc;
                    bool valid = (key >= qq) && (key <= qq + 128) && (nb > 0 || key >= 128);
                    float p = valid ? __expf(sf[i][t][r] - mn) : 0.0f;
                    rs += p;
                    ushort_t ph, pl;
                    split2(p, ph, pl);
                    int col = t * 16 + lc;
                    int addr = qq * 32 + ((((col >> 3) + (qq >> 1)) & 3) * 8) + (col & 7);
                    Phi[addr] = ph;
                    Plo[addr] = pl;
                }
                #pragma unroll
                for (int xm = 1; xm < 16; xm <<= 1)
                    rs += __shfl_xor(rs, xm, 64);
                lrun[i][r] += rs;
                mrun[i][r] = mn;
            }
        }

        bf16x8 ph[2], pl[2];
        #pragma unroll
        for (int i = 0; i < 2; ++i) {
            int row = w * 32 + i * 16 + lc;
            int sg = (quad + (row >> 1)) & 3;
            ph[i] = *(const bf16x8*)&Phi[row * 32 + sg * 8];
            pl[i] = *(const bf16x8*)&Plo[row * 32 + sg * 8];
        }
        #pragma unroll
        for (int j = 0; j < 4; ++j) {
            int dim = j * 16 + lc;
            int sg = (quad + (dim >> 1)) & 3;
            bf16x8 vh = *(const bf16x8*)&Vthi[dim * 32 + sg * 8];
            bf16x8 vl = *(const bf16x8*)&Vtlo[dim * 32 + sg * 8];
            #pragma unroll
            for (int i = 0; i < 2; ++i) {
                acc[i][j] = __builtin_amdgcn_mfma_f32_16x16x32_bf16(ph[i], vh, acc[i][j], 0, 0, 0);
                acc[i][j] = __builtin_amdgcn_mfma_f32_16x16x32_bf16(ph[i], vl, acc[i][j], 0, 0, 0);
                acc[i][j] = __builtin_amdgcn_mfma_f32_16x16x32_bf16(pl[i], vh, acc[i][j], 0, 0, 0);
            }
        }
        __syncthreads();
    }

    #pragma unroll
    for (int i = 0; i < 2; ++i) {
        #pragma unroll
        for (int r = 0; r < 4; ++r) {
            int qtok = nb * 128 + w * 32 + i * 16 + quad * 4 + r;
            size_t base = ((size_t)(b * LSEQ + qtok)) * 1024 + head * 64;
            float inv = 1.0f / lrun[i][r];
            #pragma unroll
            for (int j = 0; j < 4; ++j) {
                float v = acc[i][j][r] * inv;
                ushort_t hi, lo;
                split2(v, hi, lo);
                attn2[base + j * 16 + lc] = hi;
                attn2[base + 512 + j * 16 + lc] = lo;
            }
        }
    }
}

// ---------------- head: LN + silu + 31-dim head + postprocess -----------------
__global__ __launch_bounds__(256)
void head_kernel(const float* __restrict__ h, const float* __restrict__ lw,
                 const float* __restrict__ lb, const float* __restrict__ head_w,
                 const float* __restrict__ head_b, float* __restrict__ out) {
    int wid = threadIdx.x >> 6, lane = threadIdx.x & 63;
    int t = blockIdx.x * 4 + wid;
    __shared__ float yv[4][32];
    const float* xr = h + (size_t)t * 512;
    float xv[8];
    float s = 0.0f;
    #pragma unroll
    for (int u = 0; u < 8; ++u) { xv[u] = xr[u * 64 + lane]; s += xv[u]; }
    #pragma unroll
    for (int off = 32; off > 0; off >>= 1) s += __shfl_xor(s, off, 64);
    float m = s * (1.0f / 512.0f);
    float var = 0.0f;
    #pragma unroll
    for (int u = 0; u < 8; ++u) { xv[u] -= m; var += xv[u] * xv[u]; }
    #pragma unroll
    for (int off = 32; off > 0; off >>= 1) var += __shfl_xor(var, off, 64);
    float inv = rsqrtf(var * (1.0f / 512.0f) + 1e-5f);
    #pragma unroll
    for (int u = 0; u < 8; ++u)
        xv[u] = silu_f(xv[u] * inv * lw[u * 64 + lane] + lb[u * 64 + lane]);

    for (int j = 0; j < 31; ++j) {
        const float* wr = head_w + (size_t)j * 512;
        float p = 0.0f;
        #pragma unroll
        for (int u = 0; u < 8; ++u) p += xv[u] * wr[u * 64 + lane];
        #pragma unroll
        for (int off = 32; off > 0; off >>= 1) p += __shfl_down(p, off, 64);
        if (lane == 0) yv[wid][j] = p + head_b[j];
    }
    if (lane == 0) {
        float* y = yv[wid];
        float* op = out + (size_t)t * 40;
        int am = 0; float best = y[0];
        for (int j = 1; j < 11; ++j) if (y[j] > best) { best = y[j]; am = j; }
        float fc_reg = softplus_f(y[11]);
        op[0] = (am < 10) ? (float)(am + 1) : fc_reg;
        for (int j = 0; j < 11; ++j) op[1 + j] = y[j];
        op[12] = fc_reg;
        int am2 = 0; float best2 = y[12];
        for (int j = 1; j < 11; ++j) if (y[12 + j] > best2) { best2 = y[12 + j]; am2 = j; }
        float ec_reg = softplus_f(y[23]);
        op[13] = (am2 < 10) ? (float)(am2 + 1) : ec_reg;
        for (int j = 0; j < 11; ++j) op[14 + j] = y[12 + j];
        op[25] = ec_reg;
        float bm_log = y[24];
        op[26] = 1.0f / (1.0f + expf(-bm_log));
        float mi = fmaxf(y[25], fmaxf(y[26], y[27]));
        float e0 = expf(y[25] - mi), e1 = expf(y[26] - mi), e2 = expf(y[27] - mi);
        float si = e0 + e1 + e2;
        op[27] = e0 / si; op[28] = e1 / si; op[29] = e2 / si;
        float md = fmaxf(y[28], fmaxf(y[29], y[30]));
        float d0 = expf(y[28] - md), d1 = expf(y[29] - md), d2 = expf(y[30] - md);
        float sd = d0 + d1 + d2;
        op[30] = d0 / sd; op[31] = d1 / sd; op[32] = d2 / sd;
        op[33] = bm_log;
        op[34] = y[25]; op[35] = y[26]; op[36] = y[27];
        op[37] = y[28]; op[38] = y[29]; op[39] = y[30];
    }
}

// ---------------- launch -------------------------------------------------------
extern "C" void kernel_launch(void* const* d_in, const int* in_sizes, int n_in,
                              void* d_out, int out_size, void* d_ws, size_t ws_size,
                              hipStream_t stream) {
    const int*   x        = (const int*)d_in[0];
    const float* emb      = (const float*)d_in[1];
    const float* reg_w    = (const float*)d_in[2];
    const float* reg_b    = (const float*)d_in[3];
    const float* br_w     = (const float*)d_in[4];
    const float* br_b     = (const float*)d_in[5];
    const float* sh_w     = (const float*)d_in[6];
    const float* sh_b     = (const float*)d_in[7];
    const float* inst_w   = (const float*)d_in[8];
    const float* inst_b   = (const float*)d_in[9];
    const float* enc_ln_w = (const float*)d_in[10];
    const float* enc_ln_b = (const float*)d_in[11];
    const float* qkv_w    = (const float*)d_in[12];
    const float* out_w    = (const float*)d_in[13];
    const float* out_b    = (const float*)d_in[14];
    const float* w1_w     = (const float*)d_in[15];
    const float* w1_b     = (const float*)d_in[16];
    const float* w3_w     = (const float*)d_in[17];
    const float* w3_b     = (const float*)d_in[18];
    const float* w2_w     = (const float*)d_in[19];
    const float* w2_b     = (const float*)d_in[20];
    const float* n1_w     = (const float*)d_in[21];
    const float* n2_w     = (const float*)d_in[22];
    const float* hl_w     = (const float*)d_in[23];
    const float* hl_b     = (const float*)d_in[24];
    const float* head_w   = (const float*)d_in[25];
    const float* head_b   = (const float*)d_in[26];

    char* ws = (char*)d_ws;
    size_t off = 0;
    ushort_t* inst2 = (ushort_t*)(ws + off); off += (size_t)512 * 1536 * 2;
    ushort_t* qkv2  = (ushort_t*)(ws + off); off += (size_t)3 * 1536 * 1024 * 2;
    ushort_t* out2w = (ushort_t*)(ws + off); off += (size_t)3 * 512 * 1024 * 2;
    ushort_t* w1s   = (ushort_t*)(ws + off); off += (size_t)3 * DFFP * 1024 * 2;
    ushort_t* w3s   = (ushort_t*)(ws + off); off += (size_t)3 * DFFP * 1024 * 2;
    ushort_t* w2s   = (ushort_t*)(ws + off); off += (size_t)3 * 512 * (2 * KP2) * 2;
    float*    ct    = (float*)(ws + off);    off += (size_t)LSEQ * 32 * 4;
    float*    st    = (float*)(ws + off);    off += (size_t)LSEQ * 32 * 4;
    float*    h     = (float*)(ws + off);    off += (size_t)T_TOK * 512 * 4;
    ushort_t* x2    = (ushort_t*)(ws + off); off += (size_t)T_TOK * 1024 * 2;
    ushort_t* attn2 = (ushort_t*)(ws + off); off += (size_t)T_TOK * 1024 * 2;
    float*    qkvb  = (float*)(ws + off);    off += (size_t)T_TOK * 1536 * 4;
    ushort_t* cat2  = (ushort_t*)(ws + off); off += (size_t)T_TOK * (2 * KP2) * 2;
    ushort_t* Wc2   = (ushort_t*)(ws + off); off += (size_t)640 * 576 * 2;
    float*    bc    = (float*)(ws + off);    off += 640 * 4;
    ushort_t* g2    = cat2;
    ushort_t* X2    = (ushort_t*)qkvb;

    rope_kernel<<<256, 256, 0, stream>>>(ct, st);
    build_encw<<<640, 256, 0, stream>>>(reg_w, reg_b, br_w, br_b, sh_w, sh_b, Wc2, bc);
    prep_tok<<<T_TOK, 256, 0, stream>>>(x, emb, X2, cat2);
    splitw_kernel<<<dim3(3, 512), 256, 0, stream>>>(inst_w, inst2, 512, 768, 768);
    splitw_qkv_kernel<<<dim3(2, 1536, 3), 256, 0, stream>>>(qkv_w, qkv2);
    splitw_kernel<<<dim3(2, 3 * 512), 256, 0, stream>>>(out_w, out2w, 3 * 512, 512, 512);
    splitw_ffn<<<dim3(2, 3 * DFFP), 256, 0, stream>>>(w1_w, w3_w, w1s, w3s);
    splitw_w2<<<dim3(6, 3 * 512), 256, 0, stream>>>(w2_w, w2s);

    gemm3_enc<<<dim3(64, 5), 256, 0, stream>>>(X2, Wc2, bc, cat2);
    gemm3_kernel<<<dim3(64, 4), 256, 0, stream>>>(
        cat2, 1536, inst2, 1536, inst_b, nullptr, h, 512, 768);
    ln_silu_kernel<<<T_TOK / 4, 256, 0, stream>>>(h, enc_ln_w, enc_ln_b, h);

    for (int l = 0; l < NLAYER; ++l) {
        rms_kernel<<<T_TOK / 4, 256, 0, stream>>>(h, n1_w + l * 512, x2);
        gemm3_kernel<<<dim3(64, 12), 256, 0, stream>>>(
            x2, 1024, qkv2 + (size_t)l * 1536 * 1024, 1024, nullptr, nullptr,
            qkvb, 1536, 512);
        {
            dim3 g(NBLK, NHEAD, BATCH);
            attn_kernel<<<g, 256, 0, stream>>>(qkvb, ct, st, attn2);
        }
        gemm3_kernel<<<dim3(64, 4), 256, 0, stream>>>(
            attn2, 1024, out2w + (size_t)l * 512 * 1024, 1024, out_b + l * 512,
            h, h, 512, 512);
        rms_kernel<<<T_TOK / 4, 256, 0, stream>>>(h, n2_w + l * 512, x2);
        gemm_glu3<<<dim3(64, 11), 256, 0, stream>>>(
            x2, w1s + (size_t)l * DFFP * 1024, w3s + (size_t)l * DFFP * 1024,
            w1_b + l * DFF, w3_b + l * DFF, g2);
        gemm3_kernel<<<dim3(64, 4), 256, 0, stream>>>(
            g2, 2 * KP2, w2s + (size_t)l * 512 * (2 * KP2), 2 * KP2, w2_b + l * 512,
            h, h, 512, KP2);
    }

    head_kernel<<<T_TOK / 4, 256, 0, stream>>>(h, hl_w, hl_b, head_w, head_b,
                                               (float*)d_out);
}

// Round 8
// 1167.756 us; speedup vs baseline: 4.8624x; 1.0941x over previous
//
#include <hip/hip_runtime.h>
#include <hip/hip_bf16.h>
#include <math.h>

#define T_TOK 8192
#define DMODEL 512
#define NHEAD 8
#define TEDIM 192
#define DFF 1365
#define DFFP 1408
#define KP2 1376
#define NLAYER 3
#define WINSZ 128
#define NBLK 16
#define LSEQ 2048
#define BATCH 4

typedef unsigned short ushort_t;
typedef __bf16 bf16x8 __attribute__((ext_vector_type(8)));
typedef float f32x4 __attribute__((ext_vector_type(4)));
typedef float f32x16 __attribute__((ext_vector_type(16)));

__device__ __forceinline__ float silu_f(float x) { return x / (1.0f + expf(-x)); }
__device__ __forceinline__ float softplus_f(float x) {
    return (x > 20.0f) ? x : log1pf(expf(x));
}

__device__ __forceinline__ ushort_t f2u(float x) {
    __hip_bfloat16 b = __float2bfloat16(x);
    return *reinterpret_cast<ushort_t*>(&b);
}
__device__ __forceinline__ float u2f(ushort_t u) {
    __hip_bfloat16 b = *reinterpret_cast<__hip_bfloat16*>(&u);
    return __bfloat162float(b);
}
__device__ __forceinline__ void split2(float x, ushort_t& hi, ushort_t& lo) {
    hi = f2u(x);
    lo = f2u(x - u2f(hi));
}

__device__ __forceinline__ void gl_lds16(const ushort_t* g, ushort_t* l) {
    __builtin_amdgcn_global_load_lds(
        (const __attribute__((address_space(1))) unsigned int*)g,
        (__attribute__((address_space(3))) unsigned int*)l, 16, 0, 0);
}

// ---------------- RoPE table + encoder combined weight (merged) ---------------
__global__ __launch_bounds__(256)
void prep_const(float* __restrict__ ct, float* __restrict__ st,
                const float* __restrict__ reg_w, const float* __restrict__ reg_b,
                const float* __restrict__ br_w, const float* __restrict__ br_b,
                const float* __restrict__ sh_w, const float* __restrict__ sh_b,
                ushort_t* __restrict__ Wc2, float* __restrict__ bc) {
    int bx = blockIdx.x;
    int tid = threadIdx.x;
    if (bx < 256) {
        int idx = bx * 256 + tid;
        int tok = idx >> 5, p = idx & 31;
        float invf = powf(10000.0f, -(float)p * (1.0f / 32.0f));
        float sn, cs;
        sincosf((float)tok * invf, &sn, &cs);
        ct[idx] = cs;
        st[idx] = sn;
        return;
    }
    int n = bx - 256;             // 0..639
    for (int k = tid; k < 288; k += 256) {
        float v = 0.0f;
        if (n < 192) {
            if (k < 64) v = reg_w[(size_t)n * 64 + k];
        } else if (n < 384) {
            if (k >= 256) v = br_w[(size_t)(n - 192) * 32 + (k - 256)];
        } else if (n < 576) {
            if (k >= 64 && k < 256) v = sh_w[(size_t)(n - 384) * 192 + (k - 64)];
        }
        ushort_t hi, lo;
        split2(v, hi, lo);
        Wc2[(size_t)n * 576 + k] = hi;
        Wc2[(size_t)n * 576 + 288 + k] = lo;
    }
    if (tid == 0) {
        float b = 0.0f;
        if (n < 192) b = reg_b[n];
        else if (n < 384) b = br_b[n - 192];
        else if (n < 576) b = sh_b[n - 384];
        bc[n] = b;
    }
}

// ---------------- weight splits ------------------------------------------------
__global__ __launch_bounds__(256)
void splitw_kernel(const float* __restrict__ W, ushort_t* __restrict__ W2,
                   int N, int K, int Kp) {
    int n = blockIdx.y;
    int k = blockIdx.x * 256 + threadIdx.x;
    if (k >= Kp) return;
    float v = (n < N && k < K) ? W[(size_t)n * K + k] : 0.0f;
    ushort_t hi, lo;
    split2(v, hi, lo);
    W2[(size_t)n * (2 * Kp) + k] = hi;
    W2[(size_t)n * (2 * Kp) + Kp + k] = lo;
}

__global__ __launch_bounds__(256)
void splitw_qkv_kernel(const float* __restrict__ W, ushort_t* __restrict__ W2) {
    int l = blockIdx.z;
    int rr = blockIdx.y;
    int k = blockIdx.x * 256 + threadIdx.x;
    int h = rr / 192, rem = rr % 192;
    int dk = rem / 3, which = rem % 3;
    int rp = which * 512 + h * 64 + dk;
    float v = W[((size_t)l * 1536 + rr) * 512 + k];
    ushort_t hi, lo;
    split2(v, hi, lo);
    W2[((size_t)l * 1536 + rp) * 1024 + k] = hi;
    W2[((size_t)l * 1536 + rp) * 1024 + 512 + k] = lo;
}

__global__ __launch_bounds__(256)
void splitw_ffn(const float* __restrict__ w1, const float* __restrict__ w3,
                ushort_t* __restrict__ W1s, ushort_t* __restrict__ W3s) {
    int rr = blockIdx.y;
    int k = blockIdx.x * 256 + threadIdx.x;
    int lyr = rr / DFFP, n = rr % DFFP;
    bool ok = (n < DFF);
    float v1 = ok ? w1[((size_t)lyr * DFF + n) * 512 + k] : 0.0f;
    float v3 = ok ? w3[((size_t)lyr * DFF + n) * 512 + k] : 0.0f;
    ushort_t hi, lo;
    split2(v1, hi, lo);
    W1s[(size_t)rr * 1024 + k] = hi;
    W1s[(size_t)rr * 1024 + 512 + k] = lo;
    split2(v3, hi, lo);
    W3s[(size_t)rr * 1024 + k] = hi;
    W3s[(size_t)rr * 1024 + 512 + k] = lo;
}

__global__ __launch_bounds__(256)
void splitw_w2(const float* __restrict__ W, ushort_t* __restrict__ W2) {
    int rr = blockIdx.y;
    int k = blockIdx.x * 256 + threadIdx.x;
    if (k >= KP2) return;
    int lyr = rr >> 9, n = rr & 511;
    float v = (k < DFF) ? W[((size_t)lyr * 512 + n) * DFF + k] : 0.0f;
    ushort_t hi, lo;
    split2(v, hi, lo);
    W2[(size_t)rr * (2 * KP2) + k] = hi;
    W2[(size_t)rr * (2 * KP2) + KP2 + k] = lo;
}

// ---------------- token prep (X hi only — ints are bf16-exact) ----------------
__global__ __launch_bounds__(256)
void prep_tok(const int* __restrict__ x, const float* __restrict__ emb,
              ushort_t* __restrict__ X2, ushort_t* __restrict__ cat2) {
    int tok = blockIdx.x;
    int tid = threadIdx.x;
    const int* xp = x + (size_t)tok * 289;
    for (int k = tid; k < 288; k += 256)
        X2[(size_t)tok * 288 + k] = f2u((float)xp[1 + k]);
    int tokid = xp[0];
    for (int c = tid; c < 192; c += 256) {
        float v = silu_f(emb[(size_t)tokid * TEDIM + c]);
        ushort_t hi, lo;
        split2(v, hi, lo);
        cat2[(size_t)tok * 1536 + c] = hi;
        cat2[(size_t)tok * 1536 + 768 + c] = lo;
    }
}

// ======== 32x32x16 bf16x3 GEMM machinery ======================================
// LDS: [rows][4 x 16B k-chunks]. Chunk c of row r at slot (c + (r>>1)) & 3.
// Staging lane tid: global chunk ((tid&3) - (tid>>3)) & 3 of row tid>>2.
// C/D layout: col = lane&31, row = (reg&3) + 8*(reg>>2) + 4*(lane>>5).

#define MFMA32(a, b, c) __builtin_amdgcn_mfma_f32_32x32x16_bf16(a, b, c, 0, 0, 0)

// ---------------- 128x128 GEMM (fp32 out + bias/res); grid (64, Ntiles) -------
__global__ __launch_bounds__(256)
void gemm3_kernel(const ushort_t* __restrict__ A2, int rsA,
                  const ushort_t* __restrict__ B2, int rsB,
                  const float* __restrict__ bias,
                  const float* __restrict__ res,
                  float* __restrict__ Cf, int rsC, int Kp) {
    __shared__ __align__(16) ushort_t lds[4 * 4096];
    const int tid = threadIdx.x;
    const int bm = blockIdx.x * 128, bn = blockIdx.y * 128;
    const int w = tid >> 6, l = tid & 63;
    const int wm = (w & 1) * 64, wn = (w >> 1) * 64;

    f32x16 acc[2][2];
    #pragma unroll
    for (int i = 0; i < 2; ++i)
        #pragma unroll
        for (int j = 0; j < 2; ++j)
            #pragma unroll
            for (int r = 0; r < 16; ++r) acc[i][j][r] = 0.0f;

    const int r0 = tid >> 2;
    const int k8 = (((tid & 3) - (tid >> 3)) & 3) * 8;
    const ushort_t* gA0 = A2 + (size_t)(bm + r0) * rsA + k8;
    const ushort_t* gA1 = A2 + (size_t)(bm + 64 + r0) * rsA + k8;
    const ushort_t* gB0 = B2 + (size_t)(bn + r0) * rsB + k8;
    const ushort_t* gB1 = B2 + (size_t)(bn + 64 + r0) * rsB + k8;
    ushort_t* l0 = lds + tid * 8;
    ushort_t* l1 = lds + 2048 + tid * 8;

    const int ar = l & 31, qh = l >> 5;

    for (int kt = 0; kt < Kp; kt += 32) {
        gl_lds16(gA0 + kt, l0);
        gl_lds16(gA1 + kt, l1);
        gl_lds16(gA0 + kt + Kp, l0 + 4096);
        gl_lds16(gA1 + kt + Kp, l1 + 4096);
        gl_lds16(gB0 + kt, l0 + 8192);
        gl_lds16(gB1 + kt, l1 + 8192);
        gl_lds16(gB0 + kt + Kp, l0 + 12288);
        gl_lds16(gB1 + kt + Kp, l1 + 12288);
        __syncthreads();

        #pragma unroll
        for (int kh = 0; kh < 2; ++kh) {
            const int kq = kh * 2 + qh;
            bf16x8 ah[2], al_[2], bh[2], bl[2];
            #pragma unroll
            for (int i = 0; i < 2; ++i) {
                int row = wm + i * 32 + ar;
                int ba = row * 32 + (((kq + (row >> 1)) & 3) * 8);
                ah[i]  = *(const bf16x8*)&lds[ba];
                al_[i] = *(const bf16x8*)&lds[4096 + ba];
            }
            #pragma unroll
            for (int j = 0; j < 2; ++j) {
                int row = wn + j * 32 + ar;
                int bb = row * 32 + (((kq + (row >> 1)) & 3) * 8);
                bh[j] = *(const bf16x8*)&lds[8192 + bb];
                bl[j] = *(const bf16x8*)&lds[12288 + bb];
            }
            #pragma unroll
            for (int i = 0; i < 2; ++i)
                #pragma unroll
                for (int j = 0; j < 2; ++j) {
                    acc[i][j] = MFMA32(ah[i], bh[j], acc[i][j]);
                    acc[i][j] = MFMA32(ah[i], bl[j], acc[i][j]);
                    acc[i][j] = MFMA32(al_[i], bh[j], acc[i][j]);
                }
        }
        __syncthreads();
    }

    const int ec = l & 31, rb = (l >> 5) * 4;
    #pragma unroll
    for (int i = 0; i < 2; ++i)
        #pragma unroll
        for (int j = 0; j < 2; ++j) {
            int gn = bn + wn + j * 32 + ec;
            float bv = bias ? bias[gn] : 0.0f;
            #pragma unroll
            for (int r = 0; r < 16; ++r) {
                int gm = bm + wm + i * 32 + rb + (r & 3) + 8 * (r >> 2);
                float v = acc[i][j][r] + bv;
                if (res) v += res[(size_t)gm * rsC + gn];
                Cf[(size_t)gm * rsC + gn] = v;
            }
        }
}

// ---------------- 128x64 GEMM (more blocks/CU for N=512 cases) ----------------
__global__ __launch_bounds__(256)
void gemm3_n64(const ushort_t* __restrict__ A2, int rsA,
               const ushort_t* __restrict__ B2, int rsB,
               const float* __restrict__ bias,
               const float* __restrict__ res,
               float* __restrict__ Cf, int rsC, int Kp) {
    __shared__ __align__(16) ushort_t lds[12288];   // Ahi 4096 | Alo 4096 | Bhi 2048 | Blo 2048
    const int tid = threadIdx.x;
    const int bm = blockIdx.x * 128, bn = blockIdx.y * 64;
    const int w = tid >> 6, l = tid & 63;
    const int wm = (w & 1) * 64, wn = (w >> 1) * 32;

    f32x16 acc[2];
    #pragma unroll
    for (int i = 0; i < 2; ++i)
        #pragma unroll
        for (int r = 0; r < 16; ++r) acc[i][r] = 0.0f;

    const int r0 = tid >> 2;
    const int k8 = (((tid & 3) - (tid >> 3)) & 3) * 8;
    const ushort_t* gA0 = A2 + (size_t)(bm + r0) * rsA + k8;
    const ushort_t* gA1 = A2 + (size_t)(bm + 64 + r0) * rsA + k8;
    const ushort_t* gB0 = B2 + (size_t)(bn + r0) * rsB + k8;   // 64 rows
    ushort_t* l0 = lds + tid * 8;
    ushort_t* l1 = lds + 2048 + tid * 8;

    const int ar = l & 31, qh = l >> 5;

    for (int kt = 0; kt < Kp; kt += 32) {
        gl_lds16(gA0 + kt, l0);
        gl_lds16(gA1 + kt, l1);
        gl_lds16(gA0 + kt + Kp, l0 + 4096);
        gl_lds16(gA1 + kt + Kp, l1 + 4096);
        gl_lds16(gB0 + kt, l0 + 8192);
        gl_lds16(gB0 + kt + Kp, l0 + 10240);
        __syncthreads();

        #pragma unroll
        for (int kh = 0; kh < 2; ++kh) {
            const int kq = kh * 2 + qh;
            bf16x8 ah[2], al_[2];
            #pragma unroll
            for (int i = 0; i < 2; ++i) {
                int row = wm + i * 32 + ar;
                int ba = row * 32 + (((kq + (row >> 1)) & 3) * 8);
                ah[i]  = *(const bf16x8*)&lds[ba];
                al_[i] = *(const bf16x8*)&lds[4096 + ba];
            }
            int rowb = wn + ar;
            int bb = rowb * 32 + (((kq + (rowb >> 1)) & 3) * 8);
            bf16x8 bh = *(const bf16x8*)&lds[8192 + bb];
            bf16x8 bl = *(const bf16x8*)&lds[10240 + bb];
            #pragma unroll
            for (int i = 0; i < 2; ++i) {
                acc[i] = MFMA32(ah[i], bh, acc[i]);
                acc[i] = MFMA32(ah[i], bl, acc[i]);
                acc[i] = MFMA32(al_[i], bh, acc[i]);
            }
        }
        __syncthreads();
    }

    const int ec = l & 31, rb = (l >> 5) * 4;
    int gn = bn + wn + ec;
    float bv = bias ? bias[gn] : 0.0f;
    #pragma unroll
    for (int i = 0; i < 2; ++i)
        #pragma unroll
        for (int r = 0; r < 16; ++r) {
            int gm = bm + wm + i * 32 + rb + (r & 3) + 8 * (r >> 2);
            float v = acc[i][r] + bv;
            if (res) v += res[(size_t)gm * rsC + gn];
            Cf[(size_t)gm * rsC + gn] = v;
        }
}

// ---------------- encoder GEMM (A exact-bf16, hi only): 128x64 ----------------
__global__ __launch_bounds__(256)
void gemm3_enc(const ushort_t* __restrict__ A2, const ushort_t* __restrict__ B2,
               const float* __restrict__ bc, ushort_t* __restrict__ cat2) {
    __shared__ __align__(16) ushort_t lds[8192];  // Ahi 4096 | Bhi 2048 | Blo 2048
    const int tid = threadIdx.x;
    const int bm = blockIdx.x * 128, bn = blockIdx.y * 64;
    const int w = tid >> 6, l = tid & 63;
    const int wm = (w & 1) * 64, wn = (w >> 1) * 32;
    const int Kp = 288;

    f32x16 acc[2];
    #pragma unroll
    for (int i = 0; i < 2; ++i)
        #pragma unroll
        for (int r = 0; r < 16; ++r) acc[i][r] = 0.0f;

    const int r0 = tid >> 2;
    const int k8 = (((tid & 3) - (tid >> 3)) & 3) * 8;
    const ushort_t* gA0 = A2 + (size_t)(bm + r0) * 288 + k8;
    const ushort_t* gA1 = A2 + (size_t)(bm + 64 + r0) * 288 + k8;
    const ushort_t* gB0 = B2 + (size_t)(bn + r0) * 576 + k8;
    ushort_t* l0 = lds + tid * 8;
    ushort_t* l1 = lds + 2048 + tid * 8;
    const int ar = l & 31, qh = l >> 5;

    for (int kt = 0; kt < Kp; kt += 32) {
        gl_lds16(gA0 + kt, l0);
        gl_lds16(gA1 + kt, l1);
        gl_lds16(gB0 + kt, l0 + 4096);
        gl_lds16(gB0 + kt + Kp, l0 + 6144);
        __syncthreads();
        #pragma unroll
        for (int kh = 0; kh < 2; ++kh) {
            const int kq = kh * 2 + qh;
            bf16x8 ah[2];
            #pragma unroll
            for (int i = 0; i < 2; ++i) {
                int row = wm + i * 32 + ar;
                int ba = row * 32 + (((kq + (row >> 1)) & 3) * 8);
                ah[i] = *(const bf16x8*)&lds[ba];
            }
            int rowb = wn + ar;
            int bb = rowb * 32 + (((kq + (rowb >> 1)) & 3) * 8);
            bf16x8 bh = *(const bf16x8*)&lds[4096 + bb];
            bf16x8 bl = *(const bf16x8*)&lds[6144 + bb];
            #pragma unroll
            for (int i = 0; i < 2; ++i) {
                acc[i] = MFMA32(ah[i], bh, acc[i]);
                acc[i] = MFMA32(ah[i], bl, acc[i]);
            }
        }
        __syncthreads();
    }

    const int ec = l & 31, rb = (l >> 5) * 4;
    int gn = bn + wn + ec;
    if (gn < 576) {
        float bv = bc[gn];
        #pragma unroll
        for (int i = 0; i < 2; ++i)
            #pragma unroll
            for (int r = 0; r < 16; ++r) {
                int gm = bm + wm + i * 32 + rb + (r & 3) + 8 * (r >> 2);
                float v = silu_f(acc[i][r] + bv);
                ushort_t hi, lo;
                split2(v, hi, lo);
                cat2[(size_t)gm * 1536 + 192 + gn] = hi;
                cat2[(size_t)gm * 1536 + 960 + gn] = lo;
            }
    }
}

// ---------------- fused GLU GEMM (128x128) ------------------------------------
__global__ __launch_bounds__(256)
void gemm_glu3(const ushort_t* __restrict__ A2,
               const ushort_t* __restrict__ W1, const ushort_t* __restrict__ W3,
               const float* __restrict__ b1, const float* __restrict__ b3,
               ushort_t* __restrict__ C2) {
    __shared__ __align__(16) ushort_t lds[6 * 4096];
    const int tid = threadIdx.x;
    const int bm = blockIdx.x * 128, bn = blockIdx.y * 128;
    const int w = tid >> 6, l = tid & 63;
    const int wm = (w & 1) * 64, wn = (w >> 1) * 64;
    const int Kp = 512;

    f32x16 acc1[2][2], acc3[2][2];
    #pragma unroll
    for (int i = 0; i < 2; ++i)
        #pragma unroll
        for (int j = 0; j < 2; ++j)
            #pragma unroll
            for (int r = 0; r < 16; ++r) { acc1[i][j][r] = 0.0f; acc3[i][j][r] = 0.0f; }

    const int r0 = tid >> 2;
    const int k8 = (((tid & 3) - (tid >> 3)) & 3) * 8;
    const ushort_t* gA0 = A2 + (size_t)(bm + r0) * 1024 + k8;
    const ushort_t* gA1 = A2 + (size_t)(bm + 64 + r0) * 1024 + k8;
    const ushort_t* g10 = W1 + (size_t)(bn + r0) * 1024 + k8;
    const ushort_t* g11 = W1 + (size_t)(bn + 64 + r0) * 1024 + k8;
    const ushort_t* g30 = W3 + (size_t)(bn + r0) * 1024 + k8;
    const ushort_t* g31 = W3 + (size_t)(bn + 64 + r0) * 1024 + k8;
    ushort_t* l0 = lds + tid * 8;
    ushort_t* l1 = lds + 2048 + tid * 8;
    const int ar = l & 31, qh = l >> 5;

    for (int kt = 0; kt < Kp; kt += 32) {
        gl_lds16(gA0 + kt, l0);
        gl_lds16(gA1 + kt, l1);
        gl_lds16(gA0 + kt + Kp, l0 + 4096);
        gl_lds16(gA1 + kt + Kp, l1 + 4096);
        gl_lds16(g10 + kt, l0 + 8192);
        gl_lds16(g11 + kt, l1 + 8192);
        gl_lds16(g10 + kt + Kp, l0 + 12288);
        gl_lds16(g11 + kt + Kp, l1 + 12288);
        gl_lds16(g30 + kt, l0 + 16384);
        gl_lds16(g31 + kt, l1 + 16384);
        gl_lds16(g30 + kt + Kp, l0 + 20480);
        gl_lds16(g31 + kt + Kp, l1 + 20480);
        __syncthreads();

        #pragma unroll
        for (int kh = 0; kh < 2; ++kh) {
            const int kq = kh * 2 + qh;
            bf16x8 ah[2], al_[2];
            #pragma unroll
            for (int i = 0; i < 2; ++i) {
                int row = wm + i * 32 + ar;
                int ba = row * 32 + (((kq + (row >> 1)) & 3) * 8);
                ah[i]  = *(const bf16x8*)&lds[ba];
                al_[i] = *(const bf16x8*)&lds[4096 + ba];
            }
            #pragma unroll
            for (int j = 0; j < 2; ++j) {
                int row = wn + j * 32 + ar;
                int bb = row * 32 + (((kq + (row >> 1)) & 3) * 8);
                bf16x8 w1h = *(const bf16x8*)&lds[8192 + bb];
                bf16x8 w1l = *(const bf16x8*)&lds[12288 + bb];
                bf16x8 w3h = *(const bf16x8*)&lds[16384 + bb];
                bf16x8 w3l = *(const bf16x8*)&lds[20480 + bb];
                #pragma unroll
                for (int i = 0; i < 2; ++i) {
                    acc1[i][j] = MFMA32(ah[i], w1h, acc1[i][j]);
                    acc1[i][j] = MFMA32(ah[i], w1l, acc1[i][j]);
                    acc1[i][j] = MFMA32(al_[i], w1h, acc1[i][j]);
                    acc3[i][j] = MFMA32(ah[i], w3h, acc3[i][j]);
                    acc3[i][j] = MFMA32(ah[i], w3l, acc3[i][j]);
                    acc3[i][j] = MFMA32(al_[i], w3h, acc3[i][j]);
                }
            }
        }
        __syncthreads();
    }

    const int ec = l & 31, rb = (l >> 5) * 4;
    #pragma unroll
    for (int i = 0; i < 2; ++i)
        #pragma unroll
        for (int j = 0; j < 2; ++j) {
            int gn = bn + wn + j * 32 + ec;
            if (gn < KP2) {
                float bv1 = (gn < DFF) ? b1[gn] : 0.0f;
                float bv3 = (gn < DFF) ? b3[gn] : 0.0f;
                #pragma unroll
                for (int r = 0; r < 16; ++r) {
                    int gm = bm + wm + i * 32 + rb + (r & 3) + 8 * (r >> 2);
                    float g = silu_f(acc1[i][j][r] + bv1) * (acc3[i][j][r] + bv3);
                    ushort_t hi, lo;
                    split2(g, hi, lo);
                    C2[(size_t)gm * (2 * KP2) + gn] = hi;
                    C2[(size_t)gm * (2 * KP2) + KP2 + gn] = lo;
                }
            }
        }
}

// ---------------- per-token reductions (wave-per-token) -----------------------
__global__ __launch_bounds__(256)
void rms_kernel(const float* __restrict__ h, const float* __restrict__ w,
                ushort_t* __restrict__ out2) {
    int wid = threadIdx.x >> 6, lane = threadIdx.x & 63;
    int t = blockIdx.x * 4 + wid;
    const float* hp = h + (size_t)t * 512;
    float xv[8];
    float ss = 0.0f;
    #pragma unroll
    for (int u = 0; u < 8; ++u) { xv[u] = hp[u * 64 + lane]; ss += xv[u] * xv[u]; }
    #pragma unroll
    for (int off = 32; off > 0; off >>= 1) ss += __shfl_xor(ss, off, 64);
    float inv = rsqrtf(ss * (1.0f / 512.0f) + 1.1920929e-07f);
    ushort_t* op = out2 + (size_t)t * 1024;
    #pragma unroll
    for (int u = 0; u < 8; ++u) {
        ushort_t hi, lo;
        split2(xv[u] * inv * w[u * 64 + lane], hi, lo);
        op[u * 64 + lane] = hi;
        op[512 + u * 64 + lane] = lo;
    }
}

__global__ __launch_bounds__(256)
void ln_silu_kernel(const float* __restrict__ h, const float* __restrict__ w,
                    const float* __restrict__ b, float* __restrict__ out) {
    int wid = threadIdx.x >> 6, lane = threadIdx.x & 63;
    int t = blockIdx.x * 4 + wid;
    const float* hp = h + (size_t)t * 512;
    float xv[8];
    float s = 0.0f;
    #pragma unroll
    for (int u = 0; u < 8; ++u) { xv[u] = hp[u * 64 + lane]; s += xv[u]; }
    #pragma unroll
    for (int off = 32; off > 0; off >>= 1) s += __shfl_xor(s, off, 64);
    float m = s * (1.0f / 512.0f);
    float v = 0.0f;
    #pragma unroll
    for (int u = 0; u < 8; ++u) { xv[u] -= m; v += xv[u] * xv[u]; }
    #pragma unroll
    for (int off = 32; off > 0; off >>= 1) v += __shfl_xor(v, off, 64);
    float inv = rsqrtf(v * (1.0f / 512.0f) + 1e-5f);
    float* op = out + (size_t)t * 512;
    #pragma unroll
    for (int u = 0; u < 8; ++u)
        op[u * 64 + lane] = silu_f(xv[u] * inv * w[u * 64 + lane] + b[u * 64 + lane]);
}

// ---------------- MFMA local attention (16x16 path) ---------------------------
__global__ __launch_bounds__(256)
void attn_kernel(const float* __restrict__ qkv, const float* __restrict__ ct,
                 const float* __restrict__ st, ushort_t* __restrict__ attn2) {
    __shared__ __align__(16) ushort_t Khi[32 * 64], Klo[32 * 64];
    __shared__ __align__(16) ushort_t Vthi[64 * 32], Vtlo[64 * 32];
    __shared__ __align__(16) ushort_t Phi[128 * 32], Plo[128 * 32];
    const int nb = blockIdx.x, head = blockIdx.y, b = blockIdx.z;
    const int tid = threadIdx.x;
    const int w = tid >> 6, lane = tid & 63;
    const int quad = lane >> 4, lc = lane & 15;

    bf16x8 qhi[2][2], qlo[2][2];
    #pragma unroll
    for (int i = 0; i < 2; ++i) {
        int qtok = nb * 128 + w * 32 + i * 16 + lc;
        const float* qp = qkv + ((size_t)(b * LSEQ + qtok)) * 1536 + head * 64;
        #pragma unroll
        for (int s = 0; s < 2; ++s) {
            float4 a = *(const float4*)&qp[s * 32 + quad * 8];
            float4 bq = *(const float4*)&qp[s * 32 + quad * 8 + 4];
            float4 c4 = *(const float4*)&ct[qtok * 32 + s * 16 + quad * 4];
            float4 s4 = *(const float4*)&st[qtok * 32 + s * 16 + quad * 4];
            float e[8];
            e[0] = (a.x * c4.x - a.y * s4.x) * 0.125f;
            e[1] = (a.x * s4.x + a.y * c4.x) * 0.125f;
            e[2] = (a.z * c4.y - a.w * s4.y) * 0.125f;
            e[3] = (a.z * s4.y + a.w * c4.y) * 0.125f;
            e[4] = (bq.x * c4.z - bq.y * s4.z) * 0.125f;
            e[5] = (bq.x * s4.z + bq.y * c4.z) * 0.125f;
            e[6] = (bq.z * c4.w - bq.w * s4.w) * 0.125f;
            e[7] = (bq.z * s4.w + bq.w * c4.w) * 0.125f;
            union { bf16x8 v; ushort_t u[8]; } hh, ll;
            #pragma unroll
            for (int d = 0; d < 8; ++d) split2(e[d], hh.u[d], ll.u[d]);
            qhi[i][s] = hh.v;
            qlo[i][s] = ll.v;
        }
    }

    f32x4 acc[2][4];
    float mrun[2][4], lrun[2][4];
    #pragma unroll
    for (int i = 0; i < 2; ++i) {
        #pragma unroll
        for (int j = 0; j < 4; ++j) acc[i][j] = (f32x4){0.f, 0.f, 0.f, 0.f};
        #pragma unroll
        for (int r = 0; r < 4; ++r) { mrun[i][r] = -1e30f; lrun[i][r] = 0.0f; }
    }

    const int c0 = (nb == 0) ? 4 : 0;
    for (int c = c0; c < 8; ++c) {
        {
            int key = tid >> 3, g = tid & 7;
            int ktok = nb * 128 - 128 + c * 32 + key;
            const float* kp = qkv + ((size_t)(b * LSEQ + ktok)) * 1536 + 512 + head * 64 + g * 8;
            float4 a = *(const float4*)kp;
            float4 bq = *(const float4*)(kp + 4);
            float4 c4 = *(const float4*)&ct[ktok * 32 + g * 4];
            float4 s4 = *(const float4*)&st[ktok * 32 + g * 4];
            float e[8];
            e[0] = a.x * c4.x - a.y * s4.x;
            e[1] = a.x * s4.x + a.y * c4.x;
            e[2] = a.z * c4.y - a.w * s4.y;
            e[3] = a.z * s4.y + a.w * c4.y;
            e[4] = bq.x * c4.z - bq.y * s4.z;
            e[5] = bq.x * s4.z + bq.y * c4.z;
            e[6] = bq.z * c4.w - bq.w * s4.w;
            e[7] = bq.z * s4.w + bq.w * c4.w;
            union { bf16x8 v; ushort_t u[8]; } hh, ll;
            #pragma unroll
            for (int d = 0; d < 8; ++d) split2(e[d], hh.u[d], ll.u[d]);
            int sg = g ^ (key & 7);
            *(bf16x8*)&Khi[key * 64 + sg * 8] = hh.v;
            *(bf16x8*)&Klo[key * 64 + sg * 8] = ll.v;

            const float* vp = kp + 512;
            float4 va = *(const float4*)vp;
            float4 vb = *(const float4*)(vp + 4);
            float ve[8] = {va.x, va.y, va.z, va.w, vb.x, vb.y, vb.z, vb.w};
            int kg = key >> 3, k7 = key & 7;
            #pragma unroll
            for (int d = 0; d < 8; ++d) {
                ushort_t vh, vl;
                split2(ve[d], vh, vl);
                int dim = g * 8 + d;
                int addr = dim * 32 + (((kg + (dim >> 1)) & 3) * 8) + k7;
                Vthi[addr] = vh;
                Vtlo[addr] = vl;
            }
        }
        __syncthreads();

        f32x4 sf[2][2];
        #pragma unroll
        for (int i = 0; i < 2; ++i)
            #pragma unroll
            for (int t = 0; t < 2; ++t) sf[i][t] = (f32x4){0.f, 0.f, 0.f, 0.f};
        #pragma unroll
        for (int t = 0; t < 2; ++t) {
            #pragma unroll
            for (int s = 0; s < 2; ++s) {
                int row = t * 16 + lc;
                int sg = (s * 4 + quad) ^ (row & 7);
                bf16x8 kh = *(const bf16x8*)&Khi[row * 64 + sg * 8];
                bf16x8 kl = *(const bf16x8*)&Klo[row * 64 + sg * 8];
                #pragma unroll
                for (int i = 0; i < 2; ++i) {
                    sf[i][t] = __builtin_amdgcn_mfma_f32_16x16x32_bf16(qhi[i][s], kh, sf[i][t], 0, 0, 0);
                    sf[i][t] = __builtin_amdgcn_mfma_f32_16x16x32_bf16(qhi[i][s], kl, sf[i][t], 0, 0, 0);
                    sf[i][t] = __builtin_amdgcn_mfma_f32_16x16x32_bf16(qlo[i][s], kh, sf[i][t], 0, 0, 0);
                }
            }
        }

        #pragma unroll
        for (int i = 0; i < 2; ++i) {
            #pragma unroll
            for (int r = 0; r < 4; ++r) {
                int qq = w * 32 + i * 16 + quad * 4 + r;
                float rm = -1e30f;
                #pragma unroll
                for (int t = 0; t < 2; ++t) {
                    int key = c * 32 + t * 16 + lc;
                    bool valid = (key >= qq) && (key <= qq + 128) && (nb > 0 || key >= 128);
                    float sv = valid ? sf[i][t][r] : -1e30f;
                    sf[i][t][r] = sv;
                    rm = fmaxf(rm, sv);
                }
                #pragma unroll
                for (int xm = 1; xm < 16; xm <<= 1)
                    rm = fmaxf(rm, __shfl_xor(rm, xm, 64));
                float mn = fmaxf(mrun[i][r], rm);
                float alpha = __expf(mrun[i][r] - mn);
                lrun[i][r] *= alpha;
                #pragma unroll
                for (int j = 0; j < 4; ++j) acc[i][j][r] *= alpha;
                float rs = 0.0f;
                #pragma unroll
                for (int t = 0; t < 2; ++t) {
                    int key = c * 32 + t * 16 + lc;
                    bool valid = (key >= qq) && (key <= qq + 128) && (nb > 0 || key >= 128);
                    float p = valid ? __expf(sf[i][t][r] - mn) : 0.0f;
                    rs += p;
                    ushort_t ph, pl;
                    split2(p, ph, pl);
                    int col = t * 16 + lc;
                    int addr = qq * 32 + ((((col >> 3) + (qq >> 1)) & 3) * 8) + (col & 7);
                    Phi[addr] = ph;
                    Plo[addr] = pl;
                }
                #pragma unroll
                for (int xm = 1; xm < 16; xm <<= 1)
                    rs += __shfl_xor(rs, xm, 64);
                lrun[i][r] += rs;
                mrun[i][r] = mn;
            }
        }

        bf16x8 ph[2], pl[2];
        #pragma unroll
        for (int i = 0; i < 2; ++i) {
            int row = w * 32 + i * 16 + lc;
            int sg = (quad + (row >> 1)) & 3;
            ph[i] = *(const bf16x8*)&Phi[row * 32 + sg * 8];
            pl[i] = *(const bf16x8*)&Plo[row * 32 + sg * 8];
        }
        #pragma unroll
        for (int j = 0; j < 4; ++j) {
            int dim = j * 16 + lc;
            int sg = (quad + (dim >> 1)) & 3;
            bf16x8 vh = *(const bf16x8*)&Vthi[dim * 32 + sg * 8];
            bf16x8 vl = *(const bf16x8*)&Vtlo[dim * 32 + sg * 8];
            #pragma unroll
            for (int i = 0; i < 2; ++i) {
                acc[i][j] = __builtin_amdgcn_mfma_f32_16x16x32_bf16(ph[i], vh, acc[i][j], 0, 0, 0);
                acc[i][j] = __builtin_amdgcn_mfma_f32_16x16x32_bf16(ph[i], vl, acc[i][j], 0, 0, 0);
                acc[i][j] = __builtin_amdgcn_mfma_f32_16x16x32_bf16(pl[i], vh, acc[i][j], 0, 0, 0);
            }
        }
        __syncthreads();
    }

    #pragma unroll
    for (int i = 0; i < 2; ++i) {
        #pragma unroll
        for (int r = 0; r < 4; ++r) {
            int qtok = nb * 128 + w * 32 + i * 16 + quad * 4 + r;
            size_t base = ((size_t)(b * LSEQ + qtok)) * 1024 + head * 64;
            float inv = 1.0f / lrun[i][r];
            #pragma unroll
            for (int j = 0; j < 4; ++j) {
                float v = acc[i][j][r] * inv;
                ushort_t hi, lo;
                split2(v, hi, lo);
                attn2[base + j * 16 + lc] = hi;
                attn2[base + 512 + j * 16 + lc] = lo;
            }
        }
    }
}

// ---------------- head: LN + silu + 31-dim head + postprocess -----------------
__global__ __launch_bounds__(256)
void head_kernel(const float* __restrict__ h, const float* __restrict__ lw,
                 const float* __restrict__ lb, const float* __restrict__ head_w,
                 const float* __restrict__ head_b, float* __restrict__ out) {
    int wid = threadIdx.x >> 6, lane = threadIdx.x & 63;
    int t = blockIdx.x * 4 + wid;
    __shared__ float yv[4][32];
    const float* xr = h + (size_t)t * 512;
    float xv[8];
    float s = 0.0f;
    #pragma unroll
    for (int u = 0; u < 8; ++u) { xv[u] = xr[u * 64 + lane]; s += xv[u]; }
    #pragma unroll
    for (int off = 32; off > 0; off >>= 1) s += __shfl_xor(s, off, 64);
    float m = s * (1.0f / 512.0f);
    float var = 0.0f;
    #pragma unroll
    for (int u = 0; u < 8; ++u) { xv[u] -= m; var += xv[u] * xv[u]; }
    #pragma unroll
    for (int off = 32; off > 0; off >>= 1) var += __shfl_xor(var, off, 64);
    float inv = rsqrtf(var * (1.0f / 512.0f) + 1e-5f);
    #pragma unroll
    for (int u = 0; u < 8; ++u)
        xv[u] = silu_f(xv[u] * inv * lw[u * 64 + lane] + lb[u * 64 + lane]);

    for (int j = 0; j < 31; ++j) {
        const float* wr = head_w + (size_t)j * 512;
        float p = 0.0f;
        #pragma unroll
        for (int u = 0; u < 8; ++u) p += xv[u] * wr[u * 64 + lane];
        #pragma unroll
        for (int off = 32; off > 0; off >>= 1) p += __shfl_down(p, off, 64);
        if (lane == 0) yv[wid][j] = p + head_b[j];
    }
    if (lane == 0) {
        float* y = yv[wid];
        float* op = out + (size_t)t * 40;
        int am = 0; float best = y[0];
        for (int j = 1; j < 11; ++j) if (y[j] > best) { best = y[j]; am = j; }
        float fc_reg = softplus_f(y[11]);
        op[0] = (am < 10) ? (float)(am + 1) : fc_reg;
        for (int j = 0; j < 11; ++j) op[1 + j] = y[j];
        op[12] = fc_reg;
        int am2 = 0; float best2 = y[12];
        for (int j = 1; j < 11; ++j) if (y[12 + j] > best2) { best2 = y[12 + j]; am2 = j; }
        float ec_reg = softplus_f(y[23]);
        op[13] = (am2 < 10) ? (float)(am2 + 1) : ec_reg;
        for (int j = 0; j < 11; ++j) op[14 + j] = y[12 + j];
        op[25] = ec_reg;
        float bm_log = y[24];
        op[26] = 1.0f / (1.0f + expf(-bm_log));
        float mi = fmaxf(y[25], fmaxf(y[26], y[27]));
        float e0 = expf(y[25] - mi), e1 = expf(y[26] - mi), e2 = expf(y[27] - mi);
        float si = e0 + e1 + e2;
        op[27] = e0 / si; op[28] = e1 / si; op[29] = e2 / si;
        float md = fmaxf(y[28], fmaxf(y[29], y[30]));
        float d0 = expf(y[28] - md), d1 = expf(y[29] - md), d2 = expf(y[30] - md);
        float sd = d0 + d1 + d2;
        op[30] = d0 / sd; op[31] = d1 / sd; op[32] = d2 / sd;
        op[33] = bm_log;
        op[34] = y[25]; op[35] = y[26]; op[36] = y[27];
        op[37] = y[28]; op[38] = y[29]; op[39] = y[30];
    }
}

// ---------------- launch -------------------------------------------------------
extern "C" void kernel_launch(void* const* d_in, const int* in_sizes, int n_in,
                              void* d_out, int out_size, void* d_ws, size_t ws_size,
                              hipStream_t stream) {
    const int*   x        = (const int*)d_in[0];
    const float* emb      = (const float*)d_in[1];
    const float* reg_w    = (const float*)d_in[2];
    const float* reg_b    = (const float*)d_in[3];
    const float* br_w     = (const float*)d_in[4];
    const float* br_b     = (const float*)d_in[5];
    const float* sh_w     = (const float*)d_in[6];
    const float* sh_b     = (const float*)d_in[7];
    const float* inst_w   = (const float*)d_in[8];
    const float* inst_b   = (const float*)d_in[9];
    const float* enc_ln_w = (const float*)d_in[10];
    const float* enc_ln_b = (const float*)d_in[11];
    const float* qkv_w    = (const float*)d_in[12];
    const float* out_w    = (const float*)d_in[13];
    const float* out_b    = (const float*)d_in[14];
    const float* w1_w     = (const float*)d_in[15];
    const float* w1_b     = (const float*)d_in[16];
    const float* w3_w     = (const float*)d_in[17];
    const float* w3_b     = (const float*)d_in[18];
    const float* w2_w     = (const float*)d_in[19];
    const float* w2_b     = (const float*)d_in[20];
    const float* n1_w     = (const float*)d_in[21];
    const float* n2_w     = (const float*)d_in[22];
    const float* hl_w     = (const float*)d_in[23];
    const float* hl_b     = (const float*)d_in[24];
    const float* head_w   = (const float*)d_in[25];
    const float* head_b   = (const float*)d_in[26];

    char* ws = (char*)d_ws;
    size_t off = 0;
    ushort_t* inst2 = (ushort_t*)(ws + off); off += (size_t)512 * 1536 * 2;
    ushort_t* qkv2  = (ushort_t*)(ws + off); off += (size_t)3 * 1536 * 1024 * 2;
    ushort_t* out2w = (ushort_t*)(ws + off); off += (size_t)3 * 512 * 1024 * 2;
    ushort_t* w1s   = (ushort_t*)(ws + off); off += (size_t)3 * DFFP * 1024 * 2;
    ushort_t* w3s   = (ushort_t*)(ws + off); off += (size_t)3 * DFFP * 1024 * 2;
    ushort_t* w2s   = (ushort_t*)(ws + off); off += (size_t)3 * 512 * (2 * KP2) * 2;
    float*    ct    = (float*)(ws + off);    off += (size_t)LSEQ * 32 * 4;
    float*    st    = (float*)(ws + off);    off += (size_t)LSEQ * 32 * 4;
    float*    h     = (float*)(ws + off);    off += (size_t)T_TOK * 512 * 4;
    ushort_t* x2    = (ushort_t*)(ws + off); off += (size_t)T_TOK * 1024 * 2;
    ushort_t* attn2 = (ushort_t*)(ws + off); off += (size_t)T_TOK * 1024 * 2;
    float*    qkvb  = (float*)(ws + off);    off += (size_t)T_TOK * 1536 * 4;
    ushort_t* cat2  = (ushort_t*)(ws + off); off += (size_t)T_TOK * (2 * KP2) * 2;
    ushort_t* Wc2   = (ushort_t*)(ws + off); off += (size_t)640 * 576 * 2;
    float*    bc    = (float*)(ws + off);    off += 640 * 4;
    ushort_t* g2    = cat2;
    ushort_t* X2    = (ushort_t*)qkvb;   // 8192*288*2 = 4.7MB, inside qkvb region

    prep_const<<<896, 256, 0, stream>>>(ct, st, reg_w, reg_b, br_w, br_b,
                                        sh_w, sh_b, Wc2, bc);
    prep_tok<<<T_TOK, 256, 0, stream>>>(x, emb, X2, cat2);
    splitw_kernel<<<dim3(3, 512), 256, 0, stream>>>(inst_w, inst2, 512, 768, 768);
    splitw_qkv_kernel<<<dim3(2, 1536, 3), 256, 0, stream>>>(qkv_w, qkv2);
    splitw_kernel<<<dim3(2, 3 * 512), 256, 0, stream>>>(out_w, out2w, 3 * 512, 512, 512);
    splitw_ffn<<<dim3(2, 3 * DFFP), 256, 0, stream>>>(w1_w, w3_w, w1s, w3s);
    splitw_w2<<<dim3(6, 3 * 512), 256, 0, stream>>>(w2_w, w2s);

    gemm3_enc<<<dim3(64, 10), 256, 0, stream>>>(X2, Wc2, bc, cat2);
    gemm3_n64<<<dim3(64, 8), 256, 0, stream>>>(
        cat2, 1536, inst2, 1536, inst_b, nullptr, h, 512, 768);
    ln_silu_kernel<<<T_TOK / 4, 256, 0, stream>>>(h, enc_ln_w, enc_ln_b, h);

    for (int l = 0; l < NLAYER; ++l) {
        rms_kernel<<<T_TOK / 4, 256, 0, stream>>>(h, n1_w + l * 512, x2);
        gemm3_kernel<<<dim3(64, 12), 256, 0, stream>>>(
            x2, 1024, qkv2 + (size_t)l * 1536 * 1024, 1024, nullptr, nullptr,
            qkvb, 1536, 512);
        {
            dim3 g(NBLK, NHEAD, BATCH);
            attn_kernel<<<g, 256, 0, stream>>>(qkvb, ct, st, attn2);
        }
        gemm3_n64<<<dim3(64, 8), 256, 0, stream>>>(
            attn2, 1024, out2w + (size_t)l * 512 * 1024, 1024, out_b + l * 512,
            h, h, 512, 512);
        rms_kernel<<<T_TOK / 4, 256, 0, stream>>>(h, n2_w + l * 512, x2);
        gemm_glu3<<<dim3(64, 11), 256, 0, stream>>>(
            x2, w1s + (size_t)l * DFFP * 1024, w3s + (size_t)l * DFFP * 1024,
            w1_b + l * DFF, w3_b + l * DFF, g2);
        gemm3_n64<<<dim3(64, 8), 256, 0, stream>>>(
            g2, 2 * KP2, w2s + (size_t)l * 512 * (2 * KP2), 2 * KP2, w2_b + l * 512,
            h, h, 512, KP2);
    }

    head_kernel<<<T_TOK / 4, 256, 0, stream>>>(h, hl_w, hl_b, head_w, head_b,
                                               (float*)d_out);
}

// Round 9
// 1114.365 us; speedup vs baseline: 5.0954x; 1.0479x over previous
//
#include <hip/hip_runtime.h>
#include <hip/hip_bf16.h>
#include <math.h>

#define T_TOK 8192
#define DMODEL 512
#define NHEAD 8
#define TEDIM 192
#define DFF 1365
#define DFFP 1408
#define KP2 1376
#define NLAYER 3
#define WINSZ 128
#define NBLK 16
#define LSEQ 2048
#define BATCH 4

typedef unsigned short ushort_t;
typedef __bf16 bf16x8 __attribute__((ext_vector_type(8)));
typedef float f32x4 __attribute__((ext_vector_type(4)));
typedef float f32x16 __attribute__((ext_vector_type(16)));

__device__ __forceinline__ float silu_f(float x) { return x / (1.0f + expf(-x)); }
__device__ __forceinline__ float softplus_f(float x) {
    return (x > 20.0f) ? x : log1pf(expf(x));
}

__device__ __forceinline__ ushort_t f2u(float x) {
    __hip_bfloat16 b = __float2bfloat16(x);
    return *reinterpret_cast<ushort_t*>(&b);
}
__device__ __forceinline__ float u2f(ushort_t u) {
    __hip_bfloat16 b = *reinterpret_cast<__hip_bfloat16*>(&u);
    return __bfloat162float(b);
}
__device__ __forceinline__ void split2(float x, ushort_t& hi, ushort_t& lo) {
    hi = f2u(x);
    lo = f2u(x - u2f(hi));
}

__device__ __forceinline__ void gl_lds16(const ushort_t* g, ushort_t* l) {
    __builtin_amdgcn_global_load_lds(
        (const __attribute__((address_space(1))) unsigned int*)g,
        (__attribute__((address_space(3))) unsigned int*)l, 16, 0, 0);
}

// ---------------- RoPE table + encoder combined weight (merged) ---------------
__global__ __launch_bounds__(256)
void prep_const(float* __restrict__ ct, float* __restrict__ st,
                const float* __restrict__ reg_w, const float* __restrict__ reg_b,
                const float* __restrict__ br_w, const float* __restrict__ br_b,
                const float* __restrict__ sh_w, const float* __restrict__ sh_b,
                ushort_t* __restrict__ Wc2, float* __restrict__ bc) {
    int bx = blockIdx.x;
    int tid = threadIdx.x;
    if (bx < 256) {
        int idx = bx * 256 + tid;
        int tok = idx >> 5, p = idx & 31;
        float invf = powf(10000.0f, -(float)p * (1.0f / 32.0f));
        float sn, cs;
        sincosf((float)tok * invf, &sn, &cs);
        ct[idx] = cs;
        st[idx] = sn;
        return;
    }
    int n = bx - 256;
    for (int k = tid; k < 288; k += 256) {
        float v = 0.0f;
        if (n < 192) {
            if (k < 64) v = reg_w[(size_t)n * 64 + k];
        } else if (n < 384) {
            if (k >= 256) v = br_w[(size_t)(n - 192) * 32 + (k - 256)];
        } else if (n < 576) {
            if (k >= 64 && k < 256) v = sh_w[(size_t)(n - 384) * 192 + (k - 64)];
        }
        ushort_t hi, lo;
        split2(v, hi, lo);
        Wc2[(size_t)n * 576 + k] = hi;
        Wc2[(size_t)n * 576 + 288 + k] = lo;
    }
    if (tid == 0) {
        float b = 0.0f;
        if (n < 192) b = reg_b[n];
        else if (n < 384) b = br_b[n - 192];
        else if (n < 576) b = sh_b[n - 384];
        bc[n] = b;
    }
}

// ---------------- weight splits ------------------------------------------------
__global__ __launch_bounds__(256)
void splitw_kernel(const float* __restrict__ W, ushort_t* __restrict__ W2,
                   int N, int K, int Kp) {
    int n = blockIdx.y;
    int k = blockIdx.x * 256 + threadIdx.x;
    if (k >= Kp) return;
    float v = (n < N && k < K) ? W[(size_t)n * K + k] : 0.0f;
    ushort_t hi, lo;
    split2(v, hi, lo);
    W2[(size_t)n * (2 * Kp) + k] = hi;
    W2[(size_t)n * (2 * Kp) + Kp + k] = lo;
}

__global__ __launch_bounds__(256)
void splitw_qkv_kernel(const float* __restrict__ W, ushort_t* __restrict__ W2) {
    int l = blockIdx.z;
    int rr = blockIdx.y;
    int k = blockIdx.x * 256 + threadIdx.x;
    int h = rr / 192, rem = rr % 192;
    int dk = rem / 3, which = rem % 3;
    int rp = which * 512 + h * 64 + dk;
    float v = W[((size_t)l * 1536 + rr) * 512 + k];
    ushort_t hi, lo;
    split2(v, hi, lo);
    W2[((size_t)l * 1536 + rp) * 1024 + k] = hi;
    W2[((size_t)l * 1536 + rp) * 1024 + 512 + k] = lo;
}

__global__ __launch_bounds__(256)
void splitw_ffn(const float* __restrict__ w1, const float* __restrict__ w3,
                ushort_t* __restrict__ W1s, ushort_t* __restrict__ W3s) {
    int rr = blockIdx.y;
    int k = blockIdx.x * 256 + threadIdx.x;
    int lyr = rr / DFFP, n = rr % DFFP;
    bool ok = (n < DFF);
    float v1 = ok ? w1[((size_t)lyr * DFF + n) * 512 + k] : 0.0f;
    float v3 = ok ? w3[((size_t)lyr * DFF + n) * 512 + k] : 0.0f;
    ushort_t hi, lo;
    split2(v1, hi, lo);
    W1s[(size_t)rr * 1024 + k] = hi;
    W1s[(size_t)rr * 1024 + 512 + k] = lo;
    split2(v3, hi, lo);
    W3s[(size_t)rr * 1024 + k] = hi;
    W3s[(size_t)rr * 1024 + 512 + k] = lo;
}

__global__ __launch_bounds__(256)
void splitw_w2(const float* __restrict__ W, ushort_t* __restrict__ W2) {
    int rr = blockIdx.y;
    int k = blockIdx.x * 256 + threadIdx.x;
    if (k >= KP2) return;
    int lyr = rr >> 9, n = rr & 511;
    float v = (k < DFF) ? W[((size_t)lyr * 512 + n) * DFF + k] : 0.0f;
    ushort_t hi, lo;
    split2(v, hi, lo);
    W2[(size_t)rr * (2 * KP2) + k] = hi;
    W2[(size_t)rr * (2 * KP2) + KP2 + k] = lo;
}

// ---------------- token prep (X hi only — ints are bf16-exact) ----------------
__global__ __launch_bounds__(256)
void prep_tok(const int* __restrict__ x, const float* __restrict__ emb,
              ushort_t* __restrict__ X2, ushort_t* __restrict__ cat2) {
    int tok = blockIdx.x;
    int tid = threadIdx.x;
    const int* xp = x + (size_t)tok * 289;
    for (int k = tid; k < 288; k += 256)
        X2[(size_t)tok * 288 + k] = f2u((float)xp[1 + k]);
    int tokid = xp[0];
    for (int c = tid; c < 192; c += 256) {
        float v = silu_f(emb[(size_t)tokid * TEDIM + c]);
        ushort_t hi, lo;
        split2(v, hi, lo);
        cat2[(size_t)tok * 1536 + c] = hi;
        cat2[(size_t)tok * 1536 + 768 + c] = lo;
    }
}

// ======== GEMM machinery ======================================================
// LDS: [rows][4 x 16B k-chunks]. Chunk c of row r at slot (c + (r>>1)) & 3.
// Staging lane tid: global chunk ((tid&3) - (tid>>3)) & 3 of row tid>>2.

#define MFMA32(a, b, c) __builtin_amdgcn_mfma_f32_32x32x16_bf16(a, b, c, 0, 0, 0)
#define MFMA16(a, b, c) __builtin_amdgcn_mfma_f32_16x16x32_bf16(a, b, c, 0, 0, 0)

// ---------------- 128x128 GEMM, 16x16 frags (VGPR<=128 -> 4 waves/SIMD) -------
// grid (Mtiles=64, Ntiles). fp32 out + bias/res.
__global__ __launch_bounds__(256)
void gemm3_kernel(const ushort_t* __restrict__ A2, int rsA,
                  const ushort_t* __restrict__ B2, int rsB,
                  const float* __restrict__ bias,
                  const float* __restrict__ res,
                  float* __restrict__ Cf, int rsC, int Kp) {
    __shared__ __align__(16) ushort_t lds[4 * 4096];
    const int tid = threadIdx.x;
    const int bm = blockIdx.x * 128, bn = blockIdx.y * 128;
    const int w = tid >> 6, l = tid & 63;
    const int wm = (w & 1) * 64, wn = (w >> 1) * 64;

    f32x4 acc[4][4];
    #pragma unroll
    for (int i = 0; i < 4; ++i)
        #pragma unroll
        for (int j = 0; j < 4; ++j) acc[i][j] = (f32x4){0.f, 0.f, 0.f, 0.f};

    const int r0 = tid >> 2;
    const int k8 = (((tid & 3) - (tid >> 3)) & 3) * 8;
    const ushort_t* gA0 = A2 + (size_t)(bm + r0) * rsA + k8;
    const ushort_t* gA1 = A2 + (size_t)(bm + 64 + r0) * rsA + k8;
    const ushort_t* gB0 = B2 + (size_t)(bn + r0) * rsB + k8;
    const ushort_t* gB1 = B2 + (size_t)(bn + 64 + r0) * rsB + k8;
    ushort_t* l0 = lds + tid * 8;
    ushort_t* l1 = lds + 2048 + tid * 8;

    const int fr = l & 15, q = l >> 4;

    for (int kt = 0; kt < Kp; kt += 32) {
        gl_lds16(gA0 + kt, l0);
        gl_lds16(gA1 + kt, l1);
        gl_lds16(gA0 + kt + Kp, l0 + 4096);
        gl_lds16(gA1 + kt + Kp, l1 + 4096);
        gl_lds16(gB0 + kt, l0 + 8192);
        gl_lds16(gB1 + kt, l1 + 8192);
        gl_lds16(gB0 + kt + Kp, l0 + 12288);
        gl_lds16(gB1 + kt + Kp, l1 + 12288);
        __syncthreads();

        bf16x8 ahi[4], alo[4], bhi[4], blo[4];
        #pragma unroll
        for (int i = 0; i < 4; ++i) {
            int rowa = wm + i * 16 + fr;
            int ba = rowa * 32 + (((q + (rowa >> 1)) & 3) * 8);
            ahi[i] = *(const bf16x8*)&lds[ba];
            alo[i] = *(const bf16x8*)&lds[4096 + ba];
            int rowb = wn + i * 16 + fr;
            int bb = rowb * 32 + (((q + (rowb >> 1)) & 3) * 8);
            bhi[i] = *(const bf16x8*)&lds[8192 + bb];
            blo[i] = *(const bf16x8*)&lds[12288 + bb];
        }
        #pragma unroll
        for (int i = 0; i < 4; ++i)
            #pragma unroll
            for (int j = 0; j < 4; ++j) {
                acc[i][j] = MFMA16(ahi[i], bhi[j], acc[i][j]);
                acc[i][j] = MFMA16(ahi[i], blo[j], acc[i][j]);
                acc[i][j] = MFMA16(alo[i], bhi[j], acc[i][j]);
            }
        __syncthreads();
    }

    const int er = (l >> 4) * 4, ec = l & 15;
    #pragma unroll
    for (int i = 0; i < 4; ++i)
        #pragma unroll
        for (int j = 0; j < 4; ++j)
            #pragma unroll
            for (int r = 0; r < 4; ++r) {
                int gm = bm + wm + i * 16 + er + r;
                int gn = bn + wn + j * 16 + ec;
                float v = acc[i][j][r];
                if (bias) v += bias[gn];
                if (res) v += res[(size_t)gm * rsC + gn];
                Cf[(size_t)gm * rsC + gn] = v;
            }
}

// ---------------- 128x64 GEMM 32x32 frags (N=512 cases) -----------------------
__global__ __launch_bounds__(256)
void gemm3_n64(const ushort_t* __restrict__ A2, int rsA,
               const ushort_t* __restrict__ B2, int rsB,
               const float* __restrict__ bias,
               const float* __restrict__ res,
               float* __restrict__ Cf, int rsC, int Kp) {
    __shared__ __align__(16) ushort_t lds[12288];
    const int tid = threadIdx.x;
    const int bm = blockIdx.x * 128, bn = blockIdx.y * 64;
    const int w = tid >> 6, l = tid & 63;
    const int wm = (w & 1) * 64, wn = (w >> 1) * 32;

    f32x16 acc[2];
    #pragma unroll
    for (int i = 0; i < 2; ++i)
        #pragma unroll
        for (int r = 0; r < 16; ++r) acc[i][r] = 0.0f;

    const int r0 = tid >> 2;
    const int k8 = (((tid & 3) - (tid >> 3)) & 3) * 8;
    const ushort_t* gA0 = A2 + (size_t)(bm + r0) * rsA + k8;
    const ushort_t* gA1 = A2 + (size_t)(bm + 64 + r0) * rsA + k8;
    const ushort_t* gB0 = B2 + (size_t)(bn + r0) * rsB + k8;
    ushort_t* l0 = lds + tid * 8;
    ushort_t* l1 = lds + 2048 + tid * 8;

    const int ar = l & 31, qh = l >> 5;

    for (int kt = 0; kt < Kp; kt += 32) {
        gl_lds16(gA0 + kt, l0);
        gl_lds16(gA1 + kt, l1);
        gl_lds16(gA0 + kt + Kp, l0 + 4096);
        gl_lds16(gA1 + kt + Kp, l1 + 4096);
        gl_lds16(gB0 + kt, l0 + 8192);
        gl_lds16(gB0 + kt + Kp, l0 + 10240);
        __syncthreads();

        #pragma unroll
        for (int kh = 0; kh < 2; ++kh) {
            const int kq = kh * 2 + qh;
            bf16x8 ah[2], al_[2];
            #pragma unroll
            for (int i = 0; i < 2; ++i) {
                int row = wm + i * 32 + ar;
                int ba = row * 32 + (((kq + (row >> 1)) & 3) * 8);
                ah[i]  = *(const bf16x8*)&lds[ba];
                al_[i] = *(const bf16x8*)&lds[4096 + ba];
            }
            int rowb = wn + ar;
            int bb = rowb * 32 + (((kq + (rowb >> 1)) & 3) * 8);
            bf16x8 bh = *(const bf16x8*)&lds[8192 + bb];
            bf16x8 bl = *(const bf16x8*)&lds[10240 + bb];
            #pragma unroll
            for (int i = 0; i < 2; ++i) {
                acc[i] = MFMA32(ah[i], bh, acc[i]);
                acc[i] = MFMA32(ah[i], bl, acc[i]);
                acc[i] = MFMA32(al_[i], bh, acc[i]);
            }
        }
        __syncthreads();
    }

    const int ec = l & 31, rb = (l >> 5) * 4;
    int gn = bn + wn + ec;
    float bv = bias ? bias[gn] : 0.0f;
    #pragma unroll
    for (int i = 0; i < 2; ++i)
        #pragma unroll
        for (int r = 0; r < 16; ++r) {
            int gm = bm + wm + i * 32 + rb + (r & 3) + 8 * (r >> 2);
            float v = acc[i][r] + bv;
            if (res) v += res[(size_t)gm * rsC + gn];
            Cf[(size_t)gm * rsC + gn] = v;
        }
}

// ---------------- encoder GEMM (A exact-bf16, hi only): 128x64 ----------------
__global__ __launch_bounds__(256)
void gemm3_enc(const ushort_t* __restrict__ A2, const ushort_t* __restrict__ B2,
               const float* __restrict__ bc, ushort_t* __restrict__ cat2) {
    __shared__ __align__(16) ushort_t lds[8192];
    const int tid = threadIdx.x;
    const int bm = blockIdx.x * 128, bn = blockIdx.y * 64;
    const int w = tid >> 6, l = tid & 63;
    const int wm = (w & 1) * 64, wn = (w >> 1) * 32;
    const int Kp = 288;

    f32x16 acc[2];
    #pragma unroll
    for (int i = 0; i < 2; ++i)
        #pragma unroll
        for (int r = 0; r < 16; ++r) acc[i][r] = 0.0f;

    const int r0 = tid >> 2;
    const int k8 = (((tid & 3) - (tid >> 3)) & 3) * 8;
    const ushort_t* gA0 = A2 + (size_t)(bm + r0) * 288 + k8;
    const ushort_t* gA1 = A2 + (size_t)(bm + 64 + r0) * 288 + k8;
    const ushort_t* gB0 = B2 + (size_t)(bn + r0) * 576 + k8;
    ushort_t* l0 = lds + tid * 8;
    ushort_t* l1 = lds + 2048 + tid * 8;
    const int ar = l & 31, qh = l >> 5;

    for (int kt = 0; kt < Kp; kt += 32) {
        gl_lds16(gA0 + kt, l0);
        gl_lds16(gA1 + kt, l1);
        gl_lds16(gB0 + kt, l0 + 4096);
        gl_lds16(gB0 + kt + Kp, l0 + 6144);
        __syncthreads();
        #pragma unroll
        for (int kh = 0; kh < 2; ++kh) {
            const int kq = kh * 2 + qh;
            bf16x8 ah[2];
            #pragma unroll
            for (int i = 0; i < 2; ++i) {
                int row = wm + i * 32 + ar;
                int ba = row * 32 + (((kq + (row >> 1)) & 3) * 8);
                ah[i] = *(const bf16x8*)&lds[ba];
            }
            int rowb = wn + ar;
            int bb = rowb * 32 + (((kq + (rowb >> 1)) & 3) * 8);
            bf16x8 bh = *(const bf16x8*)&lds[4096 + bb];
            bf16x8 bl = *(const bf16x8*)&lds[6144 + bb];
            #pragma unroll
            for (int i = 0; i < 2; ++i) {
                acc[i] = MFMA32(ah[i], bh, acc[i]);
                acc[i] = MFMA32(ah[i], bl, acc[i]);
            }
        }
        __syncthreads();
    }

    const int ec = l & 31, rb = (l >> 5) * 4;
    int gn = bn + wn + ec;
    if (gn < 576) {
        float bv = bc[gn];
        #pragma unroll
        for (int i = 0; i < 2; ++i)
            #pragma unroll
            for (int r = 0; r < 16; ++r) {
                int gm = bm + wm + i * 32 + rb + (r & 3) + 8 * (r >> 2);
                float v = silu_f(acc[i][r] + bv);
                ushort_t hi, lo;
                split2(v, hi, lo);
                cat2[(size_t)gm * 1536 + 192 + gn] = hi;
                cat2[(size_t)gm * 1536 + 960 + gn] = lo;
            }
    }
}

// ---------------- fused GLU GEMM (128x128, 16x16 frags) -----------------------
__global__ __launch_bounds__(256)
void gemm_glu3(const ushort_t* __restrict__ A2,
               const ushort_t* __restrict__ W1, const ushort_t* __restrict__ W3,
               const float* __restrict__ b1, const float* __restrict__ b3,
               ushort_t* __restrict__ C2) {
    __shared__ __align__(16) ushort_t lds[6 * 4096];
    const int tid = threadIdx.x;
    const int bm = blockIdx.x * 128, bn = blockIdx.y * 128;
    const int w = tid >> 6, l = tid & 63;
    const int wm = (w & 1) * 64, wn = (w >> 1) * 64;
    const int Kp = 512;

    f32x4 acc1[4][4], acc3[4][4];
    #pragma unroll
    for (int i = 0; i < 4; ++i)
        #pragma unroll
        for (int j = 0; j < 4; ++j) {
            acc1[i][j] = (f32x4){0.f, 0.f, 0.f, 0.f};
            acc3[i][j] = (f32x4){0.f, 0.f, 0.f, 0.f};
        }

    const int r0 = tid >> 2;
    const int k8 = (((tid & 3) - (tid >> 3)) & 3) * 8;
    const ushort_t* gA0 = A2 + (size_t)(bm + r0) * 1024 + k8;
    const ushort_t* gA1 = A2 + (size_t)(bm + 64 + r0) * 1024 + k8;
    const ushort_t* g10 = W1 + (size_t)(bn + r0) * 1024 + k8;
    const ushort_t* g11 = W1 + (size_t)(bn + 64 + r0) * 1024 + k8;
    const ushort_t* g30 = W3 + (size_t)(bn + r0) * 1024 + k8;
    const ushort_t* g31 = W3 + (size_t)(bn + 64 + r0) * 1024 + k8;
    ushort_t* l0 = lds + tid * 8;
    ushort_t* l1 = lds + 2048 + tid * 8;
    const int fr = l & 15, q = l >> 4;

    for (int kt = 0; kt < Kp; kt += 32) {
        gl_lds16(gA0 + kt, l0);
        gl_lds16(gA1 + kt, l1);
        gl_lds16(gA0 + kt + Kp, l0 + 4096);
        gl_lds16(gA1 + kt + Kp, l1 + 4096);
        gl_lds16(g10 + kt, l0 + 8192);
        gl_lds16(g11 + kt, l1 + 8192);
        gl_lds16(g10 + kt + Kp, l0 + 12288);
        gl_lds16(g11 + kt + Kp, l1 + 12288);
        gl_lds16(g30 + kt, l0 + 16384);
        gl_lds16(g31 + kt, l1 + 16384);
        gl_lds16(g30 + kt + Kp, l0 + 20480);
        gl_lds16(g31 + kt + Kp, l1 + 20480);
        __syncthreads();

        bf16x8 ahi[4], alo[4];
        #pragma unroll
        for (int i = 0; i < 4; ++i) {
            int rowa = wm + i * 16 + fr;
            int ba = rowa * 32 + (((q + (rowa >> 1)) & 3) * 8);
            ahi[i] = *(const bf16x8*)&lds[ba];
            alo[i] = *(const bf16x8*)&lds[4096 + ba];
        }
        #pragma unroll
        for (int j = 0; j < 4; ++j) {
            int rowb = wn + j * 16 + fr;
            int bb = rowb * 32 + (((q + (rowb >> 1)) & 3) * 8);
            bf16x8 w1h = *(const bf16x8*)&lds[8192 + bb];
            bf16x8 w1l = *(const bf16x8*)&lds[12288 + bb];
            bf16x8 w3h = *(const bf16x8*)&lds[16384 + bb];
            bf16x8 w3l = *(const bf16x8*)&lds[20480 + bb];
            #pragma unroll
            for (int i = 0; i < 4; ++i) {
                acc1[i][j] = MFMA16(ahi[i], w1h, acc1[i][j]);
                acc1[i][j] = MFMA16(ahi[i], w1l, acc1[i][j]);
                acc1[i][j] = MFMA16(alo[i], w1h, acc1[i][j]);
                acc3[i][j] = MFMA16(ahi[i], w3h, acc3[i][j]);
                acc3[i][j] = MFMA16(ahi[i], w3l, acc3[i][j]);
                acc3[i][j] = MFMA16(alo[i], w3h, acc3[i][j]);
            }
        }
        __syncthreads();
    }

    const int er = (l >> 4) * 4, ec = l & 15;
    #pragma unroll
    for (int i = 0; i < 4; ++i)
        #pragma unroll
        for (int j = 0; j < 4; ++j)
            #pragma unroll
            for (int r = 0; r < 4; ++r) {
                int gm = bm + wm + i * 16 + er + r;
                int gn = bn + wn + j * 16 + ec;
                if (gn < KP2) {
                    float u1 = acc1[i][j][r], u3 = acc3[i][j][r];
                    if (gn < DFF) { u1 += b1[gn]; u3 += b3[gn]; }
                    float g = silu_f(u1) * u3;
                    ushort_t hi, lo;
                    split2(g, hi, lo);
                    C2[(size_t)gm * (2 * KP2) + gn] = hi;
                    C2[(size_t)gm * (2 * KP2) + KP2 + gn] = lo;
                }
            }
}

// ---------------- per-token reductions (wave-per-token) -----------------------
__global__ __launch_bounds__(256)
void rms_kernel(const float* __restrict__ h, const float* __restrict__ w,
                ushort_t* __restrict__ out2) {
    int wid = threadIdx.x >> 6, lane = threadIdx.x & 63;
    int t = blockIdx.x * 4 + wid;
    const float* hp = h + (size_t)t * 512;
    float2 xv[4];
    float ss = 0.0f;
    #pragma unroll
    for (int u = 0; u < 4; ++u) {
        xv[u] = *(const float2*)&hp[u * 128 + lane * 2];
        ss += xv[u].x * xv[u].x + xv[u].y * xv[u].y;
    }
    #pragma unroll
    for (int off = 32; off > 0; off >>= 1) ss += __shfl_xor(ss, off, 64);
    float inv = rsqrtf(ss * (1.0f / 512.0f) + 1.1920929e-07f);
    ushort_t* op = out2 + (size_t)t * 1024;
    #pragma unroll
    for (int u = 0; u < 4; ++u) {
        float2 wv = *(const float2*)&w[u * 128 + lane * 2];
        ushort2 hv, lv;
        split2(xv[u].x * inv * wv.x, hv.x, lv.x);
        split2(xv[u].y * inv * wv.y, hv.y, lv.y);
        *(ushort2*)&op[u * 128 + lane * 2] = hv;
        *(ushort2*)&op[512 + u * 128 + lane * 2] = lv;
    }
}

__global__ __launch_bounds__(256)
void ln_silu_kernel(const float* __restrict__ h, const float* __restrict__ w,
                    const float* __restrict__ b, float* __restrict__ out) {
    int wid = threadIdx.x >> 6, lane = threadIdx.x & 63;
    int t = blockIdx.x * 4 + wid;
    const float* hp = h + (size_t)t * 512;
    float xv[8];
    float s = 0.0f;
    #pragma unroll
    for (int u = 0; u < 8; ++u) { xv[u] = hp[u * 64 + lane]; s += xv[u]; }
    #pragma unroll
    for (int off = 32; off > 0; off >>= 1) s += __shfl_xor(s, off, 64);
    float m = s * (1.0f / 512.0f);
    float v = 0.0f;
    #pragma unroll
    for (int u = 0; u < 8; ++u) { xv[u] -= m; v += xv[u] * xv[u]; }
    #pragma unroll
    for (int off = 32; off > 0; off >>= 1) v += __shfl_xor(v, off, 64);
    float inv = rsqrtf(v * (1.0f / 512.0f) + 1e-5f);
    float* op = out + (size_t)t * 512;
    #pragma unroll
    for (int u = 0; u < 8; ++u)
        op[u * 64 + lane] = silu_f(xv[u] * inv * w[u * 64 + lane] + b[u * 64 + lane]);
}

// ---------------- MFMA local attention (16x16 path) ---------------------------
__global__ __launch_bounds__(256)
void attn_kernel(const float* __restrict__ qkv, const float* __restrict__ ct,
                 const float* __restrict__ st, ushort_t* __restrict__ attn2) {
    __shared__ __align__(16) ushort_t Khi[32 * 64], Klo[32 * 64];
    __shared__ __align__(16) ushort_t Vthi[64 * 32], Vtlo[64 * 32];
    __shared__ __align__(16) ushort_t Phi[128 * 32], Plo[128 * 32];
    const int nb = blockIdx.x, head = blockIdx.y, b = blockIdx.z;
    const int tid = threadIdx.x;
    const int w = tid >> 6, lane = tid & 63;
    const int quad = lane >> 4, lc = lane & 15;

    bf16x8 qhi[2][2], qlo[2][2];
    #pragma unroll
    for (int i = 0; i < 2; ++i) {
        int qtok = nb * 128 + w * 32 + i * 16 + lc;
        const float* qp = qkv + ((size_t)(b * LSEQ + qtok)) * 1536 + head * 64;
        #pragma unroll
        for (int s = 0; s < 2; ++s) {
            float4 a = *(const float4*)&qp[s * 32 + quad * 8];
            float4 bq = *(const float4*)&qp[s * 32 + quad * 8 + 4];
            float4 c4 = *(const float4*)&ct[qtok * 32 + s * 16 + quad * 4];
            float4 s4 = *(const float4*)&st[qtok * 32 + s * 16 + quad * 4];
            float e[8];
            e[0] = (a.x * c4.x - a.y * s4.x) * 0.125f;
            e[1] = (a.x * s4.x + a.y * c4.x) * 0.125f;
            e[2] = (a.z * c4.y - a.w * s4.y) * 0.125f;
            e[3] = (a.z * s4.y + a.w * c4.y) * 0.125f;
            e[4] = (bq.x * c4.z - bq.y * s4.z) * 0.125f;
            e[5] = (bq.x * s4.z + bq.y * c4.z) * 0.125f;
            e[6] = (bq.z * c4.w - bq.w * s4.w) * 0.125f;
            e[7] = (bq.z * s4.w + bq.w * c4.w) * 0.125f;
            union { bf16x8 v; ushort_t u[8]; } hh, ll;
            #pragma unroll
            for (int d = 0; d < 8; ++d) split2(e[d], hh.u[d], ll.u[d]);
            qhi[i][s] = hh.v;
            qlo[i][s] = ll.v;
        }
    }

    f32x4 acc[2][4];
    float mrun[2][4], lrun[2][4];
    #pragma unroll
    for (int i = 0; i < 2; ++i) {
        #pragma unroll
        for (int j = 0; j < 4; ++j) acc[i][j] = (f32x4){0.f, 0.f, 0.f, 0.f};
        #pragma unroll
        for (int r = 0; r < 4; ++r) { mrun[i][r] = -1e30f; lrun[i][r] = 0.0f; }
    }

    const int c0 = (nb == 0) ? 4 : 0;
    for (int c = c0; c < 8; ++c) {
        {
            int key = tid >> 3, g = tid & 7;
            int ktok = nb * 128 - 128 + c * 32 + key;
            const float* kp = qkv + ((size_t)(b * LSEQ + ktok)) * 1536 + 512 + head * 64 + g * 8;
            float4 a = *(const float4*)kp;
            float4 bq = *(const float4*)(kp + 4);
            float4 c4 = *(const float4*)&ct[ktok * 32 + g * 4];
            float4 s4 = *(const float4*)&st[ktok * 32 + g * 4];
            float e[8];
            e[0] = a.x * c4.x - a.y * s4.x;
            e[1] = a.x * s4.x + a.y * c4.x;
            e[2] = a.z * c4.y - a.w * s4.y;
            e[3] = a.z * s4.y + a.w * c4.y;
            e[4] = bq.x * c4.z - bq.y * s4.z;
            e[5] = bq.x * s4.z + bq.y * c4.z;
            e[6] = bq.z * c4.w - bq.w * s4.w;
            e[7] = bq.z * s4.w + bq.w * c4.w;
            union { bf16x8 v; ushort_t u[8]; } hh, ll;
            #pragma unroll
            for (int d = 0; d < 8; ++d) split2(e[d], hh.u[d], ll.u[d]);
            int sg = g ^ (key & 7);
            *(bf16x8*)&Khi[key * 64 + sg * 8] = hh.v;
            *(bf16x8*)&Klo[key * 64 + sg * 8] = ll.v;

            const float* vp = kp + 512;
            float4 va = *(const float4*)vp;
            float4 vb = *(const float4*)(vp + 4);
            float ve[8] = {va.x, va.y, va.z, va.w, vb.x, vb.y, vb.z, vb.w};
            int kg = key >> 3, k7 = key & 7;
            #pragma unroll
            for (int d = 0; d < 8; ++d) {
                ushort_t vh, vl;
                split2(ve[d], vh, vl);
                int dim = g * 8 + d;
                int addr = dim * 32 + (((kg + (dim >> 1)) & 3) * 8) + k7;
                Vthi[addr] = vh;
                Vtlo[addr] = vl;
            }
        }
        __syncthreads();

        f32x4 sf[2][2];
        #pragma unroll
        for (int i = 0; i < 2; ++i)
            #pragma unroll
            for (int t = 0; t < 2; ++t) sf[i][t] = (f32x4){0.f, 0.f, 0.f, 0.f};
        #pragma unroll
        for (int t = 0; t < 2; ++t) {
            #pragma unroll
            for (int s = 0; s < 2; ++s) {
                int row = t * 16 + lc;
                int sg = (s * 4 + quad) ^ (row & 7);
                bf16x8 kh = *(const bf16x8*)&Khi[row * 64 + sg * 8];
                bf16x8 kl = *(const bf16x8*)&Klo[row * 64 + sg * 8];
                #pragma unroll
                for (int i = 0; i < 2; ++i) {
                    sf[i][t] = MFMA16(qhi[i][s], kh, sf[i][t]);
                    sf[i][t] = MFMA16(qhi[i][s], kl, sf[i][t]);
                    sf[i][t] = MFMA16(qlo[i][s], kh, sf[i][t]);
                }
            }
        }

        #pragma unroll
        for (int i = 0; i < 2; ++i) {
            #pragma unroll
            for (int r = 0; r < 4; ++r) {
                int qq = w * 32 + i * 16 + quad * 4 + r;
                float rm = -1e30f;
                #pragma unroll
                for (int t = 0; t < 2; ++t) {
                    int key = c * 32 + t * 16 + lc;
                    bool valid = (key >= qq) && (key <= qq + 128) && (nb > 0 || key >= 128);
                    float sv = valid ? sf[i][t][r] : -1e30f;
                    sf[i][t][r] = sv;
                    rm = fmaxf(rm, sv);
                }
                #pragma unroll
                for (int xm = 1; xm < 16; xm <<= 1)
                    rm = fmaxf(rm, __shfl_xor(rm, xm, 64));
                float mn = fmaxf(mrun[i][r], rm);
                float alpha = __expf(mrun[i][r] - mn);
                lrun[i][r] *= alpha;
                #pragma unroll
                for (int j = 0; j < 4; ++j) acc[i][j][r] *= alpha;
                float rs = 0.0f;
                #pragma unroll
                for (int t = 0; t < 2; ++t) {
                    int key = c * 32 + t * 16 + lc;
                    bool valid = (key >= qq) && (key <= qq + 128) && (nb > 0 || key >= 128);
                    float p = valid ? __expf(sf[i][t][r] - mn) : 0.0f;
                    rs += p;
                    ushort_t ph, pl;
                    split2(p, ph, pl);
                    int col = t * 16 + lc;
                    int addr = qq * 32 + ((((col >> 3) + (qq >> 1)) & 3) * 8) + (col & 7);
                    Phi[addr] = ph;
                    Plo[addr] = pl;
                }
                #pragma unroll
                for (int xm = 1; xm < 16; xm <<= 1)
                    rs += __shfl_xor(rs, xm, 64);
                lrun[i][r] += rs;
                mrun[i][r] = mn;
            }
        }

        bf16x8 ph[2], pl[2];
        #pragma unroll
        for (int i = 0; i < 2; ++i) {
            int row = w * 32 + i * 16 + lc;
            int sg = (quad + (row >> 1)) & 3;
            ph[i] = *(const bf16x8*)&Phi[row * 32 + sg * 8];
            pl[i] = *(const bf16x8*)&Plo[row * 32 + sg * 8];
        }
        #pragma unroll
        for (int j = 0; j < 4; ++j) {
            int dim = j * 16 + lc;
            int sg = (quad + (dim >> 1)) & 3;
            bf16x8 vh = *(const bf16x8*)&Vthi[dim * 32 + sg * 8];
            bf16x8 vl = *(const bf16x8*)&Vtlo[dim * 32 + sg * 8];
            #pragma unroll
            for (int i = 0; i < 2; ++i) {
                acc[i][j] = MFMA16(ph[i], vh, acc[i][j]);
                acc[i][j] = MFMA16(ph[i], vl, acc[i][j]);
                acc[i][j] = MFMA16(pl[i], vh, acc[i][j]);
            }
        }
        __syncthreads();
    }

    #pragma unroll
    for (int i = 0; i < 2; ++i) {
        #pragma unroll
        for (int r = 0; r < 4; ++r) {
            int qtok = nb * 128 + w * 32 + i * 16 + quad * 4 + r;
            size_t base = ((size_t)(b * LSEQ + qtok)) * 1024 + head * 64;
            float inv = 1.0f / lrun[i][r];
            #pragma unroll
            for (int j = 0; j < 4; ++j) {
                float v = acc[i][j][r] * inv;
                ushort_t hi, lo;
                split2(v, hi, lo);
                attn2[base + j * 16 + lc] = hi;
                attn2[base + 512 + j * 16 + lc] = lo;
            }
        }
    }
}

// ---------------- head: LN + silu + 31-dim head + postprocess -----------------
__global__ __launch_bounds__(256)
void head_kernel(const float* __restrict__ h, const float* __restrict__ lw,
                 const float* __restrict__ lb, const float* __restrict__ head_w,
                 const float* __restrict__ head_b, float* __restrict__ out) {
    int wid = threadIdx.x >> 6, lane = threadIdx.x & 63;
    int t = blockIdx.x * 4 + wid;
    __shared__ float yv[4][32];
    const float* xr = h + (size_t)t * 512;
    float xv[8];
    float s = 0.0f;
    #pragma unroll
    for (int u = 0; u < 8; ++u) { xv[u] = xr[u * 64 + lane]; s += xv[u]; }
    #pragma unroll
    for (int off = 32; off > 0; off >>= 1) s += __shfl_xor(s, off, 64);
    float m = s * (1.0f / 512.0f);
    float var = 0.0f;
    #pragma unroll
    for (int u = 0; u < 8; ++u) { xv[u] -= m; var += xv[u] * xv[u]; }
    #pragma unroll
    for (int off = 32; off > 0; off >>= 1) var += __shfl_xor(var, off, 64);
    float inv = rsqrtf(var * (1.0f / 512.0f) + 1e-5f);
    #pragma unroll
    for (int u = 0; u < 8; ++u)
        xv[u] = silu_f(xv[u] * inv * lw[u * 64 + lane] + lb[u * 64 + lane]);

    for (int j = 0; j < 31; ++j) {
        const float* wr = head_w + (size_t)j * 512;
        float p = 0.0f;
        #pragma unroll
        for (int u = 0; u < 8; ++u) p += xv[u] * wr[u * 64 + lane];
        #pragma unroll
        for (int off = 32; off > 0; off >>= 1) p += __shfl_down(p, off, 64);
        if (lane == 0) yv[wid][j] = p + head_b[j];
    }
    if (lane == 0) {
        float* y = yv[wid];
        float* op = out + (size_t)t * 40;
        int am = 0; float best = y[0];
        for (int j = 1; j < 11; ++j) if (y[j] > best) { best = y[j]; am = j; }
        float fc_reg = softplus_f(y[11]);
        op[0] = (am < 10) ? (float)(am + 1) : fc_reg;
        for (int j = 0; j < 11; ++j) op[1 + j] = y[j];
        op[12] = fc_reg;
        int am2 = 0; float best2 = y[12];
        for (int j = 1; j < 11; ++j) if (y[12 + j] > best2) { best2 = y[12 + j]; am2 = j; }
        float ec_reg = softplus_f(y[23]);
        op[13] = (am2 < 10) ? (float)(am2 + 1) : ec_reg;
        for (int j = 0; j < 11; ++j) op[14 + j] = y[12 + j];
        op[25] = ec_reg;
        float bm_log = y[24];
        op[26] = 1.0f / (1.0f + expf(-bm_log));
        float mi = fmaxf(y[25], fmaxf(y[26], y[27]));
        float e0 = expf(y[25] - mi), e1 = expf(y[26] - mi), e2 = expf(y[27] - mi);
        float si = e0 + e1 + e2;
        op[27] = e0 / si; op[28] = e1 / si; op[29] = e2 / si;
        float md = fmaxf(y[28], fmaxf(y[29], y[30]));
        float d0 = expf(y[28] - md), d1 = expf(y[29] - md), d2 = expf(y[30] - md);
        float sd = d0 + d1 + d2;
        op[30] = d0 / sd; op[31] = d1 / sd; op[32] = d2 / sd;
        op[33] = bm_log;
        op[34] = y[25]; op[35] = y[26]; op[36] = y[27];
        op[37] = y[28]; op[38] = y[29]; op[39] = y[30];
    }
}

// ---------------- launch -------------------------------------------------------
extern "C" void kernel_launch(void* const* d_in, const int* in_sizes, int n_in,
                              void* d_out, int out_size, void* d_ws, size_t ws_size,
                              hipStream_t stream) {
    const int*   x        = (const int*)d_in[0];
    const float* emb      = (const float*)d_in[1];
    const float* reg_w    = (const float*)d_in[2];
    const float* reg_b    = (const float*)d_in[3];
    const float* br_w     = (const float*)d_in[4];
    const float* br_b     = (const float*)d_in[5];
    const float* sh_w     = (const float*)d_in[6];
    const float* sh_b     = (const float*)d_in[7];
    const float* inst_w   = (const float*)d_in[8];
    const float* inst_b   = (const float*)d_in[9];
    const float* enc_ln_w = (const float*)d_in[10];
    const float* enc_ln_b = (const float*)d_in[11];
    const float* qkv_w    = (const float*)d_in[12];
    const float* out_w    = (const float*)d_in[13];
    const float* out_b    = (const float*)d_in[14];
    const float* w1_w     = (const float*)d_in[15];
    const float* w1_b     = (const float*)d_in[16];
    const float* w3_w     = (const float*)d_in[17];
    const float* w3_b     = (const float*)d_in[18];
    const float* w2_w     = (const float*)d_in[19];
    const float* w2_b     = (const float*)d_in[20];
    const float* n1_w     = (const float*)d_in[21];
    const float* n2_w     = (const float*)d_in[22];
    const float* hl_w     = (const float*)d_in[23];
    const float* hl_b     = (const float*)d_in[24];
    const float* head_w   = (const float*)d_in[25];
    const float* head_b   = (const float*)d_in[26];

    char* ws = (char*)d_ws;
    size_t off = 0;
    ushort_t* inst2 = (ushort_t*)(ws + off); off += (size_t)512 * 1536 * 2;
    ushort_t* qkv2  = (ushort_t*)(ws + off); off += (size_t)3 * 1536 * 1024 * 2;
    ushort_t* out2w = (ushort_t*)(ws + off); off += (size_t)3 * 512 * 1024 * 2;
    ushort_t* w1s   = (ushort_t*)(ws + off); off += (size_t)3 * DFFP * 1024 * 2;
    ushort_t* w3s   = (ushort_t*)(ws + off); off += (size_t)3 * DFFP * 1024 * 2;
    ushort_t* w2s   = (ushort_t*)(ws + off); off += (size_t)3 * 512 * (2 * KP2) * 2;
    float*    ct    = (float*)(ws + off);    off += (size_t)LSEQ * 32 * 4;
    float*    st    = (float*)(ws + off);    off += (size_t)LSEQ * 32 * 4;
    float*    h     = (float*)(ws + off);    off += (size_t)T_TOK * 512 * 4;
    ushort_t* x2    = (ushort_t*)(ws + off); off += (size_t)T_TOK * 1024 * 2;
    ushort_t* attn2 = (ushort_t*)(ws + off); off += (size_t)T_TOK * 1024 * 2;
    float*    qkvb  = (float*)(ws + off);    off += (size_t)T_TOK * 1536 * 4;
    ushort_t* cat2  = (ushort_t*)(ws + off); off += (size_t)T_TOK * (2 * KP2) * 2;
    ushort_t* Wc2   = (ushort_t*)(ws + off); off += (size_t)640 * 576 * 2;
    float*    bc    = (float*)(ws + off);    off += 640 * 4;
    ushort_t* g2    = cat2;
    ushort_t* X2    = (ushort_t*)qkvb;

    prep_const<<<896, 256, 0, stream>>>(ct, st, reg_w, reg_b, br_w, br_b,
                                        sh_w, sh_b, Wc2, bc);
    prep_tok<<<T_TOK, 256, 0, stream>>>(x, emb, X2, cat2);
    splitw_kernel<<<dim3(3, 512), 256, 0, stream>>>(inst_w, inst2, 512, 768, 768);
    splitw_qkv_kernel<<<dim3(2, 1536, 3), 256, 0, stream>>>(qkv_w, qkv2);
    splitw_kernel<<<dim3(2, 3 * 512), 256, 0, stream>>>(out_w, out2w, 3 * 512, 512, 512);
    splitw_ffn<<<dim3(2, 3 * DFFP), 256, 0, stream>>>(w1_w, w3_w, w1s, w3s);
    splitw_w2<<<dim3(6, 3 * 512), 256, 0, stream>>>(w2_w, w2s);

    gemm3_enc<<<dim3(64, 10), 256, 0, stream>>>(X2, Wc2, bc, cat2);
    gemm3_n64<<<dim3(64, 8), 256, 0, stream>>>(
        cat2, 1536, inst2, 1536, inst_b, nullptr, h, 512, 768);
    ln_silu_kernel<<<T_TOK / 4, 256, 0, stream>>>(h, enc_ln_w, enc_ln_b, h);

    for (int l = 0; l < NLAYER; ++l) {
        rms_kernel<<<T_TOK / 4, 256, 0, stream>>>(h, n1_w + l * 512, x2);
        gemm3_kernel<<<dim3(64, 12), 256, 0, stream>>>(
            x2, 1024, qkv2 + (size_t)l * 1536 * 1024, 1024, nullptr, nullptr,
            qkvb, 1536, 512);
        {
            dim3 g(NBLK, NHEAD, BATCH);
            attn_kernel<<<g, 256, 0, stream>>>(qkvb, ct, st, attn2);
        }
        gemm3_n64<<<dim3(64, 8), 256, 0, stream>>>(
            attn2, 1024, out2w + (size_t)l * 512 * 1024, 1024, out_b + l * 512,
            h, h, 512, 512);
        rms_kernel<<<T_TOK / 4, 256, 0, stream>>>(h, n2_w + l * 512, x2);
        gemm_glu3<<<dim3(64, 11), 256, 0, stream>>>(
            x2, w1s + (size_t)l * DFFP * 1024, w3s + (size_t)l * DFFP * 1024,
            w1_b + l * DFF, w3_b + l * DFF, g2);
        gemm3_n64<<<dim3(64, 8), 256, 0, stream>>>(
            g2, 2 * KP2, w2s + (size_t)l * 512 * (2 * KP2), 2 * KP2, w2_b + l * 512,
            h, h, 512, KP2);
    }

    head_kernel<<<T_TOK / 4, 256, 0, stream>>>(h, hl_w, hl_b, head_w, head_b,
                                               (float*)d_out);
}